// Round 1
// 553.912 us; speedup vs baseline: 1.0571x; 1.0571x over previous
//
#include <hip/hip_runtime.h>
#include <math.h>

#define BB 4
#define SS 2048
#define DD 1024
#define HH 16
#define DHH 64
#define DFF 4096
static constexpr float LN_EPS = 1e-5f;

typedef __bf16 bf16x8 __attribute__((ext_vector_type(8)));
typedef float f32x4 __attribute__((ext_vector_type(4)));
typedef unsigned short u16x8 __attribute__((ext_vector_type(8)));

__device__ inline unsigned short f2bf(float f) {
    union { float f; unsigned int u; } v; v.f = f;
    unsigned int u = v.u + 0x7FFFu + ((v.u >> 16) & 1u);  // RNE
    return (unsigned short)(u >> 16);
}

// Fast 2^x via the gfx hardware exp2 (v_exp_f32).
__device__ __forceinline__ float fexp2(float x) {
    return __builtin_amdgcn_exp2f(x);
}

// Async global->LDS DMA, 16 B/lane; LDS dest = wave-uniform base + lane*16.
__device__ __forceinline__ void gl_lds16(const unsigned short* g,
                                         unsigned short* l) {
    __builtin_amdgcn_global_load_lds(
        (const __attribute__((address_space(1))) unsigned int*)g,
        (__attribute__((address_space(3))) unsigned int*)l, 16, 0, 0);
}

// Raw workgroup barrier with compiler memory fence (no vmcnt drain).
#define GBAR()                               \
    do {                                     \
        asm volatile("" ::: "memory");       \
        __builtin_amdgcn_s_barrier();        \
        asm volatile("" ::: "memory");       \
    } while (0)
#define VMCNT(n) asm volatile("s_waitcnt vmcnt(" #n ")" ::: "memory")

// ---------------------------------------------------------------------------
// fp32 [R][C] -> bf16 transposed [C][R]. 64x64 LDS tiles.
// ---------------------------------------------------------------------------
__global__ __launch_bounds__(256) void transpose_bf16_kernel(
    const float* __restrict__ in, unsigned short* __restrict__ outT,
    int R, int C) {
    __shared__ float t[64][65];
    const int r0 = blockIdx.y * 64, c0 = blockIdx.x * 64;
    const int cl = threadIdx.x & 63, rl = threadIdx.x >> 6;
#pragma unroll
    for (int rr = 0; rr < 16; ++rr)
        t[rl + rr * 4][cl] = in[(size_t)(r0 + rl + rr * 4) * C + c0 + cl];
    __syncthreads();
#pragma unroll
    for (int rr = 0; rr < 16; ++rr)
        outT[(size_t)(c0 + rl + rr * 4) * R + r0 + cl] = f2bf(t[cl][rl + rr * 4]);
}

// ---------------------------------------------------------------------------
// Wqkv [H][D][192] fp32 -> Wq2T bf16 [3072][1024] (row n=h*192+e, col k=d).
// ---------------------------------------------------------------------------
__global__ __launch_bounds__(256) void repack_wqkv_bf16_kernel(
    const float* __restrict__ Wqkv, unsigned short* __restrict__ Wq2T) {
    __shared__ float t[64][65];
    const int h = blockIdx.z;
    const int d0 = blockIdx.y * 64, e0 = blockIdx.x * 64;
    const int cl = threadIdx.x & 63, rl = threadIdx.x >> 6;
#pragma unroll
    for (int rr = 0; rr < 16; ++rr)
        t[rl + rr * 4][cl] =
            Wqkv[((size_t)h * DD + d0 + rl + rr * 4) * 192 + e0 + cl];
    __syncthreads();
#pragma unroll
    for (int rr = 0; rr < 16; ++rr)
        Wq2T[((size_t)h * 192 + e0 + rl + rr * 4) * DD + d0 + cl] =
            f2bf(t[cl][rl + rr * 4]);
}

__global__ __launch_bounds__(256) void f2bf_kernel(
    const float* __restrict__ in, unsigned short* __restrict__ out, int n) {
    int i = blockIdx.x * 256 + threadIdx.x;
    if (i < n) out[i] = f2bf(in[i]);
}

// ---------------------------------------------------------------------------
// 256x256-tile, BK=64, 8-wave, 8-phase software-pipelined bf16 MFMA GEMM.
//   C[M,N] = A[M,K] @ BT[N,K]^T
// LDS (128 KiB): A[2 dbuf][2 half][128][64] bf16, then B same.
//   A half h local row r  <-> global tile row (r>>6)*128 + h*64 + (r&63)
//   B half h local row r  <-> global BT row   (r>>5)*64  + h*32 + (r&31)
// (halves = the row stripes consumed in a single phase by ALL waves, so each
//  staged region is dead one phase after its ds_reads -> race-free prefetch)
// k-chunk XOR swizzle: chunk c of local row r holds global chunk c^(r&7)
// (linear gl_lds dest + inverse-swizzled global source; reads apply same XOR
//  -> 2-way max aliasing on ds_read_b128).
// Per wave (wm=wave>>2, wn=wave&3): output 128x64 at (wm*128, wn*64),
// acc[8][4] 16x16 frags. Phase = quadrant: ph1(0,0) ph2(0,1) ph3(1,1) ph4(1,0).
// Stage stream: one half-tile per phase; vmcnt(6) at ph4/ph8 only.
// MODE 2: bf16 out = gelu_tanh(C+bias) via-LDS repack. MODE 3: fp32 C+bias+res.
// MODE 4: QKV scatter (Q*0.125*log2e, K, V^T).
// ---------------------------------------------------------------------------
__device__ __forceinline__ void read_afrag(const unsigned short* s, int base,
                                           int wm, int l15, int g,
                                           bf16x8 af[4][2]) {
#pragma unroll
    for (int ii = 0; ii < 4; ++ii) {
        const int lr = wm * 64 + ii * 16 + l15;
#pragma unroll
        for (int ks = 0; ks < 2; ++ks) {
            const int p = ((ks << 2) + g) ^ (lr & 7);
            af[ii][ks] = __builtin_bit_cast(
                bf16x8, *(const u16x8*)&s[base + lr * 64 + p * 8]);
        }
    }
}

__device__ __forceinline__ void read_bfrag(const unsigned short* s, int base,
                                           int wn, int l15, int g,
                                           bf16x8 bf2[2][2]) {
#pragma unroll
    for (int jj = 0; jj < 2; ++jj) {
        const int lr = wn * 32 + jj * 16 + l15;
#pragma unroll
        for (int ks = 0; ks < 2; ++ks) {
            const int p = ((ks << 2) + g) ^ (lr & 7);
            bf2[jj][ks] = __builtin_bit_cast(
                bf16x8, *(const u16x8*)&s[base + lr * 64 + p * 8]);
        }
    }
}

// RS=6 for A (64-row stripes / 128-row wm blocks), RS=5 for B (32/64).
template <int RS>
__device__ __forceinline__ void stage_half(const unsigned short* __restrict__ G,
                                           int ldK, int growbase, int kbase,
                                           unsigned short* lbase, int tid) {
#pragma unroll
    for (int s = 0; s < 2; ++s) {
        const int c16 = s * 512 + tid;           // 16B chunk id in half-tile
        const int r = c16 >> 3, c = c16 & 7;     // local row, chunk-in-row
        const int grow =
            growbase + ((r >> RS) << (RS + 1)) + (r & ((1 << RS) - 1));
        const int gcol = kbase + ((c ^ (r & 7)) << 3);
        gl_lds16(&G[(size_t)grow * ldK + gcol], &lbase[c16 << 3]);
    }
}

template <int MH, int NH>
__device__ __forceinline__ void mfma_quad(f32x4 acc[8][4],
                                          const bf16x8 af[4][2],
                                          const bf16x8 bf2[2][2]) {
    __builtin_amdgcn_s_setprio(1);
#pragma unroll
    for (int ks = 0; ks < 2; ++ks)
#pragma unroll
        for (int ii = 0; ii < 4; ++ii)
#pragma unroll
            for (int jj = 0; jj < 2; ++jj)
                acc[MH * 4 + ii][NH * 2 + jj] =
                    __builtin_amdgcn_mfma_f32_16x16x32_bf16(
                        af[ii][ks], bf2[jj][ks],
                        acc[MH * 4 + ii][NH * 2 + jj], 0, 0, 0);
    __builtin_amdgcn_s_setprio(0);
}

template <int MODE>
__global__ __launch_bounds__(512) void mfma_gemm256_kernel(
    const unsigned short* __restrict__ A, const unsigned short* __restrict__ BT,
    float* __restrict__ Cf, unsigned short* __restrict__ Cb,
    const float* __restrict__ bias, const float* __restrict__ resid,
    unsigned short* __restrict__ Qb, unsigned short* __restrict__ Kb,
    unsigned short* __restrict__ VTb, int M, int N, int K) {
    __shared__ __align__(16) unsigned short smem[65536];  // 128 KiB
    const int tid = threadIdx.x;
    const int lane = tid & 63, wave = tid >> 6;
    const int wm = wave >> 2, wn = wave & 3;
    const int l15 = lane & 15, g = lane >> 4;

    // XCD-aware bijective block swizzle (all grids here are %8==0).
    const int gx = gridDim.x, nwg = gx * gridDim.y;
    const int lid = blockIdx.y * gx + blockIdx.x;
    const int swz = ((nwg & 7) == 0) ? ((lid & 7) * (nwg >> 3) + (lid >> 3))
                                     : lid;
    const int row0 = (swz / gx) * 256;
    const int col0 = (swz % gx) * 256;

    const int kt = K >> 6;  // # of 64-wide K tiles (always even here)

    // LDS element bases: A(d,h) = (d*2+h)*8192; B(d,h) = 32768 + (d*2+h)*8192
    f32x4 acc[8][4] = {};

    // ---- prologue: T0 fully (buf0) + T1 A0,A1,B0 (buf1) ----
    stage_half<6>(A, K, row0, 0, smem + 0, tid);           // T0 A h0
    stage_half<6>(A, K, row0 + 64, 0, smem + 8192, tid);   // T0 A h1
    stage_half<5>(BT, K, col0, 0, smem + 32768, tid);      // T0 B h0
    stage_half<5>(BT, K, col0 + 32, 0, smem + 40960, tid); // T0 B h1
    VMCNT(4);
    stage_half<6>(A, K, row0, 64, smem + 16384, tid);      // T1 A h0
    stage_half<6>(A, K, row0 + 64, 64, smem + 24576, tid); // T1 A h1
    stage_half<5>(BT, K, col0, 64, smem + 49152, tid);     // T1 B h0
    VMCNT(6);
    GBAR();

    bf16x8 af[4][2], bf0[2][2], bf1[2][2];
    for (int it = 0; it < (kt >> 1); ++it) {
        const int t1k = (2 * it + 1) << 6;
        int t2 = 2 * it + 2; if (t2 > kt - 1) t2 = kt - 1;   // clamped
        int t3 = 2 * it + 3; if (t3 > kt - 1) t3 = kt - 1;   // (junk re-stage,
        const int t2k = t2 << 6, t3k = t3 << 6;              //  dest region dead)

        // ph1: even-tile quad(0,0); stage odd.B1 -> buf1
        read_afrag(smem, 0, wm, l15, g, af);
        read_bfrag(smem, 32768, wn, l15, g, bf0);
        stage_half<5>(BT, K, col0 + 32, t1k, smem + 57344, tid);
        GBAR();
        mfma_quad<0, 0>(acc, af, bf0);
        GBAR();

        // ph2: quad(0,1); stage T+2.A0 -> buf0 (A.h0 dead after ph1)
        read_bfrag(smem, 40960, wn, l15, g, bf1);
        stage_half<6>(A, K, row0, t2k, smem + 0, tid);
        GBAR();
        mfma_quad<0, 1>(acc, af, bf1);
        GBAR();

        // ph3: quad(1,1); stage T+2.B0 (B.h0 dead after ph1)
        read_afrag(smem, 8192, wm, l15, g, af);
        stage_half<5>(BT, K, col0, t2k, smem + 32768, tid);
        GBAR();
        mfma_quad<1, 1>(acc, af, bf1);
        GBAR();

        // ph4: quad(1,0); stage T+2.A1 (dead after ph3); counted wait
        stage_half<6>(A, K, row0 + 64, t2k, smem + 8192, tid);
        GBAR();
        mfma_quad<1, 0>(acc, af, bf0);
        VMCNT(6);  // odd tile fully resident; T+2.{A0,B0,A1} in flight
        GBAR();

        // ph5: odd-tile quad(0,0) from buf1; stage T+2.B1 (dead after ph2)
        read_afrag(smem, 16384, wm, l15, g, af);
        read_bfrag(smem, 49152, wn, l15, g, bf0);
        stage_half<5>(BT, K, col0 + 32, t2k, smem + 40960, tid);
        GBAR();
        mfma_quad<0, 0>(acc, af, bf0);
        GBAR();

        // ph6: quad(0,1); stage T+3.A0 -> buf1 (dead after ph5)
        read_bfrag(smem, 57344, wn, l15, g, bf1);
        stage_half<6>(A, K, row0, t3k, smem + 16384, tid);
        GBAR();
        mfma_quad<0, 1>(acc, af, bf1);
        GBAR();

        // ph7: quad(1,1); stage T+3.B0 (dead after ph5)
        read_afrag(smem, 24576, wm, l15, g, af);
        stage_half<5>(BT, K, col0, t3k, smem + 49152, tid);
        GBAR();
        mfma_quad<1, 1>(acc, af, bf1);
        GBAR();

        // ph8: quad(1,0); stage T+3.A1 (dead after ph7); counted wait
        stage_half<6>(A, K, row0 + 64, t3k, smem + 24576, tid);
        GBAR();
        mfma_quad<1, 0>(acc, af, bf0);
        VMCNT(6);  // next even tile fully resident
        GBAR();
    }
    VMCNT(0);  // drain junk prefetches before LDS reuse / exit
    GBAR();

    if (MODE == 2) {
        constexpr int SLAB = 264;  // 32 x 256 bf16 slab, padded stride
#pragma unroll
        for (int i2 = 0; i2 < 8; ++i2) {
            __syncthreads();
#pragma unroll
            for (int j2 = 0; j2 < 4; ++j2) {
                const int col = wn * 64 + j2 * 16 + l15;
                const float bv = bias[col0 + col];
#pragma unroll
                for (int r = 0; r < 4; ++r) {
                    float v = acc[i2][j2][r] + bv;
                    // gelu_tanh: v * t/(t+1), t = 2^(v*(2.302118+0.102942 v^2))
                    float t = fexp2(v * (2.30211849f + 0.10294198f * v * v));
                    float gel = v * t * __builtin_amdgcn_rcpf(t + 1.f);
                    smem[(wm * 16 + g * 4 + r) * SLAB + col] = f2bf(gel);
                }
            }
            __syncthreads();
            const int sr = tid >> 4;           // 0..31 slab row
            const int cc = (tid & 15) * 16;    // col base
            const int grow = row0 + ((sr >> 4) << 7) + i2 * 16 + (sr & 15);
            *(u16x8*)&Cb[(size_t)grow * N + col0 + cc] =
                *(const u16x8*)&smem[sr * SLAB + cc];
            *(u16x8*)&Cb[(size_t)grow * N + col0 + cc + 8] =
                *(const u16x8*)&smem[sr * SLAB + cc + 8];
        }
        return;
    }

#pragma unroll
    for (int i2 = 0; i2 < 8; ++i2) {
#pragma unroll
        for (int j2 = 0; j2 < 4; ++j2) {
            const int col = col0 + wn * 64 + j2 * 16 + l15;
            const int rowb = row0 + wm * 128 + i2 * 16 + g * 4;
            if (MODE == 4) {
                const int h = col / 192, e = col % 192;
                const int bb = rowb >> 11, s = rowb & 2047;
                if (e < 64) {
                    unsigned short* q =
                        Qb + (((size_t)bb * HH + h) * SS + s) * 64 + e;
#pragma unroll
                    for (int r = 0; r < 4; ++r)
                        q[r * 64] = f2bf(acc[i2][j2][r] * 0.18033688f);
                } else if (e < 128) {
                    unsigned short* kp =
                        Kb + (((size_t)bb * HH + h) * SS + s) * 64 + (e - 64);
#pragma unroll
                    for (int r = 0; r < 4; ++r)
                        kp[r * 64] = f2bf(acc[i2][j2][r]);
                } else {
                    ushort4 pk;
                    pk.x = f2bf(acc[i2][j2][0]);
                    pk.y = f2bf(acc[i2][j2][1]);
                    pk.z = f2bf(acc[i2][j2][2]);
                    pk.w = f2bf(acc[i2][j2][3]);
                    *(ushort4*)(VTb + (((size_t)bb * HH + h) * 64 + (e - 128)) *
                                          SS + s) = pk;
                }
            } else {
                const float bv = bias[col];
#pragma unroll
                for (int r = 0; r < 4; ++r) {
                    const int row = rowb + r;
                    float v = acc[i2][j2][r] + bv + resid[(size_t)row * N + col];
                    Cf[(size_t)row * N + col] = v;
                }
            }
        }
    }
}

// ---------------------------------------------------------------------------
// Flash causal attention, transposed-score formulation, exp2 domain
// (Q pre-scaled by 0.125*log2e in the QKV epilogue).
// S^T = K Q^T; softmax per q-col (2 shuffles); O^T = V^T P^T.
// Block: 128 q of one (b,h); 4 waves x 32 q; kv tiles of 64.
// ---------------------------------------------------------------------------
__global__ __launch_bounds__(256) void fattn_kernel(
    const unsigned short* __restrict__ Qb, const unsigned short* __restrict__ Kb,
    const unsigned short* __restrict__ VTb, unsigned short* __restrict__ att) {
    constexpr int QSTR = 68, KSTR = 68, VSTR = 76, PSTR = 68;
    __shared__ __align__(16) unsigned short Pls[128 * PSTR];
    __shared__ __align__(16) unsigned short Kls[64 * KSTR];
    __shared__ __align__(16) unsigned short VTls[64 * VSTR];

    const int bh = blockIdx.x;
    const int q0 = blockIdx.y * 128;
    const int tid = threadIdx.x;
    const int lane = tid & 63;
    const int wave = tid >> 6;
    const int l15 = lane & 15;
    const int g = lane >> 4;
    const int b = bh >> 4, h = bh & 15;

    const unsigned short* Qh = Qb + (size_t)bh * SS * 64;
    const unsigned short* Kh = Kb + (size_t)bh * SS * 64;
    const unsigned short* Vh = VTb + (size_t)bh * 64 * SS;

    // ---- stage Q tile ----
    {
        const int row = tid >> 1, c0 = (tid & 1) * 32;
        const unsigned short* src = Qh + (size_t)(q0 + row) * 64 + c0;
        unsigned short* dst = &Pls[row * QSTR + c0];
#pragma unroll
        for (int c = 0; c < 32; c += 8)
            *(u16x8*)(dst + c) = *(const u16x8*)(src + c);
    }
    __syncthreads();
    bf16x8 qf[2][2];   // B-frag: [n=q=l15][k=dh]
#pragma unroll
    for (int i = 0; i < 2; ++i)
#pragma unroll
        for (int ks = 0; ks < 2; ++ks)
            qf[i][ks] = __builtin_bit_cast(
                bf16x8, *(const u16x8*)&Pls[(wave * 32 + i * 16 + l15) * QSTR +
                                            ks * 32 + g * 8]);
    __syncthreads();   // Q region dead; Pls reused for P^T

    f32x4 oacc[4][2] = {};          // O^T tiles: [jo=dh][i=q]
    float mst[2], lst[2];
#pragma unroll
    for (int i = 0; i < 2; ++i) { mst[i] = -1e30f; lst[i] = 0.f; }

    const int srow = tid >> 2, sc0 = (tid & 3) * 16;
    const int qlim = q0 + wave * 32 + 31;
    const int qrow = wave * 32 + l15;

    for (int t0 = 0; t0 <= q0 + 64; t0 += 64) {
        __syncthreads();
        {
            const unsigned short* ksrc = Kh + (size_t)(t0 + srow) * 64 + sc0;
            *(u16x8*)&Kls[srow * KSTR + sc0]     = *(const u16x8*)ksrc;
            *(u16x8*)&Kls[srow * KSTR + sc0 + 8] = *(const u16x8*)(ksrc + 8);
            const unsigned short* vsrc = Vh + (size_t)srow * SS + t0 + sc0;
            *(u16x8*)&VTls[srow * VSTR + sc0]     = *(const u16x8*)vsrc;
            *(u16x8*)&VTls[srow * VSTR + sc0 + 8] = *(const u16x8*)(vsrc + 8);
        }
        __syncthreads();
        if (t0 > qlim) continue;

        // ---- S^T = K Q^T ----
        f32x4 sacc[4][2] = {};
#pragma unroll
        for (int ks = 0; ks < 2; ++ks) {
            bf16x8 kb[4];
#pragma unroll
            for (int j = 0; j < 4; ++j)
                kb[j] = __builtin_bit_cast(
                    bf16x8, *(const u16x8*)&Kls[(j * 16 + l15) * KSTR +
                                                ks * 32 + g * 8]);
#pragma unroll
            for (int j = 0; j < 4; ++j)
#pragma unroll
                for (int i = 0; i < 2; ++i)
                    sacc[j][i] = __builtin_amdgcn_mfma_f32_16x16x32_bf16(
                        kb[j], qf[i][ks], sacc[j][i], 0, 0, 0);
        }

        // ---- causal mask ----
        if (t0 >= q0) {
#pragma unroll
            for (int j = 0; j < 4; ++j)
#pragma unroll
                for (int i = 0; i < 2; ++i)
#pragma unroll
                    for (int r = 0; r < 4; ++r) {
                        const int kg = t0 + j * 16 + g * 4 + r;
                        const int qg = q0 + qrow + i * 16;
                        if (kg > qg) sacc[j][i][r] = -1e30f;
                    }
        }

        // ---- online softmax (exp2 domain); P^T -> Pls[q][kv] ----
#pragma unroll
        for (int i = 0; i < 2; ++i) {
            float mx = -1e30f;
#pragma unroll
            for (int j = 0; j < 4; ++j)
#pragma unroll
                for (int r = 0; r < 4; ++r) mx = fmaxf(mx, sacc[j][i][r]);
            mx = fmaxf(mx, __shfl_xor(mx, 16));
            mx = fmaxf(mx, __shfl_xor(mx, 32));
            const float mn = fmaxf(mst[i], mx);
            const float al = fexp2(mst[i] - mn);
            mst[i] = mn;
            float rsum = 0.f;
            const int pbase = (qrow + i * 16) * PSTR + g * 4;
#pragma unroll
            for (int j = 0; j < 4; ++j) {
                float p0 = fexp2(sacc[j][i][0] - mn);
                float p1 = fexp2(sacc[j][i][1] - mn);
                float p2 = fexp2(sacc[j][i][2] - mn);
                float p3 = fexp2(sacc[j][i][3] - mn);
                rsum += (p0 + p1) + (p2 + p3);
                ushort4 pk;
                pk.x = f2bf(p0); pk.y = f2bf(p1);
                pk.z = f2bf(p2); pk.w = f2bf(p3);
                *(ushort4*)&Pls[pbase + j * 16] = pk;
            }
            rsum += __shfl_xor(rsum, 16);
            rsum += __shfl_xor(rsum, 32);
            lst[i] = lst[i] * al + rsum;
#pragma unroll
            for (int jo = 0; jo < 4; ++jo)
#pragma unroll
                for (int r = 0; r < 4; ++r) oacc[jo][i][r] *= al;
        }
        __syncthreads();

        // ---- O^T += V^T P^T ----
#pragma unroll
        for (int ks = 0; ks < 2; ++ks) {
            bf16x8 vb[4], pf[2];
#pragma unroll
            for (int jo = 0; jo < 4; ++jo)
                vb[jo] = __builtin_bit_cast(
                    bf16x8, *(const u16x8*)&VTls[(jo * 16 + l15) * VSTR +
                                                 ks * 32 + g * 8]);
#pragma unroll
            for (int i = 0; i < 2; ++i)
                pf[i] = __builtin_bit_cast(
                    bf16x8, *(const u16x8*)&Pls[(qrow + i * 16) * PSTR +
                                                ks * 32 + g * 8]);
#pragma unroll
            for (int jo = 0; jo < 4; ++jo)
#pragma unroll
                for (int i = 0; i < 2; ++i)
                    oacc[jo][i] = __builtin_amdgcn_mfma_f32_16x16x32_bf16(
                        vb[jo], pf[i], oacc[jo][i], 0, 0, 0);
        }
    }

    // ---- epilogue: O^T/l -> att[b, q, h*64+dh], packed ushort4 ----
#pragma unroll
    for (int i = 0; i < 2; ++i) {
        const float inv = 1.f / lst[i];
        const int qg = q0 + qrow + i * 16;
        unsigned short* dst = att + ((size_t)b * SS + qg) * DD + h * 64 + g * 4;
#pragma unroll
        for (int jo = 0; jo < 4; ++jo) {
            ushort4 pk;
            pk.x = f2bf(oacc[jo][i][0] * inv);
            pk.y = f2bf(oacc[jo][i][1] * inv);
            pk.z = f2bf(oacc[jo][i][2] * inv);
            pk.w = f2bf(oacc[jo][i][3] * inv);
            *(ushort4*)(dst + jo * 16) = pk;
        }
    }
}

// ---------------------------------------------------------------------------
// LayerNorm over D=1024; optional bf16 copy. In-place safe.
// ---------------------------------------------------------------------------
__global__ __launch_bounds__(256) void ln_kernel(
    const float* __restrict__ X, const float* __restrict__ g,
    const float* __restrict__ bta, float* __restrict__ Y,
    unsigned short* __restrict__ Yb) {
    const int row = blockIdx.x;
    const float4 xv = ((const float4*)(X + (size_t)row * DD))[threadIdx.x];

    __shared__ float red1[4], red2[4];
    float s = xv.x + xv.y + xv.z + xv.w;
#pragma unroll
    for (int off = 32; off > 0; off >>= 1) s += __shfl_down(s, off);
    const int wave = threadIdx.x >> 6;
    if ((threadIdx.x & 63) == 0) red1[wave] = s;
    __syncthreads();
    const float mu = (red1[0] + red1[1] + red1[2] + red1[3]) * (1.f / DD);

    float dx = xv.x - mu, dy = xv.y - mu, dz = xv.z - mu, dw = xv.w - mu;
    float s2 = dx * dx + dy * dy + dz * dz + dw * dw;
#pragma unroll
    for (int off = 32; off > 0; off >>= 1) s2 += __shfl_down(s2, off);
    if ((threadIdx.x & 63) == 0) red2[wave] = s2;
    __syncthreads();
    const float var = (red2[0] + red2[1] + red2[2] + red2[3]) * (1.f / DD);
    const float rstd = rsqrtf(var + LN_EPS);

    const float4 gv = ((const float4*)g)[threadIdx.x];
    const float4 bv = ((const float4*)bta)[threadIdx.x];
    float4 yv;
    yv.x = dx * rstd * gv.x + bv.x;
    yv.y = dy * rstd * gv.y + bv.y;
    yv.z = dz * rstd * gv.z + bv.z;
    yv.w = dw * rstd * gv.w + bv.w;
    ((float4*)(Y + (size_t)row * DD))[threadIdx.x] = yv;
    if (Yb) {
        ushort4 q;
        q.x = f2bf(yv.x); q.y = f2bf(yv.y);
        q.z = f2bf(yv.z); q.w = f2bf(yv.w);
        ((ushort4*)(Yb + (size_t)row * DD))[threadIdx.x] = q;
    }
}

// ---------------------------------------------------------------------------
// Workspace (byte offsets, peak 144 MB):
//   [0,16M)    Qb bf16 (ph2-3) -> out1b bf16 (ph5+)
//   [16M,32M)  Kb; [32M,48M) VTb (ph2-3) -> hbuf bf16 [16M,80M) (ph6-7)
//   [96M,102M) Wq2T; [102M,118M) xb (ph1-2)
//   [96M,112M) att bf16 (ph3-4); [96M,128M) out1 fp32 (ph5-7)
//   [118M,120M) WprojT; [128M,136M) W1T; [136M,144M) W2T
// ---------------------------------------------------------------------------
extern "C" void kernel_launch(void* const* d_in, const int* in_sizes, int n_in,
                              void* d_out, int out_size, void* d_ws,
                              size_t ws_size, hipStream_t stream) {
    const float* x     = (const float*)d_in[0];
    const float* Wqkv  = (const float*)d_in[1];
    const float* Wproj = (const float*)d_in[2];
    const float* bproj = (const float*)d_in[3];
    const float* ln1_g = (const float*)d_in[4];
    const float* ln1_b = (const float*)d_in[5];
    const float* ln2_g = (const float*)d_in[6];
    const float* ln2_b = (const float*)d_in[7];
    const float* W1    = (const float*)d_in[8];
    const float* b1    = (const float*)d_in[9];
    const float* W2    = (const float*)d_in[10];
    const float* b2    = (const float*)d_in[11];
    float* out = (float*)d_out;

    const size_t M = (size_t)BB * SS;     // 8192
    const size_t MB = 1024 * 1024;
    char* w = (char*)d_ws;
    unsigned short* Qb     = (unsigned short*)(w + 0);
    unsigned short* out1b  = (unsigned short*)(w + 0);
    unsigned short* Kb     = (unsigned short*)(w + 16 * MB);
    unsigned short* VTb    = (unsigned short*)(w + 32 * MB);
    unsigned short* hbuf   = (unsigned short*)(w + 16 * MB);
    unsigned short* Wq2T   = (unsigned short*)(w + 96 * MB);
    unsigned short* xb     = (unsigned short*)(w + 102 * MB);
    unsigned short* att    = (unsigned short*)(w + 96 * MB);
    float*          out1   = (float*)(w + 96 * MB);
    unsigned short* WprojT = (unsigned short*)(w + 118 * MB);
    unsigned short* W1T    = (unsigned short*)(w + 128 * MB);
    unsigned short* W2T    = (unsigned short*)(w + 136 * MB);

    // 1. weight/input conversions
    repack_wqkv_bf16_kernel<<<dim3(3, 16, 16), 256, 0, stream>>>(Wqkv, Wq2T);
    transpose_bf16_kernel<<<dim3(16, 16), 256, 0, stream>>>(Wproj, WprojT, 1024, 1024);
    transpose_bf16_kernel<<<dim3(64, 16), 256, 0, stream>>>(W1, W1T, 1024, 4096);
    transpose_bf16_kernel<<<dim3(16, 64), 256, 0, stream>>>(W2, W2T, 4096, 1024);
    f2bf_kernel<<<(int)((M * DD + 255) / 256), 256, 0, stream>>>(x, xb, (int)(M * DD));

    // 2. QKV GEMM -> flash layouts Qb/Kb/VTb (bf16, Q in exp2 domain)
    mfma_gemm256_kernel<4><<<dim3(3072 / 256, M / 256), 512, 0, stream>>>(
        xb, Wq2T, nullptr, nullptr, nullptr, nullptr, Qb, Kb, VTb,
        (int)M, 3072, 1024);

    // 3. flash causal attention -> att bf16
    fattn_kernel<<<dim3(BB * HH, SS / 128), 256, 0, stream>>>(Qb, Kb, VTb, att);

    // 4. proj GEMM + bias + residual(x) -> d_out fp32
    mfma_gemm256_kernel<3><<<dim3(1024 / 256, M / 256), 512, 0, stream>>>(
        att, WprojT, out, nullptr, bproj, x, nullptr, nullptr, nullptr,
        (int)M, 1024, 1024);

    // 5. LN1 -> out1 fp32 + out1b bf16
    ln_kernel<<<(int)M, 256, 0, stream>>>(out, ln1_g, ln1_b, out1, out1b);

    // 6. MLP up + GELU -> hbuf bf16
    mfma_gemm256_kernel<2><<<dim3(4096 / 256, M / 256), 512, 0, stream>>>(
        out1b, W1T, nullptr, hbuf, b1, nullptr, nullptr, nullptr, nullptr,
        (int)M, 4096, 1024);

    // 7. MLP down + bias + residual(out1) -> d_out fp32
    mfma_gemm256_kernel<3><<<dim3(1024 / 256, M / 256), 512, 0, stream>>>(
        hbuf, W2T, out, nullptr, b2, out1, nullptr, nullptr, nullptr,
        (int)M, 1024, 4096);

    // 8. LN2 in-place on d_out
    ln_kernel<<<(int)M, 256, 0, stream>>>(out, ln2_g, ln2_b, out, nullptr);
}

// Round 2
// 510.323 us; speedup vs baseline: 1.1473x; 1.0854x over previous
//
#include <hip/hip_runtime.h>
#include <math.h>

#define BB 4
#define SS 2048
#define DD 1024
#define HH 16
#define DHH 64
#define DFF 4096
static constexpr float LN_EPS = 1e-5f;

typedef __bf16 bf16x8 __attribute__((ext_vector_type(8)));
typedef float f32x4 __attribute__((ext_vector_type(4)));
typedef unsigned short u16x8 __attribute__((ext_vector_type(8)));

__device__ inline unsigned short f2bf(float f) {
    union { float f; unsigned int u; } v; v.f = f;
    unsigned int u = v.u + 0x7FFFu + ((v.u >> 16) & 1u);  // RNE
    return (unsigned short)(u >> 16);
}

// Fast 2^x via the gfx hardware exp2 (v_exp_f32).
__device__ __forceinline__ float fexp2(float x) {
    return __builtin_amdgcn_exp2f(x);
}

// Async global->LDS DMA, 16 B/lane; LDS dest = wave-uniform base + lane*16.
__device__ __forceinline__ void gl_lds16(const unsigned short* g,
                                         unsigned short* l) {
    __builtin_amdgcn_global_load_lds(
        (const __attribute__((address_space(1))) unsigned int*)g,
        (__attribute__((address_space(3))) unsigned int*)l, 16, 0, 0);
}

// Raw workgroup barrier with compiler memory fence (no vmcnt drain).
#define GBAR()                               \
    do {                                     \
        asm volatile("" ::: "memory");       \
        __builtin_amdgcn_s_barrier();        \
        asm volatile("" ::: "memory");       \
    } while (0)
#define VMCNT(n) asm volatile("s_waitcnt vmcnt(" #n ")" ::: "memory")

// ---------------------------------------------------------------------------
// fp32 [R][C] -> bf16 transposed [C][R]. 64x64 LDS tiles.
// ---------------------------------------------------------------------------
__global__ __launch_bounds__(256) void transpose_bf16_kernel(
    const float* __restrict__ in, unsigned short* __restrict__ outT,
    int R, int C) {
    __shared__ float t[64][65];
    const int r0 = blockIdx.y * 64, c0 = blockIdx.x * 64;
    const int cl = threadIdx.x & 63, rl = threadIdx.x >> 6;
#pragma unroll
    for (int rr = 0; rr < 16; ++rr)
        t[rl + rr * 4][cl] = in[(size_t)(r0 + rl + rr * 4) * C + c0 + cl];
    __syncthreads();
#pragma unroll
    for (int rr = 0; rr < 16; ++rr)
        outT[(size_t)(c0 + rl + rr * 4) * R + r0 + cl] = f2bf(t[cl][rl + rr * 4]);
}

// ---------------------------------------------------------------------------
// Wqkv [H][D][192] fp32 -> Wq2T bf16 [3072][1024] (row n=h*192+e, col k=d).
// ---------------------------------------------------------------------------
__global__ __launch_bounds__(256) void repack_wqkv_bf16_kernel(
    const float* __restrict__ Wqkv, unsigned short* __restrict__ Wq2T) {
    __shared__ float t[64][65];
    const int h = blockIdx.z;
    const int d0 = blockIdx.y * 64, e0 = blockIdx.x * 64;
    const int cl = threadIdx.x & 63, rl = threadIdx.x >> 6;
#pragma unroll
    for (int rr = 0; rr < 16; ++rr)
        t[rl + rr * 4][cl] =
            Wqkv[((size_t)h * DD + d0 + rl + rr * 4) * 192 + e0 + cl];
    __syncthreads();
#pragma unroll
    for (int rr = 0; rr < 16; ++rr)
        Wq2T[((size_t)h * 192 + e0 + rl + rr * 4) * DD + d0 + cl] =
            f2bf(t[cl][rl + rr * 4]);
}

__global__ __launch_bounds__(256) void f2bf_kernel(
    const float* __restrict__ in, unsigned short* __restrict__ out, int n) {
    int i = blockIdx.x * 256 + threadIdx.x;
    if (i < n) out[i] = f2bf(in[i]);
}

// ---------------------------------------------------------------------------
// Shared staging / fragment helpers (k-chunk XOR swizzle: chunk c of local
// row r holds global chunk c^(r&7); reads apply the same XOR).
// ---------------------------------------------------------------------------
// 128 local rows (2 gl_lds/thread). RS=6: 64-row stripes; RS=5: 32-row stripes.
template <int RS>
__device__ __forceinline__ void stage_half(const unsigned short* __restrict__ G,
                                           int ldK, int growbase, int kbase,
                                           unsigned short* lbase, int tid) {
#pragma unroll
    for (int s = 0; s < 2; ++s) {
        const int c16 = s * 512 + tid;           // 16B chunk id in half-tile
        const int r = c16 >> 3, c = c16 & 7;     // local row, chunk-in-row
        const int grow =
            growbase + ((r >> RS) << (RS + 1)) + (r & ((1 << RS) - 1));
        const int gcol = kbase + ((c ^ (r & 7)) << 3);
        gl_lds16(&G[(size_t)grow * ldK + gcol], &lbase[c16 << 3]);
    }
}

// 64 local rows (1 gl_lds/thread), 32-row stripes.
__device__ __forceinline__ void stage_64(const unsigned short* __restrict__ G,
                                         int ldK, int growbase, int kbase,
                                         unsigned short* lbase, int tid) {
    const int r = tid >> 3, c = tid & 7;
    const int grow = growbase + ((r >> 5) << 6) + (r & 31);
    const int gcol = kbase + ((c ^ (r & 7)) << 3);
    gl_lds16(&G[(size_t)grow * ldK + gcol], &lbase[tid << 3]);
}

// ---------------------------------------------------------------------------
// 256x256-tile, BK=64, 8-wave, 8-phase software-pipelined bf16 MFMA GEMM.
// (used for MLP-up, MODE 2). Per wave (wm=wave>>2, wn=wave&3): 128x64 output.
// vmcnt(6) at ph4/ph8 only. MODE 2: bf16 out = gelu_tanh(C+bias) LDS repack.
// ---------------------------------------------------------------------------
__device__ __forceinline__ void read_afrag(const unsigned short* s, int base,
                                           int wm, int l15, int g,
                                           bf16x8 af[4][2]) {
#pragma unroll
    for (int ii = 0; ii < 4; ++ii) {
        const int lr = wm * 64 + ii * 16 + l15;
#pragma unroll
        for (int ks = 0; ks < 2; ++ks) {
            const int p = ((ks << 2) + g) ^ (lr & 7);
            af[ii][ks] = __builtin_bit_cast(
                bf16x8, *(const u16x8*)&s[base + lr * 64 + p * 8]);
        }
    }
}

__device__ __forceinline__ void read_bfrag(const unsigned short* s, int base,
                                           int wn, int l15, int g,
                                           bf16x8 bf2[2][2]) {
#pragma unroll
    for (int jj = 0; jj < 2; ++jj) {
        const int lr = wn * 32 + jj * 16 + l15;
#pragma unroll
        for (int ks = 0; ks < 2; ++ks) {
            const int p = ((ks << 2) + g) ^ (lr & 7);
            bf2[jj][ks] = __builtin_bit_cast(
                bf16x8, *(const u16x8*)&s[base + lr * 64 + p * 8]);
        }
    }
}

template <int MH, int NH>
__device__ __forceinline__ void mfma_quad(f32x4 acc[8][4],
                                          const bf16x8 af[4][2],
                                          const bf16x8 bf2[2][2]) {
    __builtin_amdgcn_s_setprio(1);
#pragma unroll
    for (int ks = 0; ks < 2; ++ks)
#pragma unroll
        for (int ii = 0; ii < 4; ++ii)
#pragma unroll
            for (int jj = 0; jj < 2; ++jj)
                acc[MH * 4 + ii][NH * 2 + jj] =
                    __builtin_amdgcn_mfma_f32_16x16x32_bf16(
                        af[ii][ks], bf2[jj][ks],
                        acc[MH * 4 + ii][NH * 2 + jj], 0, 0, 0);
    __builtin_amdgcn_s_setprio(0);
}

template <int MODE>
__global__ __launch_bounds__(512) void mfma_gemm256_kernel(
    const unsigned short* __restrict__ A, const unsigned short* __restrict__ BT,
    float* __restrict__ Cf, unsigned short* __restrict__ Cb,
    const float* __restrict__ bias, const float* __restrict__ resid,
    int M, int N, int K) {
    __shared__ __align__(16) unsigned short smem[65536];  // 128 KiB
    const int tid = threadIdx.x;
    const int lane = tid & 63, wave = tid >> 6;
    const int wm = wave >> 2, wn = wave & 3;
    const int l15 = lane & 15, g = lane >> 4;

    const int gx = gridDim.x, nwg = gx * gridDim.y;
    const int lid = blockIdx.y * gx + blockIdx.x;
    const int swz = ((nwg & 7) == 0) ? ((lid & 7) * (nwg >> 3) + (lid >> 3))
                                     : lid;
    const int row0 = (swz / gx) * 256;
    const int col0 = (swz % gx) * 256;

    const int kt = K >> 6;

    f32x4 acc[8][4] = {};

    stage_half<6>(A, K, row0, 0, smem + 0, tid);           // T0 A h0
    stage_half<6>(A, K, row0 + 64, 0, smem + 8192, tid);   // T0 A h1
    stage_half<5>(BT, K, col0, 0, smem + 32768, tid);      // T0 B h0
    stage_half<5>(BT, K, col0 + 32, 0, smem + 40960, tid); // T0 B h1
    VMCNT(4);
    stage_half<6>(A, K, row0, 64, smem + 16384, tid);      // T1 A h0
    stage_half<6>(A, K, row0 + 64, 64, smem + 24576, tid); // T1 A h1
    stage_half<5>(BT, K, col0, 64, smem + 49152, tid);     // T1 B h0
    VMCNT(6);
    GBAR();

    bf16x8 af[4][2], bf0[2][2], bf1[2][2];
    for (int it = 0; it < (kt >> 1); ++it) {
        const int t1k = (2 * it + 1) << 6;
        int t2 = 2 * it + 2; if (t2 > kt - 1) t2 = kt - 1;
        int t3 = 2 * it + 3; if (t3 > kt - 1) t3 = kt - 1;
        const int t2k = t2 << 6, t3k = t3 << 6;

        read_afrag(smem, 0, wm, l15, g, af);
        read_bfrag(smem, 32768, wn, l15, g, bf0);
        stage_half<5>(BT, K, col0 + 32, t1k, smem + 57344, tid);
        GBAR();
        mfma_quad<0, 0>(acc, af, bf0);
        GBAR();

        read_bfrag(smem, 40960, wn, l15, g, bf1);
        stage_half<6>(A, K, row0, t2k, smem + 0, tid);
        GBAR();
        mfma_quad<0, 1>(acc, af, bf1);
        GBAR();

        read_afrag(smem, 8192, wm, l15, g, af);
        stage_half<5>(BT, K, col0, t2k, smem + 32768, tid);
        GBAR();
        mfma_quad<1, 1>(acc, af, bf1);
        GBAR();

        stage_half<6>(A, K, row0 + 64, t2k, smem + 8192, tid);
        GBAR();
        mfma_quad<1, 0>(acc, af, bf0);
        VMCNT(6);
        GBAR();

        read_afrag(smem, 16384, wm, l15, g, af);
        read_bfrag(smem, 49152, wn, l15, g, bf0);
        stage_half<5>(BT, K, col0 + 32, t2k, smem + 40960, tid);
        GBAR();
        mfma_quad<0, 0>(acc, af, bf0);
        GBAR();

        read_bfrag(smem, 57344, wn, l15, g, bf1);
        stage_half<6>(A, K, row0, t3k, smem + 16384, tid);
        GBAR();
        mfma_quad<0, 1>(acc, af, bf1);
        GBAR();

        read_afrag(smem, 24576, wm, l15, g, af);
        stage_half<5>(BT, K, col0, t3k, smem + 49152, tid);
        GBAR();
        mfma_quad<1, 1>(acc, af, bf1);
        GBAR();

        stage_half<6>(A, K, row0 + 64, t3k, smem + 24576, tid);
        GBAR();
        mfma_quad<1, 0>(acc, af, bf0);
        VMCNT(6);
        GBAR();
    }
    VMCNT(0);
    GBAR();

    if (MODE == 2) {
        constexpr int SLAB = 264;  // 32 x 256 bf16 slab, padded stride
#pragma unroll
        for (int i2 = 0; i2 < 8; ++i2) {
            __syncthreads();
#pragma unroll
            for (int j2 = 0; j2 < 4; ++j2) {
                const int col = wn * 64 + j2 * 16 + l15;
                const float bv = bias[col0 + col];
#pragma unroll
                for (int r = 0; r < 4; ++r) {
                    float v = acc[i2][j2][r] + bv;
                    // gelu_tanh: v * t/(t+1), t = 2^(v*(2.302118+0.102942 v^2))
                    float t = fexp2(v * (2.30211849f + 0.10294198f * v * v));
                    float gel = v * t * __builtin_amdgcn_rcpf(t + 1.f);
                    smem[(wm * 16 + g * 4 + r) * SLAB + col] = f2bf(gel);
                }
            }
            __syncthreads();
            const int sr = tid >> 4;           // 0..31 slab row
            const int cc = (tid & 15) * 16;    // col base
            const int grow = row0 + ((sr >> 4) << 7) + i2 * 16 + (sr & 15);
            *(u16x8*)&Cb[(size_t)grow * N + col0 + cc] =
                *(const u16x8*)&smem[sr * SLAB + cc];
            *(u16x8*)&Cb[(size_t)grow * N + col0 + cc + 8] =
                *(const u16x8*)&smem[sr * SLAB + cc + 8];
        }
        return;
    }

#pragma unroll
    for (int i2 = 0; i2 < 8; ++i2) {
#pragma unroll
        for (int j2 = 0; j2 < 4; ++j2) {
            const int col = col0 + wn * 64 + j2 * 16 + l15;
            const int rowb = row0 + wm * 128 + i2 * 16 + g * 4;
            const float bv = bias[col];
#pragma unroll
            for (int r = 0; r < 4; ++r) {
                const int row = rowb + r;
                float v = acc[i2][j2][r] + bv + resid[(size_t)row * N + col];
                Cf[(size_t)row * N + col] = v;
            }
        }
    }
}

// ---------------------------------------------------------------------------
// 256x128-tile, BK=64, 8-wave (4M x 2N), 8-phase GEMM — for N=1024/3072 cases
// where a 256x256 grid under-fills the 256 CUs.
// LDS 96 KiB: A[2 dbuf][2 half(128 rows)][stripe-mapped], B[2 dbuf][2 half(64)].
//   A half h local row r (0..127) <-> global tile row (r>>5)*64 + h*32 + (r&31)
//   B half h local row r (0..63)  <-> global BT row   (r>>5)*64 + h*32 + (r&31)
// Per wave (wm=wave>>1, wn=wave&1): output 64x64, acc[4][4].
// Quad (MH,NH): rows wm*64+MH*32+..., cols wn*64+NH*32+...
// Loads/thread per phase {1,2,1,2}; vmcnt(5) at ph4/ph8 (next tile's 6 loads
// drained, following tile's 5 in flight).
// MODE 3: fp32 C+bias+resid. MODE 4: QKV scatter.
// ---------------------------------------------------------------------------
__device__ __forceinline__ void read_af128(const unsigned short* s, int base,
                                           int wm, int l15, int g,
                                           bf16x8 af[2][2]) {
#pragma unroll
    for (int ii = 0; ii < 2; ++ii) {
        const int lr = wm * 32 + ii * 16 + l15;
#pragma unroll
        for (int ks = 0; ks < 2; ++ks) {
            const int p = ((ks << 2) + g) ^ (lr & 7);
            af[ii][ks] = __builtin_bit_cast(
                bf16x8, *(const u16x8*)&s[base + lr * 64 + p * 8]);
        }
    }
}

__device__ __forceinline__ void read_bf128(const unsigned short* s, int base,
                                           int wn, int l15, int g,
                                           bf16x8 bf2[2][2]) {
#pragma unroll
    for (int jj = 0; jj < 2; ++jj) {
        const int lr = wn * 32 + jj * 16 + l15;
#pragma unroll
        for (int ks = 0; ks < 2; ++ks) {
            const int p = ((ks << 2) + g) ^ (lr & 7);
            bf2[jj][ks] = __builtin_bit_cast(
                bf16x8, *(const u16x8*)&s[base + lr * 64 + p * 8]);
        }
    }
}

template <int MH, int NH>
__device__ __forceinline__ void mfma_quad128(f32x4 acc[4][4],
                                             const bf16x8 af[2][2],
                                             const bf16x8 bf2[2][2]) {
    __builtin_amdgcn_s_setprio(1);
#pragma unroll
    for (int ks = 0; ks < 2; ++ks)
#pragma unroll
        for (int ii = 0; ii < 2; ++ii)
#pragma unroll
            for (int jj = 0; jj < 2; ++jj)
                acc[MH * 2 + ii][NH * 2 + jj] =
                    __builtin_amdgcn_mfma_f32_16x16x32_bf16(
                        af[ii][ks], bf2[jj][ks],
                        acc[MH * 2 + ii][NH * 2 + jj], 0, 0, 0);
    __builtin_amdgcn_s_setprio(0);
}

template <int MODE>
__global__ __launch_bounds__(512) void gemm_n128_kernel(
    const unsigned short* __restrict__ A, const unsigned short* __restrict__ BT,
    float* __restrict__ Cf, const float* __restrict__ bias,
    const float* __restrict__ resid, unsigned short* __restrict__ Qb,
    unsigned short* __restrict__ Kb, unsigned short* __restrict__ VTb,
    int M, int N, int K) {
    __shared__ __align__(16) unsigned short smem[49152];  // 96 KiB
    const int tid = threadIdx.x;
    const int lane = tid & 63, wave = tid >> 6;
    const int wm = wave >> 1, wn = wave & 1;
    const int l15 = lane & 15, g = lane >> 4;

    const int gx = gridDim.x, nwg = gx * gridDim.y;
    const int lid = blockIdx.y * gx + blockIdx.x;
    const int swz = ((nwg & 7) == 0) ? ((lid & 7) * (nwg >> 3) + (lid >> 3))
                                     : lid;
    const int row0 = (swz / gx) * 256;
    const int col0 = (swz % gx) * 128;

    const int kt = K >> 6;

    // LDS bases (elems): A buf d half h: (d*2+h)*8192 ; B: 32768+(d*2+h)*4096
    f32x4 acc[4][4] = {};

    stage_half<5>(A, K, row0, 0, smem + 0, tid);            // T0 A h0 (2)
    stage_half<5>(A, K, row0 + 32, 0, smem + 8192, tid);    // T0 A h1 (2)
    stage_64(BT, K, col0, 0, smem + 32768, tid);            // T0 B h0 (1)
    stage_64(BT, K, col0 + 32, 0, smem + 36864, tid);       // T0 B h1 (1)
    VMCNT(4);
    stage_half<5>(A, K, row0, 64, smem + 16384, tid);       // T1 A h0 (2)
    stage_half<5>(A, K, row0 + 32, 64, smem + 24576, tid);  // T1 A h1 (2)
    stage_64(BT, K, col0, 64, smem + 40960, tid);           // T1 B h0 (1)
    VMCNT(5);   // T0's 6 loads done; T1's 5 in flight
    GBAR();

    bf16x8 af[2][2], bf0[2][2], bf1[2][2];
    for (int it = 0; it < (kt >> 1); ++it) {
        const int t1k = (2 * it + 1) << 6;
        int t2 = 2 * it + 2; if (t2 > kt - 1) t2 = kt - 1;   // clamped
        int t3 = 2 * it + 3; if (t3 > kt - 1) t3 = kt - 1;   // (junk re-stage,
        const int t2k = t2 << 6, t3k = t3 << 6;              //  dest dead)

        // ph1: quad(0,0); stage odd.B1 -> buf1
        read_af128(smem, 0, wm, l15, g, af);
        read_bf128(smem, 32768, wn, l15, g, bf0);
        stage_64(BT, K, col0 + 32, t1k, smem + 45056, tid);
        GBAR();
        mfma_quad128<0, 0>(acc, af, bf0);
        GBAR();

        // ph2: quad(0,1); stage T+2.A0 (dead after ph1)
        read_bf128(smem, 36864, wn, l15, g, bf1);
        stage_half<5>(A, K, row0, t2k, smem + 0, tid);
        GBAR();
        mfma_quad128<0, 1>(acc, af, bf1);
        GBAR();

        // ph3: quad(1,1); stage T+2.B0 (dead after ph1)
        read_af128(smem, 8192, wm, l15, g, af);
        stage_64(BT, K, col0, t2k, smem + 32768, tid);
        GBAR();
        mfma_quad128<1, 1>(acc, af, bf1);
        GBAR();

        // ph4: quad(1,0); stage T+2.A1 (dead after ph3); counted wait
        stage_half<5>(A, K, row0 + 32, t2k, smem + 8192, tid);
        GBAR();
        mfma_quad128<1, 0>(acc, af, bf0);
        VMCNT(5);  // odd tile's 6 resident; T+2's 5 in flight
        GBAR();

        // ph5: odd quad(0,0) from buf1; stage T+2.B1 (dead after ph2)
        read_af128(smem, 16384, wm, l15, g, af);
        read_bf128(smem, 40960, wn, l15, g, bf0);
        stage_64(BT, K, col0 + 32, t2k, smem + 36864, tid);
        GBAR();
        mfma_quad128<0, 0>(acc, af, bf0);
        GBAR();

        // ph6: quad(0,1); stage T+3.A0 (dead after ph5)
        read_bf128(smem, 45056, wn, l15, g, bf1);
        stage_half<5>(A, K, row0, t3k, smem + 16384, tid);
        GBAR();
        mfma_quad128<0, 1>(acc, af, bf1);
        GBAR();

        // ph7: quad(1,1); stage T+3.B0 (dead after ph5)
        read_af128(smem, 24576, wm, l15, g, af);
        stage_64(BT, K, col0, t3k, smem + 40960, tid);
        GBAR();
        mfma_quad128<1, 1>(acc, af, bf1);
        GBAR();

        // ph8: quad(1,0); stage T+3.A1 (dead after ph7); counted wait
        stage_half<5>(A, K, row0 + 32, t3k, smem + 24576, tid);
        GBAR();
        mfma_quad128<1, 0>(acc, af, bf0);
        VMCNT(5);
        GBAR();
    }
    VMCNT(0);  // drain junk prefetches before exit
    GBAR();

#pragma unroll
    for (int i2 = 0; i2 < 4; ++i2) {
#pragma unroll
        for (int j2 = 0; j2 < 4; ++j2) {
            const int col = col0 + wn * 64 + j2 * 16 + l15;
            const int rowb = row0 + wm * 64 + i2 * 16 + g * 4;
            if (MODE == 4) {
                const int h = col / 192, e = col % 192;
                const int bb = rowb >> 11, s = rowb & 2047;
                if (e < 64) {
                    unsigned short* q =
                        Qb + (((size_t)bb * HH + h) * SS + s) * 64 + e;
#pragma unroll
                    for (int r = 0; r < 4; ++r)
                        q[r * 64] = f2bf(acc[i2][j2][r] * 0.18033688f);
                } else if (e < 128) {
                    unsigned short* kp =
                        Kb + (((size_t)bb * HH + h) * SS + s) * 64 + (e - 64);
#pragma unroll
                    for (int r = 0; r < 4; ++r)
                        kp[r * 64] = f2bf(acc[i2][j2][r]);
                } else {
                    ushort4 pk;
                    pk.x = f2bf(acc[i2][j2][0]);
                    pk.y = f2bf(acc[i2][j2][1]);
                    pk.z = f2bf(acc[i2][j2][2]);
                    pk.w = f2bf(acc[i2][j2][3]);
                    *(ushort4*)(VTb + (((size_t)bb * HH + h) * 64 + (e - 128)) *
                                          SS + s) = pk;
                }
            } else {
                const float bv = bias[col];
#pragma unroll
                for (int r = 0; r < 4; ++r) {
                    const int row = rowb + r;
                    float v = acc[i2][j2][r] + bv + resid[(size_t)row * N + col];
                    Cf[(size_t)row * N + col] = v;
                }
            }
        }
    }
}

// ---------------------------------------------------------------------------
// Flash causal attention, transposed-score formulation, exp2 domain
// (Q pre-scaled by 0.125*log2e in the QKV epilogue).
// S^T = K Q^T; softmax per q-col (2 shuffles); O^T = V^T P^T.
// Block: 128 q of one (b,h); 4 waves x 32 q; kv tiles of 64.
// ---------------------------------------------------------------------------
__global__ __launch_bounds__(256) void fattn_kernel(
    const unsigned short* __restrict__ Qb, const unsigned short* __restrict__ Kb,
    const unsigned short* __restrict__ VTb, unsigned short* __restrict__ att) {
    constexpr int QSTR = 68, KSTR = 68, VSTR = 76, PSTR = 68;
    __shared__ __align__(16) unsigned short Pls[128 * PSTR];
    __shared__ __align__(16) unsigned short Kls[64 * KSTR];
    __shared__ __align__(16) unsigned short VTls[64 * VSTR];

    const int bh = blockIdx.x;
    const int q0 = blockIdx.y * 128;
    const int tid = threadIdx.x;
    const int lane = tid & 63;
    const int wave = tid >> 6;
    const int l15 = lane & 15;
    const int g = lane >> 4;
    const int b = bh >> 4, h = bh & 15;

    const unsigned short* Qh = Qb + (size_t)bh * SS * 64;
    const unsigned short* Kh = Kb + (size_t)bh * SS * 64;
    const unsigned short* Vh = VTb + (size_t)bh * 64 * SS;

    // ---- stage Q tile ----
    {
        const int row = tid >> 1, c0 = (tid & 1) * 32;
        const unsigned short* src = Qh + (size_t)(q0 + row) * 64 + c0;
        unsigned short* dst = &Pls[row * QSTR + c0];
#pragma unroll
        for (int c = 0; c < 32; c += 8)
            *(u16x8*)(dst + c) = *(const u16x8*)(src + c);
    }
    __syncthreads();
    bf16x8 qf[2][2];   // B-frag: [n=q=l15][k=dh]
#pragma unroll
    for (int i = 0; i < 2; ++i)
#pragma unroll
        for (int ks = 0; ks < 2; ++ks)
            qf[i][ks] = __builtin_bit_cast(
                bf16x8, *(const u16x8*)&Pls[(wave * 32 + i * 16 + l15) * QSTR +
                                            ks * 32 + g * 8]);
    __syncthreads();   // Q region dead; Pls reused for P^T

    f32x4 oacc[4][2] = {};          // O^T tiles: [jo=dh][i=q]
    float mst[2], lst[2];
#pragma unroll
    for (int i = 0; i < 2; ++i) { mst[i] = -1e30f; lst[i] = 0.f; }

    const int srow = tid >> 2, sc0 = (tid & 3) * 16;
    const int qlim = q0 + wave * 32 + 31;
    const int qrow = wave * 32 + l15;

    for (int t0 = 0; t0 <= q0 + 64; t0 += 64) {
        __syncthreads();
        {
            const unsigned short* ksrc = Kh + (size_t)(t0 + srow) * 64 + sc0;
            *(u16x8*)&Kls[srow * KSTR + sc0]     = *(const u16x8*)ksrc;
            *(u16x8*)&Kls[srow * KSTR + sc0 + 8] = *(const u16x8*)(ksrc + 8);
            const unsigned short* vsrc = Vh + (size_t)srow * SS + t0 + sc0;
            *(u16x8*)&VTls[srow * VSTR + sc0]     = *(const u16x8*)vsrc;
            *(u16x8*)&VTls[srow * VSTR + sc0 + 8] = *(const u16x8*)(vsrc + 8);
        }
        __syncthreads();
        if (t0 > qlim) continue;

        // ---- S^T = K Q^T ----
        f32x4 sacc[4][2] = {};
#pragma unroll
        for (int ks = 0; ks < 2; ++ks) {
            bf16x8 kb[4];
#pragma unroll
            for (int j = 0; j < 4; ++j)
                kb[j] = __builtin_bit_cast(
                    bf16x8, *(const u16x8*)&Kls[(j * 16 + l15) * KSTR +
                                                ks * 32 + g * 8]);
#pragma unroll
            for (int j = 0; j < 4; ++j)
#pragma unroll
                for (int i = 0; i < 2; ++i)
                    sacc[j][i] = __builtin_amdgcn_mfma_f32_16x16x32_bf16(
                        kb[j], qf[i][ks], sacc[j][i], 0, 0, 0);
        }

        // ---- causal mask ----
        if (t0 >= q0) {
#pragma unroll
            for (int j = 0; j < 4; ++j)
#pragma unroll
                for (int i = 0; i < 2; ++i)
#pragma unroll
                    for (int r = 0; r < 4; ++r) {
                        const int kg = t0 + j * 16 + g * 4 + r;
                        const int qg = q0 + qrow + i * 16;
                        if (kg > qg) sacc[j][i][r] = -1e30f;
                    }
        }

        // ---- online softmax (exp2 domain); P^T -> Pls[q][kv] ----
#pragma unroll
        for (int i = 0; i < 2; ++i) {
            float mx = -1e30f;
#pragma unroll
            for (int j = 0; j < 4; ++j)
#pragma unroll
                for (int r = 0; r < 4; ++r) mx = fmaxf(mx, sacc[j][i][r]);
            mx = fmaxf(mx, __shfl_xor(mx, 16));
            mx = fmaxf(mx, __shfl_xor(mx, 32));
            const float mn = fmaxf(mst[i], mx);
            const float al = fexp2(mst[i] - mn);
            mst[i] = mn;
            float rsum = 0.f;
            const int pbase = (qrow + i * 16) * PSTR + g * 4;
#pragma unroll
            for (int j = 0; j < 4; ++j) {
                float p0 = fexp2(sacc[j][i][0] - mn);
                float p1 = fexp2(sacc[j][i][1] - mn);
                float p2 = fexp2(sacc[j][i][2] - mn);
                float p3 = fexp2(sacc[j][i][3] - mn);
                rsum += (p0 + p1) + (p2 + p3);
                ushort4 pk;
                pk.x = f2bf(p0); pk.y = f2bf(p1);
                pk.z = f2bf(p2); pk.w = f2bf(p3);
                *(ushort4*)&Pls[pbase + j * 16] = pk;
            }
            rsum += __shfl_xor(rsum, 16);
            rsum += __shfl_xor(rsum, 32);
            lst[i] = lst[i] * al + rsum;
#pragma unroll
            for (int jo = 0; jo < 4; ++jo)
#pragma unroll
                for (int r = 0; r < 4; ++r) oacc[jo][i][r] *= al;
        }
        __syncthreads();

        // ---- O^T += V^T P^T ----
#pragma unroll
        for (int ks = 0; ks < 2; ++ks) {
            bf16x8 vb[4], pf[2];
#pragma unroll
            for (int jo = 0; jo < 4; ++jo)
                vb[jo] = __builtin_bit_cast(
                    bf16x8, *(const u16x8*)&VTls[(jo * 16 + l15) * VSTR +
                                                 ks * 32 + g * 8]);
#pragma unroll
            for (int i = 0; i < 2; ++i)
                pf[i] = __builtin_bit_cast(
                    bf16x8, *(const u16x8*)&Pls[(qrow + i * 16) * PSTR +
                                                ks * 32 + g * 8]);
#pragma unroll
            for (int jo = 0; jo < 4; ++jo)
#pragma unroll
                for (int i = 0; i < 2; ++i)
                    oacc[jo][i] = __builtin_amdgcn_mfma_f32_16x16x32_bf16(
                        vb[jo], pf[i], oacc[jo][i], 0, 0, 0);
        }
    }

    // ---- epilogue: O^T/l -> att[b, q, h*64+dh], packed ushort4 ----
#pragma unroll
    for (int i = 0; i < 2; ++i) {
        const float inv = 1.f / lst[i];
        const int qg = q0 + qrow + i * 16;
        unsigned short* dst = att + ((size_t)b * SS + qg) * DD + h * 64 + g * 4;
#pragma unroll
        for (int jo = 0; jo < 4; ++jo) {
            ushort4 pk;
            pk.x = f2bf(oacc[jo][i][0] * inv);
            pk.y = f2bf(oacc[jo][i][1] * inv);
            pk.z = f2bf(oacc[jo][i][2] * inv);
            pk.w = f2bf(oacc[jo][i][3] * inv);
            *(ushort4*)(dst + jo * 16) = pk;
        }
    }
}

// ---------------------------------------------------------------------------
// LayerNorm over D=1024; optional bf16 copy. In-place safe.
// ---------------------------------------------------------------------------
__global__ __launch_bounds__(256) void ln_kernel(
    const float* __restrict__ X, const float* __restrict__ g,
    const float* __restrict__ bta, float* __restrict__ Y,
    unsigned short* __restrict__ Yb) {
    const int row = blockIdx.x;
    const float4 xv = ((const float4*)(X + (size_t)row * DD))[threadIdx.x];

    __shared__ float red1[4], red2[4];
    float s = xv.x + xv.y + xv.z + xv.w;
#pragma unroll
    for (int off = 32; off > 0; off >>= 1) s += __shfl_down(s, off);
    const int wave = threadIdx.x >> 6;
    if ((threadIdx.x & 63) == 0) red1[wave] = s;
    __syncthreads();
    const float mu = (red1[0] + red1[1] + red1[2] + red1[3]) * (1.f / DD);

    float dx = xv.x - mu, dy = xv.y - mu, dz = xv.z - mu, dw = xv.w - mu;
    float s2 = dx * dx + dy * dy + dz * dz + dw * dw;
#pragma unroll
    for (int off = 32; off > 0; off >>= 1) s2 += __shfl_down(s2, off);
    if ((threadIdx.x & 63) == 0) red2[wave] = s2;
    __syncthreads();
    const float var = (red2[0] + red2[1] + red2[2] + red2[3]) * (1.f / DD);
    const float rstd = rsqrtf(var + LN_EPS);

    const float4 gv = ((const float4*)g)[threadIdx.x];
    const float4 bv = ((const float4*)bta)[threadIdx.x];
    float4 yv;
    yv.x = dx * rstd * gv.x + bv.x;
    yv.y = dy * rstd * gv.y + bv.y;
    yv.z = dz * rstd * gv.z + bv.z;
    yv.w = dw * rstd * gv.w + bv.w;
    ((float4*)(Y + (size_t)row * DD))[threadIdx.x] = yv;
    if (Yb) {
        ushort4 q;
        q.x = f2bf(yv.x); q.y = f2bf(yv.y);
        q.z = f2bf(yv.z); q.w = f2bf(yv.w);
        ((ushort4*)(Yb + (size_t)row * DD))[threadIdx.x] = q;
    }
}

// ---------------------------------------------------------------------------
// Workspace (byte offsets, peak 144 MB):
//   [0,16M)    Qb bf16 (ph2-3) -> out1b bf16 (ph5+)
//   [16M,32M)  Kb; [32M,48M) VTb (ph2-3) -> hbuf bf16 [16M,80M) (ph6-7)
//   [96M,102M) Wq2T; [102M,118M) xb (ph1-2)
//   [96M,112M) att bf16 (ph3-4); [96M,128M) out1 fp32 (ph5-7)
//   [118M,120M) WprojT; [128M,136M) W1T; [136M,144M) W2T
// ---------------------------------------------------------------------------
extern "C" void kernel_launch(void* const* d_in, const int* in_sizes, int n_in,
                              void* d_out, int out_size, void* d_ws,
                              size_t ws_size, hipStream_t stream) {
    const float* x     = (const float*)d_in[0];
    const float* Wqkv  = (const float*)d_in[1];
    const float* Wproj = (const float*)d_in[2];
    const float* bproj = (const float*)d_in[3];
    const float* ln1_g = (const float*)d_in[4];
    const float* ln1_b = (const float*)d_in[5];
    const float* ln2_g = (const float*)d_in[6];
    const float* ln2_b = (const float*)d_in[7];
    const float* W1    = (const float*)d_in[8];
    const float* b1    = (const float*)d_in[9];
    const float* W2    = (const float*)d_in[10];
    const float* b2    = (const float*)d_in[11];
    float* out = (float*)d_out;

    const size_t M = (size_t)BB * SS;     // 8192
    const size_t MB = 1024 * 1024;
    char* w = (char*)d_ws;
    unsigned short* Qb     = (unsigned short*)(w + 0);
    unsigned short* out1b  = (unsigned short*)(w + 0);
    unsigned short* Kb     = (unsigned short*)(w + 16 * MB);
    unsigned short* VTb    = (unsigned short*)(w + 32 * MB);
    unsigned short* hbuf   = (unsigned short*)(w + 16 * MB);
    unsigned short* Wq2T   = (unsigned short*)(w + 96 * MB);
    unsigned short* xb     = (unsigned short*)(w + 102 * MB);
    unsigned short* att    = (unsigned short*)(w + 96 * MB);
    float*          out1   = (float*)(w + 96 * MB);
    unsigned short* WprojT = (unsigned short*)(w + 118 * MB);
    unsigned short* W1T    = (unsigned short*)(w + 128 * MB);
    unsigned short* W2T    = (unsigned short*)(w + 136 * MB);

    // 1. weight/input conversions
    repack_wqkv_bf16_kernel<<<dim3(3, 16, 16), 256, 0, stream>>>(Wqkv, Wq2T);
    transpose_bf16_kernel<<<dim3(16, 16), 256, 0, stream>>>(Wproj, WprojT, 1024, 1024);
    transpose_bf16_kernel<<<dim3(64, 16), 256, 0, stream>>>(W1, W1T, 1024, 4096);
    transpose_bf16_kernel<<<dim3(16, 64), 256, 0, stream>>>(W2, W2T, 4096, 1024);
    f2bf_kernel<<<(int)((M * DD + 255) / 256), 256, 0, stream>>>(x, xb, (int)(M * DD));

    // 2. QKV GEMM -> flash layouts Qb/Kb/VTb (bf16, Q in exp2 domain)
    gemm_n128_kernel<4><<<dim3(3072 / 128, M / 256), 512, 0, stream>>>(
        xb, Wq2T, nullptr, nullptr, nullptr, Qb, Kb, VTb, (int)M, 3072, 1024);

    // 3. flash causal attention -> att bf16
    fattn_kernel<<<dim3(BB * HH, SS / 128), 256, 0, stream>>>(Qb, Kb, VTb, att);

    // 4. proj GEMM + bias + residual(x) -> d_out fp32
    gemm_n128_kernel<3><<<dim3(1024 / 128, M / 256), 512, 0, stream>>>(
        att, WprojT, out, bproj, x, nullptr, nullptr, nullptr,
        (int)M, 1024, 1024);

    // 5. LN1 -> out1 fp32 + out1b bf16
    ln_kernel<<<(int)M, 256, 0, stream>>>(out, ln1_g, ln1_b, out1, out1b);

    // 6. MLP up + GELU -> hbuf bf16
    mfma_gemm256_kernel<2><<<dim3(4096 / 256, M / 256), 512, 0, stream>>>(
        out1b, W1T, nullptr, hbuf, b1, nullptr, (int)M, 4096, 1024);

    // 7. MLP down + bias + residual(out1) -> d_out fp32
    gemm_n128_kernel<3><<<dim3(1024 / 128, M / 256), 512, 0, stream>>>(
        hbuf, W2T, out, b2, out1, nullptr, nullptr, nullptr,
        (int)M, 1024, 4096);

    // 8. LN2 in-place on d_out
    ln_kernel<<<(int)M, 256, 0, stream>>>(out, ln2_g, ln2_b, out, nullptr);
}

// Round 3
// 505.252 us; speedup vs baseline: 1.1589x; 1.0100x over previous
//
#include <hip/hip_runtime.h>
#include <math.h>

#define BB 4
#define SS 2048
#define DD 1024
#define HH 16
#define DHH 64
#define DFF 4096
static constexpr float LN_EPS = 1e-5f;

typedef __bf16 bf16x8 __attribute__((ext_vector_type(8)));
typedef float f32x4 __attribute__((ext_vector_type(4)));
typedef unsigned short u16x8 __attribute__((ext_vector_type(8)));

// bf16 convert via HW RNE cvt (bit-identical to manual round-to-nearest-even).
__device__ __forceinline__ unsigned short f2bf(float f) {
    return __builtin_bit_cast(unsigned short, (__bf16)f);
}

// Fast 2^x via the gfx hardware exp2 (v_exp_f32).
__device__ __forceinline__ float fexp2(float x) {
    return __builtin_amdgcn_exp2f(x);
}

// Async global->LDS DMA, 16 B/lane; LDS dest = wave-uniform base + lane*16.
__device__ __forceinline__ void gl_lds16(const unsigned short* g,
                                         unsigned short* l) {
    __builtin_amdgcn_global_load_lds(
        (const __attribute__((address_space(1))) unsigned int*)g,
        (__attribute__((address_space(3))) unsigned int*)l, 16, 0, 0);
}

// Raw workgroup barrier with compiler memory fence (no vmcnt drain).
#define GBAR()                               \
    do {                                     \
        asm volatile("" ::: "memory");       \
        __builtin_amdgcn_s_barrier();        \
        asm volatile("" ::: "memory");       \
    } while (0)
#define VMCNT(n) asm volatile("s_waitcnt vmcnt(" #n ")" ::: "memory")

// ---------------------------------------------------------------------------
// fp32 [R][C] -> bf16 transposed [C][R]. 64x64 LDS tiles.
// ---------------------------------------------------------------------------
__global__ __launch_bounds__(256) void transpose_bf16_kernel(
    const float* __restrict__ in, unsigned short* __restrict__ outT,
    int R, int C) {
    __shared__ float t[64][65];
    const int r0 = blockIdx.y * 64, c0 = blockIdx.x * 64;
    const int cl = threadIdx.x & 63, rl = threadIdx.x >> 6;
#pragma unroll
    for (int rr = 0; rr < 16; ++rr)
        t[rl + rr * 4][cl] = in[(size_t)(r0 + rl + rr * 4) * C + c0 + cl];
    __syncthreads();
#pragma unroll
    for (int rr = 0; rr < 16; ++rr)
        outT[(size_t)(c0 + rl + rr * 4) * R + r0 + cl] = f2bf(t[cl][rl + rr * 4]);
}

// ---------------------------------------------------------------------------
// Wqkv [H][D][192] fp32 -> Wq2T bf16 [3072][1024] (row n=h*192+e, col k=d).
// ---------------------------------------------------------------------------
__global__ __launch_bounds__(256) void repack_wqkv_bf16_kernel(
    const float* __restrict__ Wqkv, unsigned short* __restrict__ Wq2T) {
    __shared__ float t[64][65];
    const int h = blockIdx.z;
    const int d0 = blockIdx.y * 64, e0 = blockIdx.x * 64;
    const int cl = threadIdx.x & 63, rl = threadIdx.x >> 6;
#pragma unroll
    for (int rr = 0; rr < 16; ++rr)
        t[rl + rr * 4][cl] =
            Wqkv[((size_t)h * DD + d0 + rl + rr * 4) * 192 + e0 + cl];
    __syncthreads();
#pragma unroll
    for (int rr = 0; rr < 16; ++rr)
        Wq2T[((size_t)h * 192 + e0 + rl + rr * 4) * DD + d0 + cl] =
            f2bf(t[cl][rl + rr * 4]);
}

__global__ __launch_bounds__(256) void f2bf_kernel(
    const float* __restrict__ in, unsigned short* __restrict__ out, int n) {
    int i = blockIdx.x * 256 + threadIdx.x;
    if (i < n) out[i] = f2bf(in[i]);
}

// ---------------------------------------------------------------------------
// Shared staging / fragment helpers (k-chunk XOR swizzle: chunk c of local
// row r holds global chunk c^(r&7); reads apply the same XOR).
// ---------------------------------------------------------------------------
// 128 local rows (2 gl_lds/thread). RS=6: 64-row stripes; RS=5: 32-row stripes.
template <int RS>
__device__ __forceinline__ void stage_half(const unsigned short* __restrict__ G,
                                           int ldK, int growbase, int kbase,
                                           unsigned short* lbase, int tid) {
#pragma unroll
    for (int s = 0; s < 2; ++s) {
        const int c16 = s * 512 + tid;           // 16B chunk id in half-tile
        const int r = c16 >> 3, c = c16 & 7;     // local row, chunk-in-row
        const int grow =
            growbase + ((r >> RS) << (RS + 1)) + (r & ((1 << RS) - 1));
        const int gcol = kbase + ((c ^ (r & 7)) << 3);
        gl_lds16(&G[(size_t)grow * ldK + gcol], &lbase[c16 << 3]);
    }
}

// 64 local rows (1 gl_lds/thread), 32-row stripes.
__device__ __forceinline__ void stage_64(const unsigned short* __restrict__ G,
                                         int ldK, int growbase, int kbase,
                                         unsigned short* lbase, int tid) {
    const int r = tid >> 3, c = tid & 7;
    const int grow = growbase + ((r >> 5) << 6) + (r & 31);
    const int gcol = kbase + ((c ^ (r & 7)) << 3);
    gl_lds16(&G[(size_t)grow * ldK + gcol], &lbase[tid << 3]);
}

// 64x64 bf16 tile, arbitrary src row stride (for attention K / V^T tiles):
// 2 gl_lds/thread at 256 threads; local rows in natural order.
__device__ __forceinline__ void stage_kv(const unsigned short* __restrict__ src,
                                         size_t rstride, unsigned short* dst,
                                         int tid) {
#pragma unroll
    for (int s = 0; s < 2; ++s) {
        const int c16 = s * 256 + tid;
        const int r = c16 >> 3, c = c16 & 7;
        gl_lds16(&src[(size_t)r * rstride + ((c ^ (r & 7)) << 3)],
                 &dst[c16 << 3]);
    }
}

// ---------------------------------------------------------------------------
// 256x256-tile, BK=64, 8-wave, 8-phase software-pipelined bf16 MFMA GEMM.
// (used for MLP-up, MODE 2). Per wave (wm=wave>>2, wn=wave&3): 128x64 output.
// vmcnt(6) at ph4/ph8 only. MODE 2: bf16 out = gelu_tanh(C+bias) LDS repack.
// ---------------------------------------------------------------------------
__device__ __forceinline__ void read_afrag(const unsigned short* s, int base,
                                           int wm, int l15, int g,
                                           bf16x8 af[4][2]) {
#pragma unroll
    for (int ii = 0; ii < 4; ++ii) {
        const int lr = wm * 64 + ii * 16 + l15;
#pragma unroll
        for (int ks = 0; ks < 2; ++ks) {
            const int p = ((ks << 2) + g) ^ (lr & 7);
            af[ii][ks] = __builtin_bit_cast(
                bf16x8, *(const u16x8*)&s[base + lr * 64 + p * 8]);
        }
    }
}

__device__ __forceinline__ void read_bfrag(const unsigned short* s, int base,
                                           int wn, int l15, int g,
                                           bf16x8 bf2[2][2]) {
#pragma unroll
    for (int jj = 0; jj < 2; ++jj) {
        const int lr = wn * 32 + jj * 16 + l15;
#pragma unroll
        for (int ks = 0; ks < 2; ++ks) {
            const int p = ((ks << 2) + g) ^ (lr & 7);
            bf2[jj][ks] = __builtin_bit_cast(
                bf16x8, *(const u16x8*)&s[base + lr * 64 + p * 8]);
        }
    }
}

template <int MH, int NH>
__device__ __forceinline__ void mfma_quad(f32x4 acc[8][4],
                                          const bf16x8 af[4][2],
                                          const bf16x8 bf2[2][2]) {
    __builtin_amdgcn_s_setprio(1);
#pragma unroll
    for (int ks = 0; ks < 2; ++ks)
#pragma unroll
        for (int ii = 0; ii < 4; ++ii)
#pragma unroll
            for (int jj = 0; jj < 2; ++jj)
                acc[MH * 4 + ii][NH * 2 + jj] =
                    __builtin_amdgcn_mfma_f32_16x16x32_bf16(
                        af[ii][ks], bf2[jj][ks],
                        acc[MH * 4 + ii][NH * 2 + jj], 0, 0, 0);
    __builtin_amdgcn_s_setprio(0);
}

template <int MODE>
__global__ __launch_bounds__(512) void mfma_gemm256_kernel(
    const unsigned short* __restrict__ A, const unsigned short* __restrict__ BT,
    float* __restrict__ Cf, unsigned short* __restrict__ Cb,
    const float* __restrict__ bias, const float* __restrict__ resid,
    int M, int N, int K) {
    __shared__ __align__(16) unsigned short smem[65536];  // 128 KiB
    const int tid = threadIdx.x;
    const int lane = tid & 63, wave = tid >> 6;
    const int wm = wave >> 2, wn = wave & 3;
    const int l15 = lane & 15, g = lane >> 4;

    const int gx = gridDim.x, nwg = gx * gridDim.y;
    const int lid = blockIdx.y * gx + blockIdx.x;
    const int swz = ((nwg & 7) == 0) ? ((lid & 7) * (nwg >> 3) + (lid >> 3))
                                     : lid;
    const int row0 = (swz / gx) * 256;
    const int col0 = (swz % gx) * 256;

    const int kt = K >> 6;

    f32x4 acc[8][4] = {};

    stage_half<6>(A, K, row0, 0, smem + 0, tid);           // T0 A h0
    stage_half<6>(A, K, row0 + 64, 0, smem + 8192, tid);   // T0 A h1
    stage_half<5>(BT, K, col0, 0, smem + 32768, tid);      // T0 B h0
    stage_half<5>(BT, K, col0 + 32, 0, smem + 40960, tid); // T0 B h1
    VMCNT(4);
    stage_half<6>(A, K, row0, 64, smem + 16384, tid);      // T1 A h0
    stage_half<6>(A, K, row0 + 64, 64, smem + 24576, tid); // T1 A h1
    stage_half<5>(BT, K, col0, 64, smem + 49152, tid);     // T1 B h0
    VMCNT(6);
    GBAR();

    bf16x8 af[4][2], bf0[2][2], bf1[2][2];
    for (int it = 0; it < (kt >> 1); ++it) {
        const int t1k = (2 * it + 1) << 6;
        int t2 = 2 * it + 2; if (t2 > kt - 1) t2 = kt - 1;
        int t3 = 2 * it + 3; if (t3 > kt - 1) t3 = kt - 1;
        const int t2k = t2 << 6, t3k = t3 << 6;

        read_afrag(smem, 0, wm, l15, g, af);
        read_bfrag(smem, 32768, wn, l15, g, bf0);
        stage_half<5>(BT, K, col0 + 32, t1k, smem + 57344, tid);
        GBAR();
        mfma_quad<0, 0>(acc, af, bf0);
        GBAR();

        read_bfrag(smem, 40960, wn, l15, g, bf1);
        stage_half<6>(A, K, row0, t2k, smem + 0, tid);
        GBAR();
        mfma_quad<0, 1>(acc, af, bf1);
        GBAR();

        read_afrag(smem, 8192, wm, l15, g, af);
        stage_half<5>(BT, K, col0, t2k, smem + 32768, tid);
        GBAR();
        mfma_quad<1, 1>(acc, af, bf1);
        GBAR();

        stage_half<6>(A, K, row0 + 64, t2k, smem + 8192, tid);
        GBAR();
        mfma_quad<1, 0>(acc, af, bf0);
        VMCNT(6);
        GBAR();

        read_afrag(smem, 16384, wm, l15, g, af);
        read_bfrag(smem, 49152, wn, l15, g, bf0);
        stage_half<5>(BT, K, col0 + 32, t2k, smem + 40960, tid);
        GBAR();
        mfma_quad<0, 0>(acc, af, bf0);
        GBAR();

        read_bfrag(smem, 57344, wn, l15, g, bf1);
        stage_half<6>(A, K, row0, t3k, smem + 16384, tid);
        GBAR();
        mfma_quad<0, 1>(acc, af, bf1);
        GBAR();

        read_afrag(smem, 24576, wm, l15, g, af);
        stage_half<5>(BT, K, col0, t3k, smem + 49152, tid);
        GBAR();
        mfma_quad<1, 1>(acc, af, bf1);
        GBAR();

        stage_half<6>(A, K, row0 + 64, t3k, smem + 24576, tid);
        GBAR();
        mfma_quad<1, 0>(acc, af, bf0);
        VMCNT(6);
        GBAR();
    }
    VMCNT(0);
    GBAR();

    if (MODE == 2) {
        constexpr int SLAB = 264;  // 32 x 256 bf16 slab, padded stride
#pragma unroll
        for (int i2 = 0; i2 < 8; ++i2) {
            __syncthreads();
#pragma unroll
            for (int j2 = 0; j2 < 4; ++j2) {
                const int col = wn * 64 + j2 * 16 + l15;
                const float bv = bias[col0 + col];
#pragma unroll
                for (int r = 0; r < 4; ++r) {
                    float v = acc[i2][j2][r] + bv;
                    // gelu_tanh: v * t/(t+1), t = 2^(v*(2.302118+0.102942 v^2))
                    float t = fexp2(v * (2.30211849f + 0.10294198f * v * v));
                    float gel = v * t * __builtin_amdgcn_rcpf(t + 1.f);
                    smem[(wm * 16 + g * 4 + r) * SLAB + col] = f2bf(gel);
                }
            }
            __syncthreads();
            const int sr = tid >> 4;           // 0..31 slab row
            const int cc = (tid & 15) * 16;    // col base
            const int grow = row0 + ((sr >> 4) << 7) + i2 * 16 + (sr & 15);
            *(u16x8*)&Cb[(size_t)grow * N + col0 + cc] =
                *(const u16x8*)&smem[sr * SLAB + cc];
            *(u16x8*)&Cb[(size_t)grow * N + col0 + cc + 8] =
                *(const u16x8*)&smem[sr * SLAB + cc + 8];
        }
        return;
    }

#pragma unroll
    for (int i2 = 0; i2 < 8; ++i2) {
#pragma unroll
        for (int j2 = 0; j2 < 4; ++j2) {
            const int col = col0 + wn * 64 + j2 * 16 + l15;
            const int rowb = row0 + wm * 128 + i2 * 16 + g * 4;
            const float bv = bias[col];
#pragma unroll
            for (int r = 0; r < 4; ++r) {
                const int row = rowb + r;
                float v = acc[i2][j2][r] + bv + resid[(size_t)row * N + col];
                Cf[(size_t)row * N + col] = v;
            }
        }
    }
}

// ---------------------------------------------------------------------------
// 256x128-tile, BK=64, 8-wave (4M x 2N), 8-phase GEMM — for N=1024/3072 cases
// where a 256x256 grid under-fills the 256 CUs. vmcnt(5) at ph4/ph8.
// MODE 3: fp32 C+bias+resid. MODE 4: QKV scatter.
// ---------------------------------------------------------------------------
__device__ __forceinline__ void read_af128(const unsigned short* s, int base,
                                           int wm, int l15, int g,
                                           bf16x8 af[2][2]) {
#pragma unroll
    for (int ii = 0; ii < 2; ++ii) {
        const int lr = wm * 32 + ii * 16 + l15;
#pragma unroll
        for (int ks = 0; ks < 2; ++ks) {
            const int p = ((ks << 2) + g) ^ (lr & 7);
            af[ii][ks] = __builtin_bit_cast(
                bf16x8, *(const u16x8*)&s[base + lr * 64 + p * 8]);
        }
    }
}

__device__ __forceinline__ void read_bf128(const unsigned short* s, int base,
                                           int wn, int l15, int g,
                                           bf16x8 bf2[2][2]) {
#pragma unroll
    for (int jj = 0; jj < 2; ++jj) {
        const int lr = wn * 32 + jj * 16 + l15;
#pragma unroll
        for (int ks = 0; ks < 2; ++ks) {
            const int p = ((ks << 2) + g) ^ (lr & 7);
            bf2[jj][ks] = __builtin_bit_cast(
                bf16x8, *(const u16x8*)&s[base + lr * 64 + p * 8]);
        }
    }
}

template <int MH, int NH>
__device__ __forceinline__ void mfma_quad128(f32x4 acc[4][4],
                                             const bf16x8 af[2][2],
                                             const bf16x8 bf2[2][2]) {
    __builtin_amdgcn_s_setprio(1);
#pragma unroll
    for (int ks = 0; ks < 2; ++ks)
#pragma unroll
        for (int ii = 0; ii < 2; ++ii)
#pragma unroll
            for (int jj = 0; jj < 2; ++jj)
                acc[MH * 2 + ii][NH * 2 + jj] =
                    __builtin_amdgcn_mfma_f32_16x16x32_bf16(
                        af[ii][ks], bf2[jj][ks],
                        acc[MH * 2 + ii][NH * 2 + jj], 0, 0, 0);
    __builtin_amdgcn_s_setprio(0);
}

template <int MODE>
__global__ __launch_bounds__(512) void gemm_n128_kernel(
    const unsigned short* __restrict__ A, const unsigned short* __restrict__ BT,
    float* __restrict__ Cf, const float* __restrict__ bias,
    const float* __restrict__ resid, unsigned short* __restrict__ Qb,
    unsigned short* __restrict__ Kb, unsigned short* __restrict__ VTb,
    int M, int N, int K) {
    __shared__ __align__(16) unsigned short smem[49152];  // 96 KiB
    const int tid = threadIdx.x;
    const int lane = tid & 63, wave = tid >> 6;
    const int wm = wave >> 1, wn = wave & 1;
    const int l15 = lane & 15, g = lane >> 4;

    const int gx = gridDim.x, nwg = gx * gridDim.y;
    const int lid = blockIdx.y * gx + blockIdx.x;
    const int swz = ((nwg & 7) == 0) ? ((lid & 7) * (nwg >> 3) + (lid >> 3))
                                     : lid;
    const int row0 = (swz / gx) * 256;
    const int col0 = (swz % gx) * 128;

    const int kt = K >> 6;

    f32x4 acc[4][4] = {};

    stage_half<5>(A, K, row0, 0, smem + 0, tid);            // T0 A h0 (2)
    stage_half<5>(A, K, row0 + 32, 0, smem + 8192, tid);    // T0 A h1 (2)
    stage_64(BT, K, col0, 0, smem + 32768, tid);            // T0 B h0 (1)
    stage_64(BT, K, col0 + 32, 0, smem + 36864, tid);       // T0 B h1 (1)
    VMCNT(4);
    stage_half<5>(A, K, row0, 64, smem + 16384, tid);       // T1 A h0 (2)
    stage_half<5>(A, K, row0 + 32, 64, smem + 24576, tid);  // T1 A h1 (2)
    stage_64(BT, K, col0, 64, smem + 40960, tid);           // T1 B h0 (1)
    VMCNT(5);   // T0's 6 loads done; T1's 5 in flight
    GBAR();

    bf16x8 af[2][2], bf0[2][2], bf1[2][2];
    for (int it = 0; it < (kt >> 1); ++it) {
        const int t1k = (2 * it + 1) << 6;
        int t2 = 2 * it + 2; if (t2 > kt - 1) t2 = kt - 1;   // clamped
        int t3 = 2 * it + 3; if (t3 > kt - 1) t3 = kt - 1;   // (junk re-stage,
        const int t2k = t2 << 6, t3k = t3 << 6;              //  dest dead)

        read_af128(smem, 0, wm, l15, g, af);
        read_bf128(smem, 32768, wn, l15, g, bf0);
        stage_64(BT, K, col0 + 32, t1k, smem + 45056, tid);
        GBAR();
        mfma_quad128<0, 0>(acc, af, bf0);
        GBAR();

        read_bf128(smem, 36864, wn, l15, g, bf1);
        stage_half<5>(A, K, row0, t2k, smem + 0, tid);
        GBAR();
        mfma_quad128<0, 1>(acc, af, bf1);
        GBAR();

        read_af128(smem, 8192, wm, l15, g, af);
        stage_64(BT, K, col0, t2k, smem + 32768, tid);
        GBAR();
        mfma_quad128<1, 1>(acc, af, bf1);
        GBAR();

        stage_half<5>(A, K, row0 + 32, t2k, smem + 8192, tid);
        GBAR();
        mfma_quad128<1, 0>(acc, af, bf0);
        VMCNT(5);
        GBAR();

        read_af128(smem, 16384, wm, l15, g, af);
        read_bf128(smem, 40960, wn, l15, g, bf0);
        stage_64(BT, K, col0 + 32, t2k, smem + 36864, tid);
        GBAR();
        mfma_quad128<0, 0>(acc, af, bf0);
        GBAR();

        read_bf128(smem, 45056, wn, l15, g, bf1);
        stage_half<5>(A, K, row0, t3k, smem + 16384, tid);
        GBAR();
        mfma_quad128<0, 1>(acc, af, bf1);
        GBAR();

        read_af128(smem, 24576, wm, l15, g, af);
        stage_64(BT, K, col0, t3k, smem + 40960, tid);
        GBAR();
        mfma_quad128<1, 1>(acc, af, bf1);
        GBAR();

        stage_half<5>(A, K, row0 + 32, t3k, smem + 24576, tid);
        GBAR();
        mfma_quad128<1, 0>(acc, af, bf0);
        VMCNT(5);
        GBAR();
    }
    VMCNT(0);  // drain junk prefetches before exit
    GBAR();

#pragma unroll
    for (int i2 = 0; i2 < 4; ++i2) {
#pragma unroll
        for (int j2 = 0; j2 < 4; ++j2) {
            const int col = col0 + wn * 64 + j2 * 16 + l15;
            const int rowb = row0 + wm * 64 + i2 * 16 + g * 4;
            if (MODE == 4) {
                const int h = col / 192, e = col % 192;
                const int bb = rowb >> 11, s = rowb & 2047;
                if (e < 64) {
                    unsigned short* q =
                        Qb + (((size_t)bb * HH + h) * SS + s) * 64 + e;
#pragma unroll
                    for (int r = 0; r < 4; ++r)
                        q[r * 64] = f2bf(acc[i2][j2][r] * 0.18033688f);
                } else if (e < 128) {
                    unsigned short* kp =
                        Kb + (((size_t)bb * HH + h) * SS + s) * 64 + (e - 64);
#pragma unroll
                    for (int r = 0; r < 4; ++r)
                        kp[r * 64] = f2bf(acc[i2][j2][r]);
                } else {
                    ushort4 pk;
                    pk.x = f2bf(acc[i2][j2][0]);
                    pk.y = f2bf(acc[i2][j2][1]);
                    pk.z = f2bf(acc[i2][j2][2]);
                    pk.w = f2bf(acc[i2][j2][3]);
                    *(ushort4*)(VTb + (((size_t)bb * HH + h) * 64 + (e - 128)) *
                                          SS + s) = pk;
                }
            } else {
                const float bv = bias[col];
#pragma unroll
                for (int r = 0; r < 4; ++r) {
                    const int row = rowb + r;
                    float v = acc[i2][j2][r] + bv + resid[(size_t)row * N + col];
                    Cf[(size_t)row * N + col] = v;
                }
            }
        }
    }
}

// ---------------------------------------------------------------------------
// Flash causal attention, transposed-score formulation, exp2 domain
// (Q pre-scaled by 0.125*log2e in the QKV epilogue).
// S^T = K Q^T; softmax per q-col (2 shuffles); O^T = V^T P^T.
// Block: 128 q of one (b,h); 4 waves x 32 q; kv tiles of 64.
// K/V double-buffered via global_load_lds (XOR k-chunk swizzle, conflict-free
// b128 reads); tile t+1 prefetched during tile t compute; vmcnt(4) counted.
// 2 barriers/tile. P/Q LDS rows are wave-private: no barriers around them.
// Defer-max (bit-exact, THR=0): skip O-rescale when __all(mx <= mst).
// ---------------------------------------------------------------------------
__global__ __launch_bounds__(256) void fattn_kernel(
    const unsigned short* __restrict__ Qb, const unsigned short* __restrict__ Kb,
    const unsigned short* __restrict__ VTb, unsigned short* __restrict__ att) {
    constexpr int PSTR = 68;
    __shared__ __align__(16) unsigned short Pls[128 * PSTR];
    __shared__ __align__(16) unsigned short Kls[2][64 * 64];
    __shared__ __align__(16) unsigned short VTls[2][64 * 64];

    const int bh = blockIdx.x;
    const int q0 = blockIdx.y * 128;
    const int tid = threadIdx.x;
    const int lane = tid & 63;
    const int wave = tid >> 6;
    const int l15 = lane & 15;
    const int g = lane >> 4;
    const int b = bh >> 4, h = bh & 15;

    const unsigned short* Qh = Qb + (size_t)bh * SS * 64;
    const unsigned short* Kh = Kb + (size_t)bh * SS * 64;
    const unsigned short* Vh = VTb + (size_t)bh * 64 * SS;

    // ---- stage Q tile (rows are wave-private: tid>>1 in [wave*32,wave*32+32))
    {
        const int row = tid >> 1, c0 = (tid & 1) * 32;
        const unsigned short* src = Qh + (size_t)(q0 + row) * 64 + c0;
        unsigned short* dst = &Pls[row * PSTR + c0];
#pragma unroll
        for (int c = 0; c < 32; c += 8)
            *(u16x8*)(dst + c) = *(const u16x8*)(src + c);
    }
    bf16x8 qf[2][2];   // B-frag: [n=q=l15][k=dh]
#pragma unroll
    for (int i = 0; i < 2; ++i)
#pragma unroll
        for (int ks = 0; ks < 2; ++ks)
            qf[i][ks] = __builtin_bit_cast(
                bf16x8, *(const u16x8*)&Pls[(wave * 32 + i * 16 + l15) * PSTR +
                                            ks * 32 + g * 8]);
    // Pls Q region now dead; reused for P^T (also wave-private rows).

    f32x4 oacc[4][2] = {};          // O^T tiles: [jo=dh][i=q]
    float mst[2], lst[2];
#pragma unroll
    for (int i = 0; i < 2; ++i) { mst[i] = -1e30f; lst[i] = 0.f; }

    const int qlim = q0 + wave * 32 + 31;
    const int qrow = wave * 32 + l15;
    const int nt = (q0 >> 6) + 2;
    const int xh = l15 & 7;          // row-XOR for K/V fragment reads

    // prologue: stage tile 0 into buf 0 (4 gl_lds/thread)
    stage_kv(Kh, 64, &Kls[0][0], tid);
    stage_kv(Vh, SS, &VTls[0][0], tid);

    for (int t = 0; t < nt; ++t) {
        const int t0 = t << 6;
        const int tn = (t + 1 < nt) ? t + 1 : nt - 1;  // last iter: junk re-stage
        stage_kv(Kh + (size_t)(tn << 6) * 64, 64, &Kls[(t + 1) & 1][0], tid);
        stage_kv(Vh + (tn << 6), SS, &VTls[(t + 1) & 1][0], tid);
        VMCNT(4);   // tile t resident; tile t+1's 4 in flight
        GBAR();

        if (t0 <= qlim) {
            const unsigned short* Kt = &Kls[t & 1][0];
            const unsigned short* Vt = &VTls[t & 1][0];

            // ---- S^T = K Q^T ----
            f32x4 sacc[4][2] = {};
#pragma unroll
            for (int ks = 0; ks < 2; ++ks) {
                const int ko = ((((ks << 2) + g) ^ xh) << 3);
                bf16x8 kb[4];
#pragma unroll
                for (int j = 0; j < 4; ++j)
                    kb[j] = __builtin_bit_cast(
                        bf16x8, *(const u16x8*)&Kt[(j * 16 + l15) * 64 + ko]);
#pragma unroll
                for (int j = 0; j < 4; ++j)
#pragma unroll
                    for (int i = 0; i < 2; ++i)
                        sacc[j][i] = __builtin_amdgcn_mfma_f32_16x16x32_bf16(
                            kb[j], qf[i][ks], sacc[j][i], 0, 0, 0);
            }

            // ---- causal mask ----
            if (t0 >= q0) {
#pragma unroll
                for (int j = 0; j < 4; ++j)
#pragma unroll
                    for (int i = 0; i < 2; ++i)
#pragma unroll
                        for (int r = 0; r < 4; ++r) {
                            const int kg = t0 + j * 16 + g * 4 + r;
                            const int qg = q0 + qrow + i * 16;
                            if (kg > qg) sacc[j][i][r] = -1e30f;
                        }
            }

            // ---- online softmax (exp2 domain); P^T -> Pls[q][kv] ----
#pragma unroll
            for (int i = 0; i < 2; ++i) {
                float mx = -1e30f;
#pragma unroll
                for (int j = 0; j < 4; ++j)
                    mx = fmaxf(mx,
                               fmaxf(fmaxf(sacc[j][i][0], sacc[j][i][1]),
                                     fmaxf(sacc[j][i][2], sacc[j][i][3])));
                mx = fmaxf(mx, __shfl_xor(mx, 16));
                mx = fmaxf(mx, __shfl_xor(mx, 32));
                // defer-max (bit-exact): if no lane's max grew, al==1 exactly.
                const bool grow = !__all(mx <= mst[i]);
                float al = 1.f;
                if (grow) {
                    const float mn = fmaxf(mst[i], mx);
                    al = fexp2(mst[i] - mn);
                    mst[i] = mn;
                }
                const float mm = mst[i];
                float rsum = 0.f;
                const int pbase = (qrow + i * 16) * PSTR + g * 4;
#pragma unroll
                for (int j = 0; j < 4; ++j) {
                    float p0 = fexp2(sacc[j][i][0] - mm);
                    float p1 = fexp2(sacc[j][i][1] - mm);
                    float p2 = fexp2(sacc[j][i][2] - mm);
                    float p3 = fexp2(sacc[j][i][3] - mm);
                    rsum += (p0 + p1) + (p2 + p3);
                    ushort4 pk;
                    pk.x = f2bf(p0); pk.y = f2bf(p1);
                    pk.z = f2bf(p2); pk.w = f2bf(p3);
                    *(ushort4*)&Pls[pbase + j * 16] = pk;
                }
                rsum += __shfl_xor(rsum, 16);
                rsum += __shfl_xor(rsum, 32);
                if (grow) {
                    lst[i] = lst[i] * al + rsum;
#pragma unroll
                    for (int jo = 0; jo < 4; ++jo)
#pragma unroll
                        for (int r = 0; r < 4; ++r) oacc[jo][i][r] *= al;
                } else {
                    lst[i] += rsum;
                }
            }

            // ---- O^T += V^T P^T (P rows wave-private; no barrier) ----
#pragma unroll
            for (int ks = 0; ks < 2; ++ks) {
                const int ko = ((((ks << 2) + g) ^ xh) << 3);
                bf16x8 vb[4], pf[2];
#pragma unroll
                for (int jo = 0; jo < 4; ++jo)
                    vb[jo] = __builtin_bit_cast(
                        bf16x8, *(const u16x8*)&Vt[(jo * 16 + l15) * 64 + ko]);
#pragma unroll
                for (int i = 0; i < 2; ++i)
                    pf[i] = __builtin_bit_cast(
                        bf16x8, *(const u16x8*)&Pls[(qrow + i * 16) * PSTR +
                                                    ks * 32 + g * 8]);
#pragma unroll
                for (int jo = 0; jo < 4; ++jo)
#pragma unroll
                    for (int i = 0; i < 2; ++i)
                        oacc[jo][i] = __builtin_amdgcn_mfma_f32_16x16x32_bf16(
                            vb[jo], pf[i], oacc[jo][i], 0, 0, 0);
            }
        }
        GBAR();   // compute reads of buf[t&1] done before next overwrite
    }
    VMCNT(0);   // drain tail junk prefetches

    // ---- epilogue: O^T/l -> att[b, q, h*64+dh], packed ushort4 ----
#pragma unroll
    for (int i = 0; i < 2; ++i) {
        const float inv = 1.f / lst[i];
        const int qg = q0 + qrow + i * 16;
        unsigned short* dst = att + ((size_t)b * SS + qg) * DD + h * 64 + g * 4;
#pragma unroll
        for (int jo = 0; jo < 4; ++jo) {
            ushort4 pk;
            pk.x = f2bf(oacc[jo][i][0] * inv);
            pk.y = f2bf(oacc[jo][i][1] * inv);
            pk.z = f2bf(oacc[jo][i][2] * inv);
            pk.w = f2bf(oacc[jo][i][3] * inv);
            *(ushort4*)(dst + jo * 16) = pk;
        }
    }
}

// ---------------------------------------------------------------------------
// LayerNorm over D=1024; optional bf16 copy. In-place safe.
// ---------------------------------------------------------------------------
__global__ __launch_bounds__(256) void ln_kernel(
    const float* __restrict__ X, const float* __restrict__ g,
    const float* __restrict__ bta, float* __restrict__ Y,
    unsigned short* __restrict__ Yb) {
    const int row = blockIdx.x;
    const float4 xv = ((const float4*)(X + (size_t)row * DD))[threadIdx.x];

    __shared__ float red1[4], red2[4];
    float s = xv.x + xv.y + xv.z + xv.w;
#pragma unroll
    for (int off = 32; off > 0; off >>= 1) s += __shfl_down(s, off);
    const int wave = threadIdx.x >> 6;
    if ((threadIdx.x & 63) == 0) red1[wave] = s;
    __syncthreads();
    const float mu = (red1[0] + red1[1] + red1[2] + red1[3]) * (1.f / DD);

    float dx = xv.x - mu, dy = xv.y - mu, dz = xv.z - mu, dw = xv.w - mu;
    float s2 = dx * dx + dy * dy + dz * dz + dw * dw;
#pragma unroll
    for (int off = 32; off > 0; off >>= 1) s2 += __shfl_down(s2, off);
    if ((threadIdx.x & 63) == 0) red2[wave] = s2;
    __syncthreads();
    const float var = (red2[0] + red2[1] + red2[2] + red2[3]) * (1.f / DD);
    const float rstd = rsqrtf(var + LN_EPS);

    const float4 gv = ((const float4*)g)[threadIdx.x];
    const float4 bv = ((const float4*)bta)[threadIdx.x];
    float4 yv;
    yv.x = dx * rstd * gv.x + bv.x;
    yv.y = dy * rstd * gv.y + bv.y;
    yv.z = dz * rstd * gv.z + bv.z;
    yv.w = dw * rstd * gv.w + bv.w;
    ((float4*)(Y + (size_t)row * DD))[threadIdx.x] = yv;
    if (Yb) {
        ushort4 q;
        q.x = f2bf(yv.x); q.y = f2bf(yv.y);
        q.z = f2bf(yv.z); q.w = f2bf(yv.w);
        ((ushort4*)(Yb + (size_t)row * DD))[threadIdx.x] = q;
    }
}

// ---------------------------------------------------------------------------
// Workspace (byte offsets, peak 144 MB):
//   [0,16M)    Qb bf16 (ph2-3) -> out1b bf16 (ph5+)
//   [16M,32M)  Kb; [32M,48M) VTb (ph2-3) -> hbuf bf16 [16M,80M) (ph6-7)
//   [96M,102M) Wq2T; [102M,118M) xb (ph1-2)
//   [96M,112M) att bf16 (ph3-4); [96M,128M) out1 fp32 (ph5-7)
//   [118M,120M) WprojT; [128M,136M) W1T; [136M,144M) W2T
// ---------------------------------------------------------------------------
extern "C" void kernel_launch(void* const* d_in, const int* in_sizes, int n_in,
                              void* d_out, int out_size, void* d_ws,
                              size_t ws_size, hipStream_t stream) {
    const float* x     = (const float*)d_in[0];
    const float* Wqkv  = (const float*)d_in[1];
    const float* Wproj = (const float*)d_in[2];
    const float* bproj = (const float*)d_in[3];
    const float* ln1_g = (const float*)d_in[4];
    const float* ln1_b = (const float*)d_in[5];
    const float* ln2_g = (const float*)d_in[6];
    const float* ln2_b = (const float*)d_in[7];
    const float* W1    = (const float*)d_in[8];
    const float* b1    = (const float*)d_in[9];
    const float* W2    = (const float*)d_in[10];
    const float* b2    = (const float*)d_in[11];
    float* out = (float*)d_out;

    const size_t M = (size_t)BB * SS;     // 8192
    const size_t MB = 1024 * 1024;
    char* w = (char*)d_ws;
    unsigned short* Qb     = (unsigned short*)(w + 0);
    unsigned short* out1b  = (unsigned short*)(w + 0);
    unsigned short* Kb     = (unsigned short*)(w + 16 * MB);
    unsigned short* VTb    = (unsigned short*)(w + 32 * MB);
    unsigned short* hbuf   = (unsigned short*)(w + 16 * MB);
    unsigned short* Wq2T   = (unsigned short*)(w + 96 * MB);
    unsigned short* xb     = (unsigned short*)(w + 102 * MB);
    unsigned short* att    = (unsigned short*)(w + 96 * MB);
    float*          out1   = (float*)(w + 96 * MB);
    unsigned short* WprojT = (unsigned short*)(w + 118 * MB);
    unsigned short* W1T    = (unsigned short*)(w + 128 * MB);
    unsigned short* W2T    = (unsigned short*)(w + 136 * MB);

    // 1. weight/input conversions
    repack_wqkv_bf16_kernel<<<dim3(3, 16, 16), 256, 0, stream>>>(Wqkv, Wq2T);
    transpose_bf16_kernel<<<dim3(16, 16), 256, 0, stream>>>(Wproj, WprojT, 1024, 1024);
    transpose_bf16_kernel<<<dim3(64, 16), 256, 0, stream>>>(W1, W1T, 1024, 4096);
    transpose_bf16_kernel<<<dim3(16, 64), 256, 0, stream>>>(W2, W2T, 4096, 1024);
    f2bf_kernel<<<(int)((M * DD + 255) / 256), 256, 0, stream>>>(x, xb, (int)(M * DD));

    // 2. QKV GEMM -> flash layouts Qb/Kb/VTb (bf16, Q in exp2 domain)
    gemm_n128_kernel<4><<<dim3(3072 / 128, M / 256), 512, 0, stream>>>(
        xb, Wq2T, nullptr, nullptr, nullptr, Qb, Kb, VTb, (int)M, 3072, 1024);

    // 3. flash causal attention -> att bf16
    fattn_kernel<<<dim3(BB * HH, SS / 128), 256, 0, stream>>>(Qb, Kb, VTb, att);

    // 4. proj GEMM + bias + residual(x) -> d_out fp32
    gemm_n128_kernel<3><<<dim3(1024 / 128, M / 256), 512, 0, stream>>>(
        att, WprojT, out, bproj, x, nullptr, nullptr, nullptr,
        (int)M, 1024, 1024);

    // 5. LN1 -> out1 fp32 + out1b bf16
    ln_kernel<<<(int)M, 256, 0, stream>>>(out, ln1_g, ln1_b, out1, out1b);

    // 6. MLP up + GELU -> hbuf bf16
    mfma_gemm256_kernel<2><<<dim3(4096 / 256, M / 256), 512, 0, stream>>>(
        out1b, W1T, nullptr, hbuf, b1, nullptr, (int)M, 4096, 1024);

    // 7. MLP down + bias + residual(out1) -> d_out fp32
    gemm_n128_kernel<3><<<dim3(1024 / 128, M / 256), 512, 0, stream>>>(
        hbuf, W2T, out, b2, out1, nullptr, nullptr, nullptr,
        (int)M, 1024, 4096);

    // 8. LN2 in-place on d_out
    ln_kernel<<<(int)M, 256, 0, stream>>>(out, ln2_g, ln2_b, out, nullptr);
}

// Round 4
// 497.089 us; speedup vs baseline: 1.1779x; 1.0164x over previous
//
#include <hip/hip_runtime.h>
#include <math.h>

#define BB 4
#define SS 2048
#define DD 1024
#define HH 16
#define DHH 64
#define DFF 4096
static constexpr float LN_EPS = 1e-5f;

typedef __bf16 bf16x8 __attribute__((ext_vector_type(8)));
typedef float f32x4 __attribute__((ext_vector_type(4)));
typedef unsigned short u16x8 __attribute__((ext_vector_type(8)));

// bf16 convert via HW RNE cvt (bit-identical to manual round-to-nearest-even).
__device__ __forceinline__ unsigned short f2bf(float f) {
    return __builtin_bit_cast(unsigned short, (__bf16)f);
}

// Fast 2^x via the gfx hardware exp2 (v_exp_f32).
__device__ __forceinline__ float fexp2(float x) {
    return __builtin_amdgcn_exp2f(x);
}

// Async global->LDS DMA, 16 B/lane; LDS dest = wave-uniform base + lane*16.
__device__ __forceinline__ void gl_lds16(const unsigned short* g,
                                         unsigned short* l) {
    __builtin_amdgcn_global_load_lds(
        (const __attribute__((address_space(1))) unsigned int*)g,
        (__attribute__((address_space(3))) unsigned int*)l, 16, 0, 0);
}

// Raw workgroup barrier with compiler memory fence (no vmcnt drain).
#define GBAR()                               \
    do {                                     \
        asm volatile("" ::: "memory");       \
        __builtin_amdgcn_s_barrier();        \
        asm volatile("" ::: "memory");       \
    } while (0)
#define VMCNT(n) asm volatile("s_waitcnt vmcnt(" #n ")" ::: "memory")

// ---------------------------------------------------------------------------
// fp32 [R][C] -> bf16 transposed [C][R]. 64x64 LDS tiles.
// ---------------------------------------------------------------------------
__global__ __launch_bounds__(256) void transpose_bf16_kernel(
    const float* __restrict__ in, unsigned short* __restrict__ outT,
    int R, int C) {
    __shared__ float t[64][65];
    const int r0 = blockIdx.y * 64, c0 = blockIdx.x * 64;
    const int cl = threadIdx.x & 63, rl = threadIdx.x >> 6;
#pragma unroll
    for (int rr = 0; rr < 16; ++rr)
        t[rl + rr * 4][cl] = in[(size_t)(r0 + rl + rr * 4) * C + c0 + cl];
    __syncthreads();
#pragma unroll
    for (int rr = 0; rr < 16; ++rr)
        outT[(size_t)(c0 + rl + rr * 4) * R + r0 + cl] = f2bf(t[cl][rl + rr * 4]);
}

// ---------------------------------------------------------------------------
// Wqkv [H][D][192] fp32 -> Wq2T bf16 [3072][1024] (row n=h*192+e, col k=d).
// ---------------------------------------------------------------------------
__global__ __launch_bounds__(256) void repack_wqkv_bf16_kernel(
    const float* __restrict__ Wqkv, unsigned short* __restrict__ Wq2T) {
    __shared__ float t[64][65];
    const int h = blockIdx.z;
    const int d0 = blockIdx.y * 64, e0 = blockIdx.x * 64;
    const int cl = threadIdx.x & 63, rl = threadIdx.x >> 6;
#pragma unroll
    for (int rr = 0; rr < 16; ++rr)
        t[rl + rr * 4][cl] =
            Wqkv[((size_t)h * DD + d0 + rl + rr * 4) * 192 + e0 + cl];
    __syncthreads();
#pragma unroll
    for (int rr = 0; rr < 16; ++rr)
        Wq2T[((size_t)h * 192 + e0 + rl + rr * 4) * DD + d0 + cl] =
            f2bf(t[cl][rl + rr * 4]);
}

__global__ __launch_bounds__(256) void f2bf_kernel(
    const float* __restrict__ in, unsigned short* __restrict__ out, int n) {
    int i = blockIdx.x * 256 + threadIdx.x;
    if (i < n) out[i] = f2bf(in[i]);
}

// ---------------------------------------------------------------------------
// Shared staging / fragment helpers (k-chunk XOR swizzle: chunk c of local
// row r holds global chunk c^(r&7); reads apply the same XOR).
// ---------------------------------------------------------------------------
// 128 local rows (2 gl_lds/thread at 512 thr). RS=6: 64-row stripes; RS=5: 32.
template <int RS>
__device__ __forceinline__ void stage_half(const unsigned short* __restrict__ G,
                                           int ldK, int growbase, int kbase,
                                           unsigned short* lbase, int tid) {
#pragma unroll
    for (int s = 0; s < 2; ++s) {
        const int c16 = s * 512 + tid;           // 16B chunk id in half-tile
        const int r = c16 >> 3, c = c16 & 7;     // local row, chunk-in-row
        const int grow =
            growbase + ((r >> RS) << (RS + 1)) + (r & ((1 << RS) - 1));
        const int gcol = kbase + ((c ^ (r & 7)) << 3);
        gl_lds16(&G[(size_t)grow * ldK + gcol], &lbase[c16 << 3]);
    }
}

// 64 local rows (1 gl_lds/thread at 512 thr), 32-row stripes.
__device__ __forceinline__ void stage_64(const unsigned short* __restrict__ G,
                                         int ldK, int growbase, int kbase,
                                         unsigned short* lbase, int tid) {
    const int r = tid >> 3, c = tid & 7;
    const int grow = growbase + ((r >> 5) << 6) + (r & 31);
    const int gcol = kbase + ((c ^ (r & 7)) << 3);
    gl_lds16(&G[(size_t)grow * ldK + gcol], &lbase[tid << 3]);
}

// 64x64 bf16 tile, arbitrary src row stride, natural row order
// (1 gl_lds/thread at 512 threads) — for attention K / V^T tiles.
__device__ __forceinline__ void stage_kv8(const unsigned short* __restrict__ src,
                                          size_t rstride, unsigned short* dst,
                                          int tid) {
    const int r = tid >> 3, c = tid & 7;
    gl_lds16(&src[(size_t)r * rstride + ((c ^ (r & 7)) << 3)], &dst[tid << 3]);
}

// ---------------------------------------------------------------------------
// 256x256-tile, BK=64, 8-wave, 8-phase software-pipelined bf16 MFMA GEMM.
// (used for MLP-up, MODE 2). Per wave (wm=wave>>2, wn=wave&3): 128x64 output.
// vmcnt(6) at ph4/ph8 only. MODE 2: bf16 out = gelu_tanh(C+bias) LDS repack.
// ---------------------------------------------------------------------------
__device__ __forceinline__ void read_afrag(const unsigned short* s, int base,
                                           int wm, int l15, int g,
                                           bf16x8 af[4][2]) {
#pragma unroll
    for (int ii = 0; ii < 4; ++ii) {
        const int lr = wm * 64 + ii * 16 + l15;
#pragma unroll
        for (int ks = 0; ks < 2; ++ks) {
            const int p = ((ks << 2) + g) ^ (lr & 7);
            af[ii][ks] = __builtin_bit_cast(
                bf16x8, *(const u16x8*)&s[base + lr * 64 + p * 8]);
        }
    }
}

__device__ __forceinline__ void read_bfrag(const unsigned short* s, int base,
                                           int wn, int l15, int g,
                                           bf16x8 bf2[2][2]) {
#pragma unroll
    for (int jj = 0; jj < 2; ++jj) {
        const int lr = wn * 32 + jj * 16 + l15;
#pragma unroll
        for (int ks = 0; ks < 2; ++ks) {
            const int p = ((ks << 2) + g) ^ (lr & 7);
            bf2[jj][ks] = __builtin_bit_cast(
                bf16x8, *(const u16x8*)&s[base + lr * 64 + p * 8]);
        }
    }
}

template <int MH, int NH>
__device__ __forceinline__ void mfma_quad(f32x4 acc[8][4],
                                          const bf16x8 af[4][2],
                                          const bf16x8 bf2[2][2]) {
    __builtin_amdgcn_s_setprio(1);
#pragma unroll
    for (int ks = 0; ks < 2; ++ks)
#pragma unroll
        for (int ii = 0; ii < 4; ++ii)
#pragma unroll
            for (int jj = 0; jj < 2; ++jj)
                acc[MH * 4 + ii][NH * 2 + jj] =
                    __builtin_amdgcn_mfma_f32_16x16x32_bf16(
                        af[ii][ks], bf2[jj][ks],
                        acc[MH * 4 + ii][NH * 2 + jj], 0, 0, 0);
    __builtin_amdgcn_s_setprio(0);
}

template <int MODE>
__global__ __launch_bounds__(512) void mfma_gemm256_kernel(
    const unsigned short* __restrict__ A, const unsigned short* __restrict__ BT,
    float* __restrict__ Cf, unsigned short* __restrict__ Cb,
    const float* __restrict__ bias, const float* __restrict__ resid,
    int M, int N, int K) {
    __shared__ __align__(16) unsigned short smem[65536];  // 128 KiB
    const int tid = threadIdx.x;
    const int lane = tid & 63, wave = tid >> 6;
    const int wm = wave >> 2, wn = wave & 3;
    const int l15 = lane & 15, g = lane >> 4;

    const int gx = gridDim.x, nwg = gx * gridDim.y;
    const int lid = blockIdx.y * gx + blockIdx.x;
    const int swz = ((nwg & 7) == 0) ? ((lid & 7) * (nwg >> 3) + (lid >> 3))
                                     : lid;
    const int row0 = (swz / gx) * 256;
    const int col0 = (swz % gx) * 256;

    const int kt = K >> 6;

    f32x4 acc[8][4] = {};

    stage_half<6>(A, K, row0, 0, smem + 0, tid);           // T0 A h0
    stage_half<6>(A, K, row0 + 64, 0, smem + 8192, tid);   // T0 A h1
    stage_half<5>(BT, K, col0, 0, smem + 32768, tid);      // T0 B h0
    stage_half<5>(BT, K, col0 + 32, 0, smem + 40960, tid); // T0 B h1
    VMCNT(4);
    stage_half<6>(A, K, row0, 64, smem + 16384, tid);      // T1 A h0
    stage_half<6>(A, K, row0 + 64, 64, smem + 24576, tid); // T1 A h1
    stage_half<5>(BT, K, col0, 64, smem + 49152, tid);     // T1 B h0
    VMCNT(6);
    GBAR();

    bf16x8 af[4][2], bf0[2][2], bf1[2][2];
    for (int it = 0; it < (kt >> 1); ++it) {
        const int t1k = (2 * it + 1) << 6;
        int t2 = 2 * it + 2; if (t2 > kt - 1) t2 = kt - 1;
        int t3 = 2 * it + 3; if (t3 > kt - 1) t3 = kt - 1;
        const int t2k = t2 << 6, t3k = t3 << 6;

        read_afrag(smem, 0, wm, l15, g, af);
        read_bfrag(smem, 32768, wn, l15, g, bf0);
        stage_half<5>(BT, K, col0 + 32, t1k, smem + 57344, tid);
        GBAR();
        mfma_quad<0, 0>(acc, af, bf0);
        GBAR();

        read_bfrag(smem, 40960, wn, l15, g, bf1);
        stage_half<6>(A, K, row0, t2k, smem + 0, tid);
        GBAR();
        mfma_quad<0, 1>(acc, af, bf1);
        GBAR();

        read_afrag(smem, 8192, wm, l15, g, af);
        stage_half<5>(BT, K, col0, t2k, smem + 32768, tid);
        GBAR();
        mfma_quad<1, 1>(acc, af, bf1);
        GBAR();

        stage_half<6>(A, K, row0 + 64, t2k, smem + 8192, tid);
        GBAR();
        mfma_quad<1, 0>(acc, af, bf0);
        VMCNT(6);
        GBAR();

        read_afrag(smem, 16384, wm, l15, g, af);
        read_bfrag(smem, 49152, wn, l15, g, bf0);
        stage_half<5>(BT, K, col0 + 32, t2k, smem + 40960, tid);
        GBAR();
        mfma_quad<0, 0>(acc, af, bf0);
        GBAR();

        read_bfrag(smem, 57344, wn, l15, g, bf1);
        stage_half<6>(A, K, row0, t3k, smem + 16384, tid);
        GBAR();
        mfma_quad<0, 1>(acc, af, bf1);
        GBAR();

        read_afrag(smem, 24576, wm, l15, g, af);
        stage_half<5>(BT, K, col0, t3k, smem + 49152, tid);
        GBAR();
        mfma_quad<1, 1>(acc, af, bf1);
        GBAR();

        stage_half<6>(A, K, row0 + 64, t3k, smem + 24576, tid);
        GBAR();
        mfma_quad<1, 0>(acc, af, bf0);
        VMCNT(6);
        GBAR();
    }
    VMCNT(0);
    GBAR();

    if (MODE == 2) {
        constexpr int SLAB = 264;  // 32 x 256 bf16 slab, padded stride
#pragma unroll
        for (int i2 = 0; i2 < 8; ++i2) {
            __syncthreads();
#pragma unroll
            for (int j2 = 0; j2 < 4; ++j2) {
                const int col = wn * 64 + j2 * 16 + l15;
                const float bv = bias[col0 + col];
#pragma unroll
                for (int r = 0; r < 4; ++r) {
                    float v = acc[i2][j2][r] + bv;
                    // gelu_tanh: v * t/(t+1), t = 2^(v*(2.302118+0.102942 v^2))
                    float t = fexp2(v * (2.30211849f + 0.10294198f * v * v));
                    float gel = v * t * __builtin_amdgcn_rcpf(t + 1.f);
                    smem[(wm * 16 + g * 4 + r) * SLAB + col] = f2bf(gel);
                }
            }
            __syncthreads();
            const int sr = tid >> 4;           // 0..31 slab row
            const int cc = (tid & 15) * 16;    // col base
            const int grow = row0 + ((sr >> 4) << 7) + i2 * 16 + (sr & 15);
            *(u16x8*)&Cb[(size_t)grow * N + col0 + cc] =
                *(const u16x8*)&smem[sr * SLAB + cc];
            *(u16x8*)&Cb[(size_t)grow * N + col0 + cc + 8] =
                *(const u16x8*)&smem[sr * SLAB + cc + 8];
        }
        return;
    }

#pragma unroll
    for (int i2 = 0; i2 < 8; ++i2) {
#pragma unroll
        for (int j2 = 0; j2 < 4; ++j2) {
            const int col = col0 + wn * 64 + j2 * 16 + l15;
            const int rowb = row0 + wm * 128 + i2 * 16 + g * 4;
            const float bv = bias[col];
#pragma unroll
            for (int r = 0; r < 4; ++r) {
                const int row = rowb + r;
                float v = acc[i2][j2][r] + bv + resid[(size_t)row * N + col];
                Cf[(size_t)row * N + col] = v;
            }
        }
    }
}

// ---------------------------------------------------------------------------
// 256x128-tile, BK=64, 8-wave (4M x 2N), 8-phase GEMM — for N=1024/3072 cases
// where a 256x256 grid under-fills the 256 CUs. vmcnt(5) at ph4/ph8.
// MODE 3: fp32 C+bias+resid. MODE 4: QKV scatter.
// ---------------------------------------------------------------------------
__device__ __forceinline__ void read_af128(const unsigned short* s, int base,
                                           int wm, int l15, int g,
                                           bf16x8 af[2][2]) {
#pragma unroll
    for (int ii = 0; ii < 2; ++ii) {
        const int lr = wm * 32 + ii * 16 + l15;
#pragma unroll
        for (int ks = 0; ks < 2; ++ks) {
            const int p = ((ks << 2) + g) ^ (lr & 7);
            af[ii][ks] = __builtin_bit_cast(
                bf16x8, *(const u16x8*)&s[base + lr * 64 + p * 8]);
        }
    }
}

__device__ __forceinline__ void read_bf128(const unsigned short* s, int base,
                                           int wn, int l15, int g,
                                           bf16x8 bf2[2][2]) {
#pragma unroll
    for (int jj = 0; jj < 2; ++jj) {
        const int lr = wn * 32 + jj * 16 + l15;
#pragma unroll
        for (int ks = 0; ks < 2; ++ks) {
            const int p = ((ks << 2) + g) ^ (lr & 7);
            bf2[jj][ks] = __builtin_bit_cast(
                bf16x8, *(const u16x8*)&s[base + lr * 64 + p * 8]);
        }
    }
}

template <int MH, int NH>
__device__ __forceinline__ void mfma_quad128(f32x4 acc[4][4],
                                             const bf16x8 af[2][2],
                                             const bf16x8 bf2[2][2]) {
    __builtin_amdgcn_s_setprio(1);
#pragma unroll
    for (int ks = 0; ks < 2; ++ks)
#pragma unroll
        for (int ii = 0; ii < 2; ++ii)
#pragma unroll
            for (int jj = 0; jj < 2; ++jj)
                acc[MH * 2 + ii][NH * 2 + jj] =
                    __builtin_amdgcn_mfma_f32_16x16x32_bf16(
                        af[ii][ks], bf2[jj][ks],
                        acc[MH * 2 + ii][NH * 2 + jj], 0, 0, 0);
    __builtin_amdgcn_s_setprio(0);
}

template <int MODE>
__global__ __launch_bounds__(512) void gemm_n128_kernel(
    const unsigned short* __restrict__ A, const unsigned short* __restrict__ BT,
    float* __restrict__ Cf, const float* __restrict__ bias,
    const float* __restrict__ resid, unsigned short* __restrict__ Qb,
    unsigned short* __restrict__ Kb, unsigned short* __restrict__ VTb,
    int M, int N, int K) {
    __shared__ __align__(16) unsigned short smem[49152];  // 96 KiB
    const int tid = threadIdx.x;
    const int lane = tid & 63, wave = tid >> 6;
    const int wm = wave >> 1, wn = wave & 1;
    const int l15 = lane & 15, g = lane >> 4;

    const int gx = gridDim.x, nwg = gx * gridDim.y;
    const int lid = blockIdx.y * gx + blockIdx.x;
    const int swz = ((nwg & 7) == 0) ? ((lid & 7) * (nwg >> 3) + (lid >> 3))
                                     : lid;
    const int row0 = (swz / gx) * 256;
    const int col0 = (swz % gx) * 128;

    const int kt = K >> 6;

    f32x4 acc[4][4] = {};

    stage_half<5>(A, K, row0, 0, smem + 0, tid);            // T0 A h0 (2)
    stage_half<5>(A, K, row0 + 32, 0, smem + 8192, tid);    // T0 A h1 (2)
    stage_64(BT, K, col0, 0, smem + 32768, tid);            // T0 B h0 (1)
    stage_64(BT, K, col0 + 32, 0, smem + 36864, tid);       // T0 B h1 (1)
    VMCNT(4);
    stage_half<5>(A, K, row0, 64, smem + 16384, tid);       // T1 A h0 (2)
    stage_half<5>(A, K, row0 + 32, 64, smem + 24576, tid);  // T1 A h1 (2)
    stage_64(BT, K, col0, 64, smem + 40960, tid);           // T1 B h0 (1)
    VMCNT(5);   // T0's 6 loads done; T1's 5 in flight
    GBAR();

    bf16x8 af[2][2], bf0[2][2], bf1[2][2];
    for (int it = 0; it < (kt >> 1); ++it) {
        const int t1k = (2 * it + 1) << 6;
        int t2 = 2 * it + 2; if (t2 > kt - 1) t2 = kt - 1;   // clamped
        int t3 = 2 * it + 3; if (t3 > kt - 1) t3 = kt - 1;   // (junk re-stage,
        const int t2k = t2 << 6, t3k = t3 << 6;              //  dest dead)

        read_af128(smem, 0, wm, l15, g, af);
        read_bf128(smem, 32768, wn, l15, g, bf0);
        stage_64(BT, K, col0 + 32, t1k, smem + 45056, tid);
        GBAR();
        mfma_quad128<0, 0>(acc, af, bf0);
        GBAR();

        read_bf128(smem, 36864, wn, l15, g, bf1);
        stage_half<5>(A, K, row0, t2k, smem + 0, tid);
        GBAR();
        mfma_quad128<0, 1>(acc, af, bf1);
        GBAR();

        read_af128(smem, 8192, wm, l15, g, af);
        stage_64(BT, K, col0, t2k, smem + 32768, tid);
        GBAR();
        mfma_quad128<1, 1>(acc, af, bf1);
        GBAR();

        stage_half<5>(A, K, row0 + 32, t2k, smem + 8192, tid);
        GBAR();
        mfma_quad128<1, 0>(acc, af, bf0);
        VMCNT(5);
        GBAR();

        read_af128(smem, 16384, wm, l15, g, af);
        read_bf128(smem, 40960, wn, l15, g, bf0);
        stage_64(BT, K, col0 + 32, t2k, smem + 36864, tid);
        GBAR();
        mfma_quad128<0, 0>(acc, af, bf0);
        GBAR();

        read_bf128(smem, 45056, wn, l15, g, bf1);
        stage_half<5>(A, K, row0, t3k, smem + 16384, tid);
        GBAR();
        mfma_quad128<0, 1>(acc, af, bf1);
        GBAR();

        read_af128(smem, 24576, wm, l15, g, af);
        stage_64(BT, K, col0, t3k, smem + 40960, tid);
        GBAR();
        mfma_quad128<1, 1>(acc, af, bf1);
        GBAR();

        stage_half<5>(A, K, row0 + 32, t3k, smem + 24576, tid);
        GBAR();
        mfma_quad128<1, 0>(acc, af, bf0);
        VMCNT(5);
        GBAR();
    }
    VMCNT(0);  // drain junk prefetches before exit
    GBAR();

#pragma unroll
    for (int i2 = 0; i2 < 4; ++i2) {
#pragma unroll
        for (int j2 = 0; j2 < 4; ++j2) {
            const int col = col0 + wn * 64 + j2 * 16 + l15;
            const int rowb = row0 + wm * 64 + i2 * 16 + g * 4;
            if (MODE == 4) {
                const int h = col / 192, e = col % 192;
                const int bb = rowb >> 11, s = rowb & 2047;
                if (e < 64) {
                    unsigned short* q =
                        Qb + (((size_t)bb * HH + h) * SS + s) * 64 + e;
#pragma unroll
                    for (int r = 0; r < 4; ++r)
                        q[r * 64] = f2bf(acc[i2][j2][r] * 0.18033688f);
                } else if (e < 128) {
                    unsigned short* kp =
                        Kb + (((size_t)bb * HH + h) * SS + s) * 64 + (e - 64);
#pragma unroll
                    for (int r = 0; r < 4; ++r)
                        kp[r * 64] = f2bf(acc[i2][j2][r]);
                } else {
                    ushort4 pk;
                    pk.x = f2bf(acc[i2][j2][0]);
                    pk.y = f2bf(acc[i2][j2][1]);
                    pk.z = f2bf(acc[i2][j2][2]);
                    pk.w = f2bf(acc[i2][j2][3]);
                    *(ushort4*)(VTb + (((size_t)bb * HH + h) * 64 + (e - 128)) *
                                          SS + s) = pk;
                }
            } else {
                const float bv = bias[col];
#pragma unroll
                for (int r = 0; r < 4; ++r) {
                    const int row = rowb + r;
                    float v = acc[i2][j2][r] + bv + resid[(size_t)row * N + col];
                    Cf[(size_t)row * N + col] = v;
                }
            }
        }
    }
}

// ---------------------------------------------------------------------------
// Flash causal attention, transposed-score formulation, exp2 domain
// (Q pre-scaled by 0.125*log2e in the QKV epilogue).
// S^T = K Q^T; softmax per q-col (2 shuffles); O^T = V^T P^T.
// Block: 256 q of one (b,h); 8 waves x 32 q; kv tiles of 64.
// blockIdx.y remap: heavy q-chunks dispatched FIRST and paired so co-resident
// pairs sum to equal work (qb = p<4 ? 7-p : p-4; pair sums = 36 tiles).
// K/V double-buffered via global_load_lds (XOR k-chunk swizzle); 1 K + 1 V
// gl_lds per thread per tile; vmcnt(2) counted. 2 barriers/tile.
// Defer-max (bit-exact, THR=0): skip O-rescale when __all(mx <= mst).
// ---------------------------------------------------------------------------
__global__ __launch_bounds__(512) void fattn_kernel(
    const unsigned short* __restrict__ Qb, const unsigned short* __restrict__ Kb,
    const unsigned short* __restrict__ VTb, unsigned short* __restrict__ att) {
    constexpr int PSTR = 68;
    __shared__ __align__(16) unsigned short Pls[256 * PSTR];
    __shared__ __align__(16) unsigned short Kls[2][64 * 64];
    __shared__ __align__(16) unsigned short VTls[2][64 * 64];

    const int bh = blockIdx.x;
    const int p = blockIdx.y;
    const int qb = (p < 4) ? (7 - p) : (p - 4);   // heavy-first, balanced pairs
    const int q0 = qb * 256;
    const int tid = threadIdx.x;
    const int lane = tid & 63;
    const int wave = tid >> 6;                    // 0..7
    const int l15 = lane & 15;
    const int g = lane >> 4;
    const int b = bh >> 4, h = bh & 15;

    const unsigned short* Qh = Qb + (size_t)bh * SS * 64;
    const unsigned short* Kh = Kb + (size_t)bh * SS * 64;
    const unsigned short* Vh = VTb + (size_t)bh * 64 * SS;

    // ---- stage Q tile (256 rows; rows are wave-private) ----
    {
        const int row = tid >> 1, c0 = (tid & 1) * 32;
        const unsigned short* src = Qh + (size_t)(q0 + row) * 64 + c0;
        unsigned short* dst = &Pls[row * PSTR + c0];
#pragma unroll
        for (int c = 0; c < 32; c += 8)
            *(u16x8*)(dst + c) = *(const u16x8*)(src + c);
    }
    bf16x8 qf[2][2];   // B-frag: [n=q=l15][k=dh]
#pragma unroll
    for (int i = 0; i < 2; ++i)
#pragma unroll
        for (int ks = 0; ks < 2; ++ks)
            qf[i][ks] = __builtin_bit_cast(
                bf16x8, *(const u16x8*)&Pls[(wave * 32 + i * 16 + l15) * PSTR +
                                            ks * 32 + g * 8]);
    // Pls Q region now dead; reused for P^T (also wave-private rows).

    f32x4 oacc[4][2] = {};          // O^T tiles: [jo=dh][i=q]
    float mst[2], lst[2];
#pragma unroll
    for (int i = 0; i < 2; ++i) { mst[i] = -1e30f; lst[i] = 0.f; }

    const int qlim = q0 + wave * 32 + 31;
    const int qrow = wave * 32 + l15;
    const int nt = qb * 4 + 4;       // kv tiles covering q0..q0+255
    const int xh = l15 & 7;          // row-XOR for K/V fragment reads

    // prologue: stage tile 0 into buf 0 (2 gl_lds/thread)
    stage_kv8(Kh, 64, &Kls[0][0], tid);
    stage_kv8(Vh, SS, &VTls[0][0], tid);

    for (int t = 0; t < nt; ++t) {
        const int t0 = t << 6;
        const int tn = (t + 1 < nt) ? t + 1 : nt - 1;  // last iter: junk re-stage
        stage_kv8(Kh + (size_t)(tn << 6) * 64, 64, &Kls[(t + 1) & 1][0], tid);
        stage_kv8(Vh + (tn << 6), SS, &VTls[(t + 1) & 1][0], tid);
        VMCNT(2);   // tile t resident; tile t+1's 2 in flight
        GBAR();

        if (t0 <= qlim) {
            const unsigned short* Kt = &Kls[t & 1][0];
            const unsigned short* Vt = &VTls[t & 1][0];

            // ---- S^T = K Q^T ----
            f32x4 sacc[4][2] = {};
#pragma unroll
            for (int ks = 0; ks < 2; ++ks) {
                const int ko = ((((ks << 2) + g) ^ xh) << 3);
                bf16x8 kb[4];
#pragma unroll
                for (int j = 0; j < 4; ++j)
                    kb[j] = __builtin_bit_cast(
                        bf16x8, *(const u16x8*)&Kt[(j * 16 + l15) * 64 + ko]);
#pragma unroll
                for (int j = 0; j < 4; ++j)
#pragma unroll
                    for (int i = 0; i < 2; ++i)
                        sacc[j][i] = __builtin_amdgcn_mfma_f32_16x16x32_bf16(
                            kb[j], qf[i][ks], sacc[j][i], 0, 0, 0);
            }

            // ---- causal mask (only when tile crosses this wave's diagonal) --
            if (t0 + 63 > q0 + wave * 32) {
#pragma unroll
                for (int j = 0; j < 4; ++j)
#pragma unroll
                    for (int i = 0; i < 2; ++i)
#pragma unroll
                        for (int r = 0; r < 4; ++r) {
                            const int kg = t0 + j * 16 + g * 4 + r;
                            const int qg = q0 + qrow + i * 16;
                            if (kg > qg) sacc[j][i][r] = -1e30f;
                        }
            }

            // ---- online softmax (exp2 domain); P^T -> Pls[q][kv] ----
#pragma unroll
            for (int i = 0; i < 2; ++i) {
                float mx = -1e30f;
#pragma unroll
                for (int j = 0; j < 4; ++j)
                    mx = fmaxf(mx,
                               fmaxf(fmaxf(sacc[j][i][0], sacc[j][i][1]),
                                     fmaxf(sacc[j][i][2], sacc[j][i][3])));
                mx = fmaxf(mx, __shfl_xor(mx, 16));
                mx = fmaxf(mx, __shfl_xor(mx, 32));
                // defer-max (bit-exact): if no lane's max grew, al==1 exactly.
                const bool grow = !__all(mx <= mst[i]);
                float al = 1.f;
                if (grow) {
                    const float mn = fmaxf(mst[i], mx);
                    al = fexp2(mst[i] - mn);
                    mst[i] = mn;
                }
                const float mm = mst[i];
                float rsum = 0.f;
                const int pbase = (qrow + i * 16) * PSTR + g * 4;
#pragma unroll
                for (int j = 0; j < 4; ++j) {
                    float p0 = fexp2(sacc[j][i][0] - mm);
                    float p1 = fexp2(sacc[j][i][1] - mm);
                    float p2 = fexp2(sacc[j][i][2] - mm);
                    float p3 = fexp2(sacc[j][i][3] - mm);
                    rsum += (p0 + p1) + (p2 + p3);
                    ushort4 pk;
                    pk.x = f2bf(p0); pk.y = f2bf(p1);
                    pk.z = f2bf(p2); pk.w = f2bf(p3);
                    *(ushort4*)&Pls[pbase + j * 16] = pk;
                }
                rsum += __shfl_xor(rsum, 16);
                rsum += __shfl_xor(rsum, 32);
                if (grow) {
                    lst[i] = lst[i] * al + rsum;
#pragma unroll
                    for (int jo = 0; jo < 4; ++jo)
#pragma unroll
                        for (int r = 0; r < 4; ++r) oacc[jo][i][r] *= al;
                } else {
                    lst[i] += rsum;
                }
            }

            // ---- O^T += V^T P^T (P rows wave-private; no barrier) ----
#pragma unroll
            for (int ks = 0; ks < 2; ++ks) {
                const int ko = ((((ks << 2) + g) ^ xh) << 3);
                bf16x8 vb[4], pf[2];
#pragma unroll
                for (int jo = 0; jo < 4; ++jo)
                    vb[jo] = __builtin_bit_cast(
                        bf16x8, *(const u16x8*)&Vt[(jo * 16 + l15) * 64 + ko]);
#pragma unroll
                for (int i = 0; i < 2; ++i)
                    pf[i] = __builtin_bit_cast(
                        bf16x8, *(const u16x8*)&Pls[(qrow + i * 16) * PSTR +
                                                    ks * 32 + g * 8]);
#pragma unroll
                for (int jo = 0; jo < 4; ++jo)
#pragma unroll
                    for (int i = 0; i < 2; ++i)
                        oacc[jo][i] = __builtin_amdgcn_mfma_f32_16x16x32_bf16(
                            vb[jo], pf[i], oacc[jo][i], 0, 0, 0);
            }
        }
        GBAR();   // compute reads of buf[t&1] done before next overwrite
    }
    VMCNT(0);   // drain tail junk prefetches

    // ---- epilogue: O^T/l -> att[b, q, h*64+dh], packed ushort4 ----
#pragma unroll
    for (int i = 0; i < 2; ++i) {
        const float inv = 1.f / lst[i];
        const int qg = q0 + qrow + i * 16;
        unsigned short* dst = att + ((size_t)b * SS + qg) * DD + h * 64 + g * 4;
#pragma unroll
        for (int jo = 0; jo < 4; ++jo) {
            ushort4 pk;
            pk.x = f2bf(oacc[jo][i][0] * inv);
            pk.y = f2bf(oacc[jo][i][1] * inv);
            pk.z = f2bf(oacc[jo][i][2] * inv);
            pk.w = f2bf(oacc[jo][i][3] * inv);
            *(ushort4*)(dst + jo * 16) = pk;
        }
    }
}

// ---------------------------------------------------------------------------
// LayerNorm over D=1024; optional bf16 copy. In-place safe.
// ---------------------------------------------------------------------------
__global__ __launch_bounds__(256) void ln_kernel(
    const float* __restrict__ X, const float* __restrict__ g,
    const float* __restrict__ bta, float* __restrict__ Y,
    unsigned short* __restrict__ Yb) {
    const int row = blockIdx.x;
    const float4 xv = ((const float4*)(X + (size_t)row * DD))[threadIdx.x];

    __shared__ float red1[4], red2[4];
    float s = xv.x + xv.y + xv.z + xv.w;
#pragma unroll
    for (int off = 32; off > 0; off >>= 1) s += __shfl_down(s, off);
    const int wave = threadIdx.x >> 6;
    if ((threadIdx.x & 63) == 0) red1[wave] = s;
    __syncthreads();
    const float mu = (red1[0] + red1[1] + red1[2] + red1[3]) * (1.f / DD);

    float dx = xv.x - mu, dy = xv.y - mu, dz = xv.z - mu, dw = xv.w - mu;
    float s2 = dx * dx + dy * dy + dz * dz + dw * dw;
#pragma unroll
    for (int off = 32; off > 0; off >>= 1) s2 += __shfl_down(s2, off);
    if ((threadIdx.x & 63) == 0) red2[wave] = s2;
    __syncthreads();
    const float var = (red2[0] + red2[1] + red2[2] + red2[3]) * (1.f / DD);
    const float rstd = rsqrtf(var + LN_EPS);

    const float4 gv = ((const float4*)g)[threadIdx.x];
    const float4 bv = ((const float4*)bta)[threadIdx.x];
    float4 yv;
    yv.x = dx * rstd * gv.x + bv.x;
    yv.y = dy * rstd * gv.y + bv.y;
    yv.z = dz * rstd * gv.z + bv.z;
    yv.w = dw * rstd * gv.w + bv.w;
    ((float4*)(Y + (size_t)row * DD))[threadIdx.x] = yv;
    if (Yb) {
        ushort4 q;
        q.x = f2bf(yv.x); q.y = f2bf(yv.y);
        q.z = f2bf(yv.z); q.w = f2bf(yv.w);
        ((ushort4*)(Yb + (size_t)row * DD))[threadIdx.x] = q;
    }
}

// ---------------------------------------------------------------------------
// Workspace (byte offsets, peak 144 MB):
//   [0,16M)    Qb bf16 (ph2-3) -> out1b bf16 (ph5+)
//   [16M,32M)  Kb; [32M,48M) VTb (ph2-3) -> hbuf bf16 [16M,80M) (ph6-7)
//   [96M,102M) Wq2T; [102M,118M) xb (ph1-2)
//   [96M,112M) att bf16 (ph3-4); [96M,128M) out1 fp32 (ph5-7)
//   [118M,120M) WprojT; [128M,136M) W1T; [136M,144M) W2T
// ---------------------------------------------------------------------------
extern "C" void kernel_launch(void* const* d_in, const int* in_sizes, int n_in,
                              void* d_out, int out_size, void* d_ws,
                              size_t ws_size, hipStream_t stream) {
    const float* x     = (const float*)d_in[0];
    const float* Wqkv  = (const float*)d_in[1];
    const float* Wproj = (const float*)d_in[2];
    const float* bproj = (const float*)d_in[3];
    const float* ln1_g = (const float*)d_in[4];
    const float* ln1_b = (const float*)d_in[5];
    const float* ln2_g = (const float*)d_in[6];
    const float* ln2_b = (const float*)d_in[7];
    const float* W1    = (const float*)d_in[8];
    const float* b1    = (const float*)d_in[9];
    const float* W2    = (const float*)d_in[10];
    const float* b2    = (const float*)d_in[11];
    float* out = (float*)d_out;

    const size_t M = (size_t)BB * SS;     // 8192
    const size_t MB = 1024 * 1024;
    char* w = (char*)d_ws;
    unsigned short* Qb     = (unsigned short*)(w + 0);
    unsigned short* out1b  = (unsigned short*)(w + 0);
    unsigned short* Kb     = (unsigned short*)(w + 16 * MB);
    unsigned short* VTb    = (unsigned short*)(w + 32 * MB);
    unsigned short* hbuf   = (unsigned short*)(w + 16 * MB);
    unsigned short* Wq2T   = (unsigned short*)(w + 96 * MB);
    unsigned short* xb     = (unsigned short*)(w + 102 * MB);
    unsigned short* att    = (unsigned short*)(w + 96 * MB);
    float*          out1   = (float*)(w + 96 * MB);
    unsigned short* WprojT = (unsigned short*)(w + 118 * MB);
    unsigned short* W1T    = (unsigned short*)(w + 128 * MB);
    unsigned short* W2T    = (unsigned short*)(w + 136 * MB);

    // 1. weight/input conversions
    repack_wqkv_bf16_kernel<<<dim3(3, 16, 16), 256, 0, stream>>>(Wqkv, Wq2T);
    transpose_bf16_kernel<<<dim3(16, 16), 256, 0, stream>>>(Wproj, WprojT, 1024, 1024);
    transpose_bf16_kernel<<<dim3(64, 16), 256, 0, stream>>>(W1, W1T, 1024, 4096);
    transpose_bf16_kernel<<<dim3(16, 64), 256, 0, stream>>>(W2, W2T, 4096, 1024);
    f2bf_kernel<<<(int)((M * DD + 255) / 256), 256, 0, stream>>>(x, xb, (int)(M * DD));

    // 2. QKV GEMM -> flash layouts Qb/Kb/VTb (bf16, Q in exp2 domain)
    gemm_n128_kernel<4><<<dim3(3072 / 128, M / 256), 512, 0, stream>>>(
        xb, Wq2T, nullptr, nullptr, nullptr, Qb, Kb, VTb, (int)M, 3072, 1024);

    // 3. flash causal attention -> att bf16 (8-wave 256-q blocks, heavy-first)
    fattn_kernel<<<dim3(BB * HH, SS / 256), 512, 0, stream>>>(Qb, Kb, VTb, att);

    // 4. proj GEMM + bias + residual(x) -> d_out fp32
    gemm_n128_kernel<3><<<dim3(1024 / 128, M / 256), 512, 0, stream>>>(
        att, WprojT, out, bproj, x, nullptr, nullptr, nullptr,
        (int)M, 1024, 1024);

    // 5. LN1 -> out1 fp32 + out1b bf16
    ln_kernel<<<(int)M, 256, 0, stream>>>(out, ln1_g, ln1_b, out1, out1b);

    // 6. MLP up + GELU -> hbuf bf16
    mfma_gemm256_kernel<2><<<dim3(4096 / 256, M / 256), 512, 0, stream>>>(
        out1b, W1T, nullptr, hbuf, b1, nullptr, (int)M, 4096, 1024);

    // 7. MLP down + bias + residual(out1) -> d_out fp32
    gemm_n128_kernel<3><<<dim3(1024 / 128, M / 256), 512, 0, stream>>>(
        hbuf, W2T, out, b2, out1, nullptr, nullptr, nullptr,
        (int)M, 1024, 4096);

    // 8. LN2 in-place on d_out
    ln_kernel<<<(int)M, 256, 0, stream>>>(out, ln2_g, ln2_b, out, nullptr);
}

// Round 5
// 483.937 us; speedup vs baseline: 1.2099x; 1.0272x over previous
//
#include <hip/hip_runtime.h>
#include <math.h>

#define BB 4
#define SS 2048
#define DD 1024
#define HH 16
#define DHH 64
#define DFF 4096
static constexpr float LN_EPS = 1e-5f;

typedef __bf16 bf16x8 __attribute__((ext_vector_type(8)));
typedef float f32x4 __attribute__((ext_vector_type(4)));
typedef unsigned short u16x8 __attribute__((ext_vector_type(8)));
typedef unsigned int u32x4 __attribute__((ext_vector_type(4)));

// bf16 convert via HW RNE cvt (bit-identical to manual round-to-nearest-even).
__device__ __forceinline__ unsigned short f2bf(float f) {
    return __builtin_bit_cast(unsigned short, (__bf16)f);
}

// Fast 2^x via the gfx hardware exp2 (v_exp_f32).
__device__ __forceinline__ float fexp2(float x) {
    return __builtin_amdgcn_exp2f(x);
}

// Async global->LDS DMA, 16 B/lane; LDS dest = wave-uniform base + lane*16.
__device__ __forceinline__ void gl_lds16(const unsigned short* g,
                                         unsigned short* l) {
    __builtin_amdgcn_global_load_lds(
        (const __attribute__((address_space(1))) unsigned int*)g,
        (__attribute__((address_space(3))) unsigned int*)l, 16, 0, 0);
}

// Raw workgroup barrier with compiler memory fence (no vmcnt drain).
#define GBAR()                               \
    do {                                     \
        asm volatile("" ::: "memory");       \
        __builtin_amdgcn_s_barrier();        \
        asm volatile("" ::: "memory");       \
    } while (0)
#define VMCNT(n) asm volatile("s_waitcnt vmcnt(" #n ")" ::: "memory")

// ---------------------------------------------------------------------------
// fp32 [R][C] -> bf16 transposed [C][R]. 64x64 LDS tiles.
// ---------------------------------------------------------------------------
__global__ __launch_bounds__(256) void transpose_bf16_kernel(
    const float* __restrict__ in, unsigned short* __restrict__ outT,
    int R, int C) {
    __shared__ float t[64][65];
    const int r0 = blockIdx.y * 64, c0 = blockIdx.x * 64;
    const int cl = threadIdx.x & 63, rl = threadIdx.x >> 6;
#pragma unroll
    for (int rr = 0; rr < 16; ++rr)
        t[rl + rr * 4][cl] = in[(size_t)(r0 + rl + rr * 4) * C + c0 + cl];
    __syncthreads();
#pragma unroll
    for (int rr = 0; rr < 16; ++rr)
        outT[(size_t)(c0 + rl + rr * 4) * R + r0 + cl] = f2bf(t[cl][rl + rr * 4]);
}

// ---------------------------------------------------------------------------
// Wqkv [H][D][192] fp32 -> Wq2T bf16 [3072][1024] (row n=h*192+e, col k=d).
// ---------------------------------------------------------------------------
__global__ __launch_bounds__(256) void repack_wqkv_bf16_kernel(
    const float* __restrict__ Wqkv, unsigned short* __restrict__ Wq2T) {
    __shared__ float t[64][65];
    const int h = blockIdx.z;
    const int d0 = blockIdx.y * 64, e0 = blockIdx.x * 64;
    const int cl = threadIdx.x & 63, rl = threadIdx.x >> 6;
#pragma unroll
    for (int rr = 0; rr < 16; ++rr)
        t[rl + rr * 4][cl] =
            Wqkv[((size_t)h * DD + d0 + rl + rr * 4) * 192 + e0 + cl];
    __syncthreads();
#pragma unroll
    for (int rr = 0; rr < 16; ++rr)
        Wq2T[((size_t)h * 192 + e0 + rl + rr * 4) * DD + d0 + cl] =
            f2bf(t[cl][rl + rr * 4]);
}

__global__ __launch_bounds__(256) void f2bf_kernel(
    const float* __restrict__ in, unsigned short* __restrict__ out, int n) {
    int i = blockIdx.x * 256 + threadIdx.x;
    if (i < n) out[i] = f2bf(in[i]);
}

// ---------------------------------------------------------------------------
// Shared staging / fragment helpers (k-chunk XOR swizzle: chunk c of local
// row r holds global chunk c^(r&7); reads apply the same XOR).
// ---------------------------------------------------------------------------
// 128 local rows (2 gl_lds/thread at 512 thr). RS=6: 64-row stripes; RS=5: 32.
template <int RS>
__device__ __forceinline__ void stage_half(const unsigned short* __restrict__ G,
                                           int ldK, int growbase, int kbase,
                                           unsigned short* lbase, int tid) {
#pragma unroll
    for (int s = 0; s < 2; ++s) {
        const int c16 = s * 512 + tid;           // 16B chunk id in half-tile
        const int r = c16 >> 3, c = c16 & 7;     // local row, chunk-in-row
        const int grow =
            growbase + ((r >> RS) << (RS + 1)) + (r & ((1 << RS) - 1));
        const int gcol = kbase + ((c ^ (r & 7)) << 3);
        gl_lds16(&G[(size_t)grow * ldK + gcol], &lbase[c16 << 3]);
    }
}

// 64 local rows (1 gl_lds/thread at 512 thr), 32-row stripes.
__device__ __forceinline__ void stage_64(const unsigned short* __restrict__ G,
                                         int ldK, int growbase, int kbase,
                                         unsigned short* lbase, int tid) {
    const int r = tid >> 3, c = tid & 7;
    const int grow = growbase + ((r >> 5) << 6) + (r & 31);
    const int gcol = kbase + ((c ^ (r & 7)) << 3);
    gl_lds16(&G[(size_t)grow * ldK + gcol], &lbase[tid << 3]);
}

// 64x64 bf16 tile, arbitrary src row stride, natural row order
// (1 gl_lds/thread at 512 threads) — for attention K / V^T tiles.
__device__ __forceinline__ void stage_kv8(const unsigned short* __restrict__ src,
                                          size_t rstride, unsigned short* dst,
                                          int tid) {
    const int r = tid >> 3, c = tid & 7;
    gl_lds16(&src[(size_t)r * rstride + ((c ^ (r & 7)) << 3)], &dst[tid << 3]);
}

// ---------------------------------------------------------------------------
// 256x256-tile, BK=64, 8-wave, 8-phase software-pipelined bf16 MFMA GEMM.
// (used for MLP-up, MODE 2). Per wave (wm=wave>>2, wn=wave&3): 128x64 output.
// vmcnt(6) at ph4/ph8 only. MODE 2: bf16 out = gelu_tanh(C+bias) LDS repack.
// ---------------------------------------------------------------------------
__device__ __forceinline__ void read_afrag(const unsigned short* s, int base,
                                           int wm, int l15, int g,
                                           bf16x8 af[4][2]) {
#pragma unroll
    for (int ii = 0; ii < 4; ++ii) {
        const int lr = wm * 64 + ii * 16 + l15;
#pragma unroll
        for (int ks = 0; ks < 2; ++ks) {
            const int p = ((ks << 2) + g) ^ (lr & 7);
            af[ii][ks] = __builtin_bit_cast(
                bf16x8, *(const u16x8*)&s[base + lr * 64 + p * 8]);
        }
    }
}

__device__ __forceinline__ void read_bfrag(const unsigned short* s, int base,
                                           int wn, int l15, int g,
                                           bf16x8 bf2[2][2]) {
#pragma unroll
    for (int jj = 0; jj < 2; ++jj) {
        const int lr = wn * 32 + jj * 16 + l15;
#pragma unroll
        for (int ks = 0; ks < 2; ++ks) {
            const int p = ((ks << 2) + g) ^ (lr & 7);
            bf2[jj][ks] = __builtin_bit_cast(
                bf16x8, *(const u16x8*)&s[base + lr * 64 + p * 8]);
        }
    }
}

template <int MH, int NH>
__device__ __forceinline__ void mfma_quad(f32x4 acc[8][4],
                                          const bf16x8 af[4][2],
                                          const bf16x8 bf2[2][2]) {
    __builtin_amdgcn_s_setprio(1);
#pragma unroll
    for (int ks = 0; ks < 2; ++ks)
#pragma unroll
        for (int ii = 0; ii < 4; ++ii)
#pragma unroll
            for (int jj = 0; jj < 2; ++jj)
                acc[MH * 4 + ii][NH * 2 + jj] =
                    __builtin_amdgcn_mfma_f32_16x16x32_bf16(
                        af[ii][ks], bf2[jj][ks],
                        acc[MH * 4 + ii][NH * 2 + jj], 0, 0, 0);
    __builtin_amdgcn_s_setprio(0);
}

template <int MODE>
__global__ __launch_bounds__(512) void mfma_gemm256_kernel(
    const unsigned short* __restrict__ A, const unsigned short* __restrict__ BT,
    float* __restrict__ Cf, unsigned short* __restrict__ Cb,
    const float* __restrict__ bias, const float* __restrict__ resid,
    int M, int N, int K) {
    __shared__ __align__(16) unsigned short smem[65536];  // 128 KiB
    const int tid = threadIdx.x;
    const int lane = tid & 63, wave = tid >> 6;
    const int wm = wave >> 2, wn = wave & 3;
    const int l15 = lane & 15, g = lane >> 4;

    const int gx = gridDim.x, nwg = gx * gridDim.y;
    const int lid = blockIdx.y * gx + blockIdx.x;
    const int swz = ((nwg & 7) == 0) ? ((lid & 7) * (nwg >> 3) + (lid >> 3))
                                     : lid;
    const int row0 = (swz / gx) * 256;
    const int col0 = (swz % gx) * 256;

    const int kt = K >> 6;

    f32x4 acc[8][4] = {};

    stage_half<6>(A, K, row0, 0, smem + 0, tid);           // T0 A h0
    stage_half<6>(A, K, row0 + 64, 0, smem + 8192, tid);   // T0 A h1
    stage_half<5>(BT, K, col0, 0, smem + 32768, tid);      // T0 B h0
    stage_half<5>(BT, K, col0 + 32, 0, smem + 40960, tid); // T0 B h1
    VMCNT(4);
    stage_half<6>(A, K, row0, 64, smem + 16384, tid);      // T1 A h0
    stage_half<6>(A, K, row0 + 64, 64, smem + 24576, tid); // T1 A h1
    stage_half<5>(BT, K, col0, 64, smem + 49152, tid);     // T1 B h0
    VMCNT(6);
    GBAR();

    bf16x8 af[4][2], bf0[2][2], bf1[2][2];
    for (int it = 0; it < (kt >> 1); ++it) {
        const int t1k = (2 * it + 1) << 6;
        int t2 = 2 * it + 2; if (t2 > kt - 1) t2 = kt - 1;
        int t3 = 2 * it + 3; if (t3 > kt - 1) t3 = kt - 1;
        const int t2k = t2 << 6, t3k = t3 << 6;

        read_afrag(smem, 0, wm, l15, g, af);
        read_bfrag(smem, 32768, wn, l15, g, bf0);
        stage_half<5>(BT, K, col0 + 32, t1k, smem + 57344, tid);
        GBAR();
        mfma_quad<0, 0>(acc, af, bf0);
        GBAR();

        read_bfrag(smem, 40960, wn, l15, g, bf1);
        stage_half<6>(A, K, row0, t2k, smem + 0, tid);
        GBAR();
        mfma_quad<0, 1>(acc, af, bf1);
        GBAR();

        read_afrag(smem, 8192, wm, l15, g, af);
        stage_half<5>(BT, K, col0, t2k, smem + 32768, tid);
        GBAR();
        mfma_quad<1, 1>(acc, af, bf1);
        GBAR();

        stage_half<6>(A, K, row0 + 64, t2k, smem + 8192, tid);
        GBAR();
        mfma_quad<1, 0>(acc, af, bf0);
        VMCNT(6);
        GBAR();

        read_afrag(smem, 16384, wm, l15, g, af);
        read_bfrag(smem, 49152, wn, l15, g, bf0);
        stage_half<5>(BT, K, col0 + 32, t2k, smem + 40960, tid);
        GBAR();
        mfma_quad<0, 0>(acc, af, bf0);
        GBAR();

        read_bfrag(smem, 57344, wn, l15, g, bf1);
        stage_half<6>(A, K, row0, t3k, smem + 16384, tid);
        GBAR();
        mfma_quad<0, 1>(acc, af, bf1);
        GBAR();

        read_afrag(smem, 24576, wm, l15, g, af);
        stage_half<5>(BT, K, col0, t3k, smem + 49152, tid);
        GBAR();
        mfma_quad<1, 1>(acc, af, bf1);
        GBAR();

        stage_half<6>(A, K, row0 + 64, t3k, smem + 24576, tid);
        GBAR();
        mfma_quad<1, 0>(acc, af, bf0);
        VMCNT(6);
        GBAR();
    }
    VMCNT(0);
    GBAR();

    if (MODE == 2) {
        constexpr int SLAB = 264;  // 32 x 256 bf16 slab, padded stride
#pragma unroll
        for (int i2 = 0; i2 < 8; ++i2) {
            __syncthreads();
#pragma unroll
            for (int j2 = 0; j2 < 4; ++j2) {
                const int col = wn * 64 + j2 * 16 + l15;
                const float bv = bias[col0 + col];
#pragma unroll
                for (int r = 0; r < 4; ++r) {
                    float v = acc[i2][j2][r] + bv;
                    // gelu_tanh: v * t/(t+1), t = 2^(v*(2.302118+0.102942 v^2))
                    float t = fexp2(v * (2.30211849f + 0.10294198f * v * v));
                    float gel = v * t * __builtin_amdgcn_rcpf(t + 1.f);
                    smem[(wm * 16 + g * 4 + r) * SLAB + col] = f2bf(gel);
                }
            }
            __syncthreads();
            const int sr = tid >> 4;           // 0..31 slab row
            const int cc = (tid & 15) * 16;    // col base
            const int grow = row0 + ((sr >> 4) << 7) + i2 * 16 + (sr & 15);
            *(u16x8*)&Cb[(size_t)grow * N + col0 + cc] =
                *(const u16x8*)&smem[sr * SLAB + cc];
            *(u16x8*)&Cb[(size_t)grow * N + col0 + cc + 8] =
                *(const u16x8*)&smem[sr * SLAB + cc + 8];
        }
        return;
    }

#pragma unroll
    for (int i2 = 0; i2 < 8; ++i2) {
#pragma unroll
        for (int j2 = 0; j2 < 4; ++j2) {
            const int col = col0 + wn * 64 + j2 * 16 + l15;
            const int rowb = row0 + wm * 128 + i2 * 16 + g * 4;
            const float bv = bias[col];
#pragma unroll
            for (int r = 0; r < 4; ++r) {
                const int row = rowb + r;
                float v = acc[i2][j2][r] + bv + resid[(size_t)row * N + col];
                Cf[(size_t)row * N + col] = v;
            }
        }
    }
}

// ---------------------------------------------------------------------------
// 256x128-tile, BK=64, 8-wave (4M x 2N), 8-phase GEMM — for N=1024/3072 cases
// where a 256x256 grid under-fills the 256 CUs. vmcnt(5) at ph4/ph8.
// MODE 3: fp32 C+bias+resid. MODE 4: QKV scatter.
// ---------------------------------------------------------------------------
__device__ __forceinline__ void read_af128(const unsigned short* s, int base,
                                           int wm, int l15, int g,
                                           bf16x8 af[2][2]) {
#pragma unroll
    for (int ii = 0; ii < 2; ++ii) {
        const int lr = wm * 32 + ii * 16 + l15;
#pragma unroll
        for (int ks = 0; ks < 2; ++ks) {
            const int p = ((ks << 2) + g) ^ (lr & 7);
            af[ii][ks] = __builtin_bit_cast(
                bf16x8, *(const u16x8*)&s[base + lr * 64 + p * 8]);
        }
    }
}

__device__ __forceinline__ void read_bf128(const unsigned short* s, int base,
                                           int wn, int l15, int g,
                                           bf16x8 bf2[2][2]) {
#pragma unroll
    for (int jj = 0; jj < 2; ++jj) {
        const int lr = wn * 32 + jj * 16 + l15;
#pragma unroll
        for (int ks = 0; ks < 2; ++ks) {
            const int p = ((ks << 2) + g) ^ (lr & 7);
            bf2[jj][ks] = __builtin_bit_cast(
                bf16x8, *(const u16x8*)&s[base + lr * 64 + p * 8]);
        }
    }
}

template <int MH, int NH>
__device__ __forceinline__ void mfma_quad128(f32x4 acc[4][4],
                                             const bf16x8 af[2][2],
                                             const bf16x8 bf2[2][2]) {
    __builtin_amdgcn_s_setprio(1);
#pragma unroll
    for (int ks = 0; ks < 2; ++ks)
#pragma unroll
        for (int ii = 0; ii < 2; ++ii)
#pragma unroll
            for (int jj = 0; jj < 2; ++jj)
                acc[MH * 2 + ii][NH * 2 + jj] =
                    __builtin_amdgcn_mfma_f32_16x16x32_bf16(
                        af[ii][ks], bf2[jj][ks],
                        acc[MH * 2 + ii][NH * 2 + jj], 0, 0, 0);
    __builtin_amdgcn_s_setprio(0);
}

template <int MODE>
__global__ __launch_bounds__(512) void gemm_n128_kernel(
    const unsigned short* __restrict__ A, const unsigned short* __restrict__ BT,
    float* __restrict__ Cf, const float* __restrict__ bias,
    const float* __restrict__ resid, unsigned short* __restrict__ Qb,
    unsigned short* __restrict__ Kb, unsigned short* __restrict__ VTb,
    int M, int N, int K) {
    __shared__ __align__(16) unsigned short smem[49152];  // 96 KiB
    const int tid = threadIdx.x;
    const int lane = tid & 63, wave = tid >> 6;
    const int wm = wave >> 1, wn = wave & 1;
    const int l15 = lane & 15, g = lane >> 4;

    const int gx = gridDim.x, nwg = gx * gridDim.y;
    const int lid = blockIdx.y * gx + blockIdx.x;
    const int swz = ((nwg & 7) == 0) ? ((lid & 7) * (nwg >> 3) + (lid >> 3))
                                     : lid;
    const int row0 = (swz / gx) * 256;
    const int col0 = (swz % gx) * 128;

    const int kt = K >> 6;

    f32x4 acc[4][4] = {};

    stage_half<5>(A, K, row0, 0, smem + 0, tid);            // T0 A h0 (2)
    stage_half<5>(A, K, row0 + 32, 0, smem + 8192, tid);    // T0 A h1 (2)
    stage_64(BT, K, col0, 0, smem + 32768, tid);            // T0 B h0 (1)
    stage_64(BT, K, col0 + 32, 0, smem + 36864, tid);       // T0 B h1 (1)
    VMCNT(4);
    stage_half<5>(A, K, row0, 64, smem + 16384, tid);       // T1 A h0 (2)
    stage_half<5>(A, K, row0 + 32, 64, smem + 24576, tid);  // T1 A h1 (2)
    stage_64(BT, K, col0, 64, smem + 40960, tid);           // T1 B h0 (1)
    VMCNT(5);   // T0's 6 loads done; T1's 5 in flight
    GBAR();

    bf16x8 af[2][2], bf0[2][2], bf1[2][2];
    for (int it = 0; it < (kt >> 1); ++it) {
        const int t1k = (2 * it + 1) << 6;
        int t2 = 2 * it + 2; if (t2 > kt - 1) t2 = kt - 1;   // clamped
        int t3 = 2 * it + 3; if (t3 > kt - 1) t3 = kt - 1;   // (junk re-stage,
        const int t2k = t2 << 6, t3k = t3 << 6;              //  dest dead)

        read_af128(smem, 0, wm, l15, g, af);
        read_bf128(smem, 32768, wn, l15, g, bf0);
        stage_64(BT, K, col0 + 32, t1k, smem + 45056, tid);
        GBAR();
        mfma_quad128<0, 0>(acc, af, bf0);
        GBAR();

        read_bf128(smem, 36864, wn, l15, g, bf1);
        stage_half<5>(A, K, row0, t2k, smem + 0, tid);
        GBAR();
        mfma_quad128<0, 1>(acc, af, bf1);
        GBAR();

        read_af128(smem, 8192, wm, l15, g, af);
        stage_64(BT, K, col0, t2k, smem + 32768, tid);
        GBAR();
        mfma_quad128<1, 1>(acc, af, bf1);
        GBAR();

        stage_half<5>(A, K, row0 + 32, t2k, smem + 8192, tid);
        GBAR();
        mfma_quad128<1, 0>(acc, af, bf0);
        VMCNT(5);
        GBAR();

        read_af128(smem, 16384, wm, l15, g, af);
        read_bf128(smem, 40960, wn, l15, g, bf0);
        stage_64(BT, K, col0 + 32, t2k, smem + 36864, tid);
        GBAR();
        mfma_quad128<0, 0>(acc, af, bf0);
        GBAR();

        read_bf128(smem, 45056, wn, l15, g, bf1);
        stage_half<5>(A, K, row0, t3k, smem + 16384, tid);
        GBAR();
        mfma_quad128<0, 1>(acc, af, bf1);
        GBAR();

        read_af128(smem, 24576, wm, l15, g, af);
        stage_64(BT, K, col0, t3k, smem + 40960, tid);
        GBAR();
        mfma_quad128<1, 1>(acc, af, bf1);
        GBAR();

        stage_half<5>(A, K, row0 + 32, t3k, smem + 24576, tid);
        GBAR();
        mfma_quad128<1, 0>(acc, af, bf0);
        VMCNT(5);
        GBAR();
    }
    VMCNT(0);  // drain junk prefetches before exit
    GBAR();

#pragma unroll
    for (int i2 = 0; i2 < 4; ++i2) {
#pragma unroll
        for (int j2 = 0; j2 < 4; ++j2) {
            const int col = col0 + wn * 64 + j2 * 16 + l15;
            const int rowb = row0 + wm * 64 + i2 * 16 + g * 4;
            if (MODE == 4) {
                const int h = col / 192, e = col % 192;
                const int bb = rowb >> 11, s = rowb & 2047;
                if (e < 64) {
                    unsigned short* q =
                        Qb + (((size_t)bb * HH + h) * SS + s) * 64 + e;
#pragma unroll
                    for (int r = 0; r < 4; ++r)
                        q[r * 64] = f2bf(acc[i2][j2][r] * 0.18033688f);
                } else if (e < 128) {
                    unsigned short* kp =
                        Kb + (((size_t)bb * HH + h) * SS + s) * 64 + (e - 64);
#pragma unroll
                    for (int r = 0; r < 4; ++r)
                        kp[r * 64] = f2bf(acc[i2][j2][r]);
                } else {
                    ushort4 pk;
                    pk.x = f2bf(acc[i2][j2][0]);
                    pk.y = f2bf(acc[i2][j2][1]);
                    pk.z = f2bf(acc[i2][j2][2]);
                    pk.w = f2bf(acc[i2][j2][3]);
                    *(ushort4*)(VTb + (((size_t)bb * HH + h) * 64 + (e - 128)) *
                                          SS + s) = pk;
                }
            } else {
                const float bv = bias[col];
#pragma unroll
                for (int r = 0; r < 4; ++r) {
                    const int row = rowb + r;
                    float v = acc[i2][j2][r] + bv + resid[(size_t)row * N + col];
                    Cf[(size_t)row * N + col] = v;
                }
            }
        }
    }
}

// ---------------------------------------------------------------------------
// Flash causal attention, transposed-score formulation, exp2 domain
// (Q pre-scaled by 0.125*log2e in the QKV epilogue).
// S^T = K Q^T; softmax per q-col (2 shuffles); O^T = V^T P^T.
// Block: 8 waves; each block processes TWO 128-q chunks {p, 15-p} of one
// (b,h) SEQUENTIALLY -> every block has identical work (34 kv tiles): zero
// tail imbalance. Wave w owns a 16-q strip of the current chunk.
// P never touches LDS: after softmax the bf16 P-words are exchanged across
// the g-lane groups with ds_bpermute (srcA = l15|32*(g&1), srcB = srcA+16;
// j = 2ks+(g>>1)) to build the PV B-fragment directly in registers.
// Q fragments load straight global->reg (wave-private rows).
// LDS = K/V double-buffer only (32 KiB). vmcnt(2) counted prefetch.
// Defer-max (bit-exact, THR=0): skip O-rescale when __all(mx <= mst).
// ---------------------------------------------------------------------------
__global__ __launch_bounds__(512, 4) void fattn_kernel(
    const unsigned short* __restrict__ Qb, const unsigned short* __restrict__ Kb,
    const unsigned short* __restrict__ VTb, unsigned short* __restrict__ att) {
    __shared__ __align__(16) unsigned short Kls[2][64 * 64];
    __shared__ __align__(16) unsigned short VTls[2][64 * 64];

    const int bh = blockIdx.x;
    const int p = blockIdx.y;                    // 0..7 -> chunks {p, 15-p}
    const int tid = threadIdx.x;
    const int lane = tid & 63;
    const int wave = tid >> 6;                   // 0..7
    const int l15 = lane & 15;
    const int g = lane >> 4;
    const int b = bh >> 4, h = bh & 15;
    const int xh = l15 & 7;

    const unsigned short* Qh = Qb + (size_t)bh * SS * 64;
    const unsigned short* Kh = Kb + (size_t)bh * SS * 64;
    const unsigned short* Vh = VTb + (size_t)bh * 64 * SS;

    const int srcA = l15 | ((lane & 16) << 1);   // src lane bit5=g&1, bit4=0
    const int srcB = srcA | 16;                  // bit4=1
    const bool ghi = (lane & 32) != 0;           // g>=2 -> j = 2ks+1

#pragma unroll 1
    for (int half = 0; half < 2; ++half) {
        const int cidx = half ? (15 - p) : p;    // chunk index 0..15
        const int q0c = cidx << 7;
        const int qrow = wave * 16 + l15;
        const int qg = q0c + qrow;               // this lane's q row
        const int qlim = q0c + wave * 16 + 15;
        const int nt = (cidx << 1) + 2;          // kv tiles for this chunk

        // Q fragment straight from global (wave-private rows).
        bf16x8 qf[2];
#pragma unroll
        for (int ks = 0; ks < 2; ++ks)
            qf[ks] = __builtin_bit_cast(
                bf16x8, *(const u16x8*)&Qh[(size_t)qg * 64 + ks * 32 + g * 8]);

        f32x4 oacc[4] = {};                      // O^T: [jo=dh], col=q=l15
        float mst = -1e30f, lst = 0.f;

        stage_kv8(Kh, 64, &Kls[0][0], tid);
        stage_kv8(Vh, SS, &VTls[0][0], tid);

        for (int t = 0; t < nt; ++t) {
            const int t0 = t << 6;
            if (t + 1 < nt) {
                stage_kv8(Kh + ((size_t)(t + 1) << 6) * 64, 64,
                          &Kls[(t + 1) & 1][0], tid);
                stage_kv8(Vh + ((t + 1) << 6), SS, &VTls[(t + 1) & 1][0], tid);
                VMCNT(2);   // tile t resident; t+1's 2 in flight
            } else {
                VMCNT(0);   // last tile: drain
            }
            GBAR();

            if (t0 <= qlim) {
                const unsigned short* Kt = &Kls[t & 1][0];
                const unsigned short* Vt = &VTls[t & 1][0];

                // ---- S^T = K Q^T ----
                f32x4 sacc[4] = {};
                __builtin_amdgcn_s_setprio(1);
#pragma unroll
                for (int ks = 0; ks < 2; ++ks) {
                    const int ko = ((((ks << 2) + g) ^ xh) << 3);
                    bf16x8 kb[4];
#pragma unroll
                    for (int j = 0; j < 4; ++j)
                        kb[j] = __builtin_bit_cast(
                            bf16x8,
                            *(const u16x8*)&Kt[(j * 16 + l15) * 64 + ko]);
#pragma unroll
                    for (int j = 0; j < 4; ++j)
                        sacc[j] = __builtin_amdgcn_mfma_f32_16x16x32_bf16(
                            kb[j], qf[ks], sacc[j], 0, 0, 0);
                }
                __builtin_amdgcn_s_setprio(0);

                // ---- causal mask (tile crossing this wave's diagonal) ----
                if (t0 + 63 > q0c + wave * 16) {
#pragma unroll
                    for (int j = 0; j < 4; ++j)
#pragma unroll
                        for (int r = 0; r < 4; ++r) {
                            const int kg = t0 + j * 16 + g * 4 + r;
                            if (kg > qg) sacc[j][r] = -1e30f;
                        }
                }

                // ---- online softmax (exp2 domain), P in registers ----
                float mx = -1e30f;
#pragma unroll
                for (int j = 0; j < 4; ++j)
                    mx = fmaxf(mx, fmaxf(fmaxf(sacc[j][0], sacc[j][1]),
                                         fmaxf(sacc[j][2], sacc[j][3])));
                mx = fmaxf(mx, __shfl_xor(mx, 16));
                mx = fmaxf(mx, __shfl_xor(mx, 32));
                const bool grow = !__all(mx <= mst);
                float al = 1.f;
                if (grow) {
                    const float mn = fmaxf(mst, mx);
                    al = fexp2(mst - mn);
                    mst = mn;
                }
                const float mm = mst;
                float rsum = 0.f;
                unsigned int Aw[4], Bw[4];   // Aw=kv{0,1}, Bw=kv{2,3} per j
#pragma unroll
                for (int j = 0; j < 4; ++j) {
                    float p0 = fexp2(sacc[j][0] - mm);
                    float p1 = fexp2(sacc[j][1] - mm);
                    float p2 = fexp2(sacc[j][2] - mm);
                    float p3 = fexp2(sacc[j][3] - mm);
                    rsum += (p0 + p1) + (p2 + p3);
                    Aw[j] = (unsigned int)f2bf(p0) |
                            ((unsigned int)f2bf(p1) << 16);
                    Bw[j] = (unsigned int)f2bf(p2) |
                            ((unsigned int)f2bf(p3) << 16);
                }
                rsum += __shfl_xor(rsum, 16);
                rsum += __shfl_xor(rsum, 32);
                if (grow) {
                    lst = lst * al + rsum;
#pragma unroll
                    for (int jo = 0; jo < 4; ++jo)
#pragma unroll
                        for (int r = 0; r < 4; ++r) oacc[jo][r] *= al;
                } else {
                    lst += rsum;
                }

                // ---- P exchange (regs) + O^T += V^T P^T ----
#pragma unroll
                for (int ks = 0; ks < 2; ++ks) {
                    const int jl = ks * 2, jh = ks * 2 + 1;
                    const int aLo0 = __shfl((int)Aw[jl], srcA);
                    const int aHi0 = __shfl((int)Aw[jh], srcA);
                    const int bLo0 = __shfl((int)Bw[jl], srcA);
                    const int bHi0 = __shfl((int)Bw[jh], srcA);
                    const int aLo1 = __shfl((int)Aw[jl], srcB);
                    const int aHi1 = __shfl((int)Aw[jh], srcB);
                    const int bLo1 = __shfl((int)Bw[jl], srcB);
                    const int bHi1 = __shfl((int)Bw[jh], srcB);
                    u32x4 pw;
                    pw[0] = (unsigned int)(ghi ? aHi0 : aLo0);
                    pw[1] = (unsigned int)(ghi ? bHi0 : bLo0);
                    pw[2] = (unsigned int)(ghi ? aHi1 : aLo1);
                    pw[3] = (unsigned int)(ghi ? bHi1 : bLo1);
                    const bf16x8 pf = __builtin_bit_cast(bf16x8, pw);

                    const int ko = ((((ks << 2) + g) ^ xh) << 3);
                    __builtin_amdgcn_s_setprio(1);
#pragma unroll
                    for (int jo = 0; jo < 4; ++jo) {
                        const bf16x8 vb = __builtin_bit_cast(
                            bf16x8,
                            *(const u16x8*)&Vt[(jo * 16 + l15) * 64 + ko]);
                        oacc[jo] = __builtin_amdgcn_mfma_f32_16x16x32_bf16(
                            vb, pf, oacc[jo], 0, 0, 0);
                    }
                    __builtin_amdgcn_s_setprio(0);
                }
            }
            GBAR();   // reads of buf[t&1] done before next overwrite
        }

        // ---- epilogue: O^T/l -> att[b, q, h*64+dh] ----
        const float inv = 1.f / lst;
        unsigned short* dst =
            att + ((size_t)b * SS + qg) * DD + h * 64 + g * 4;
#pragma unroll
        for (int jo = 0; jo < 4; ++jo) {
            ushort4 pk;
            pk.x = f2bf(oacc[jo][0] * inv);
            pk.y = f2bf(oacc[jo][1] * inv);
            pk.z = f2bf(oacc[jo][2] * inv);
            pk.w = f2bf(oacc[jo][3] * inv);
            *(ushort4*)(dst + jo * 16) = pk;
        }
        GBAR();   // all epilogue LDS-independent; sync before next chunk stage
    }
}

// ---------------------------------------------------------------------------
// LayerNorm over D=1024; optional bf16 copy. In-place safe.
// ---------------------------------------------------------------------------
__global__ __launch_bounds__(256) void ln_kernel(
    const float* __restrict__ X, const float* __restrict__ g,
    const float* __restrict__ bta, float* __restrict__ Y,
    unsigned short* __restrict__ Yb) {
    const int row = blockIdx.x;
    const float4 xv = ((const float4*)(X + (size_t)row * DD))[threadIdx.x];

    __shared__ float red1[4], red2[4];
    float s = xv.x + xv.y + xv.z + xv.w;
#pragma unroll
    for (int off = 32; off > 0; off >>= 1) s += __shfl_down(s, off);
    const int wave = threadIdx.x >> 6;
    if ((threadIdx.x & 63) == 0) red1[wave] = s;
    __syncthreads();
    const float mu = (red1[0] + red1[1] + red1[2] + red1[3]) * (1.f / DD);

    float dx = xv.x - mu, dy = xv.y - mu, dz = xv.z - mu, dw = xv.w - mu;
    float s2 = dx * dx + dy * dy + dz * dz + dw * dw;
#pragma unroll
    for (int off = 32; off > 0; off >>= 1) s2 += __shfl_down(s2, off);
    if ((threadIdx.x & 63) == 0) red2[wave] = s2;
    __syncthreads();
    const float var = (red2[0] + red2[1] + red2[2] + red2[3]) * (1.f / DD);
    const float rstd = rsqrtf(var + LN_EPS);

    const float4 gv = ((const float4*)g)[threadIdx.x];
    const float4 bv = ((const float4*)bta)[threadIdx.x];
    float4 yv;
    yv.x = dx * rstd * gv.x + bv.x;
    yv.y = dy * rstd * gv.y + bv.y;
    yv.z = dz * rstd * gv.z + bv.z;
    yv.w = dw * rstd * gv.w + bv.w;
    ((float4*)(Y + (size_t)row * DD))[threadIdx.x] = yv;
    if (Yb) {
        ushort4 q;
        q.x = f2bf(yv.x); q.y = f2bf(yv.y);
        q.z = f2bf(yv.z); q.w = f2bf(yv.w);
        ((ushort4*)(Yb + (size_t)row * DD))[threadIdx.x] = q;
    }
}

// ---------------------------------------------------------------------------
// Workspace (byte offsets, peak 144 MB):
//   [0,16M)    Qb bf16 (ph2-3) -> out1b bf16 (ph5+)
//   [16M,32M)  Kb; [32M,48M) VTb (ph2-3) -> hbuf bf16 [16M,80M) (ph6-7)
//   [96M,102M) Wq2T; [102M,118M) xb (ph1-2)
//   [96M,112M) att bf16 (ph3-4); [96M,128M) out1 fp32 (ph5-7)
//   [118M,120M) WprojT; [128M,136M) W1T; [136M,144M) W2T
// ---------------------------------------------------------------------------
extern "C" void kernel_launch(void* const* d_in, const int* in_sizes, int n_in,
                              void* d_out, int out_size, void* d_ws,
                              size_t ws_size, hipStream_t stream) {
    const float* x     = (const float*)d_in[0];
    const float* Wqkv  = (const float*)d_in[1];
    const float* Wproj = (const float*)d_in[2];
    const float* bproj = (const float*)d_in[3];
    const float* ln1_g = (const float*)d_in[4];
    const float* ln1_b = (const float*)d_in[5];
    const float* ln2_g = (const float*)d_in[6];
    const float* ln2_b = (const float*)d_in[7];
    const float* W1    = (const float*)d_in[8];
    const float* b1    = (const float*)d_in[9];
    const float* W2    = (const float*)d_in[10];
    const float* b2    = (const float*)d_in[11];
    float* out = (float*)d_out;

    const size_t M = (size_t)BB * SS;     // 8192
    const size_t MB = 1024 * 1024;
    char* w = (char*)d_ws;
    unsigned short* Qb     = (unsigned short*)(w + 0);
    unsigned short* out1b  = (unsigned short*)(w + 0);
    unsigned short* Kb     = (unsigned short*)(w + 16 * MB);
    unsigned short* VTb    = (unsigned short*)(w + 32 * MB);
    unsigned short* hbuf   = (unsigned short*)(w + 16 * MB);
    unsigned short* Wq2T   = (unsigned short*)(w + 96 * MB);
    unsigned short* xb     = (unsigned short*)(w + 102 * MB);
    unsigned short* att    = (unsigned short*)(w + 96 * MB);
    float*          out1   = (float*)(w + 96 * MB);
    unsigned short* WprojT = (unsigned short*)(w + 118 * MB);
    unsigned short* W1T    = (unsigned short*)(w + 128 * MB);
    unsigned short* W2T    = (unsigned short*)(w + 136 * MB);

    // 1. weight/input conversions
    repack_wqkv_bf16_kernel<<<dim3(3, 16, 16), 256, 0, stream>>>(Wqkv, Wq2T);
    transpose_bf16_kernel<<<dim3(16, 16), 256, 0, stream>>>(Wproj, WprojT, 1024, 1024);
    transpose_bf16_kernel<<<dim3(64, 16), 256, 0, stream>>>(W1, W1T, 1024, 4096);
    transpose_bf16_kernel<<<dim3(16, 64), 256, 0, stream>>>(W2, W2T, 4096, 1024);
    f2bf_kernel<<<(int)((M * DD + 255) / 256), 256, 0, stream>>>(x, xb, (int)(M * DD));

    // 2. QKV GEMM -> flash layouts Qb/Kb/VTb (bf16, Q in exp2 domain)
    gemm_n128_kernel<4><<<dim3(3072 / 128, M / 256), 512, 0, stream>>>(
        xb, Wq2T, nullptr, nullptr, nullptr, Qb, Kb, VTb, (int)M, 3072, 1024);

    // 3. flash causal attention -> att bf16 (equal-work chunk-pair blocks)
    fattn_kernel<<<dim3(BB * HH, 8), 512, 0, stream>>>(Qb, Kb, VTb, att);

    // 4. proj GEMM + bias + residual(x) -> d_out fp32
    gemm_n128_kernel<3><<<dim3(1024 / 128, M / 256), 512, 0, stream>>>(
        att, WprojT, out, bproj, x, nullptr, nullptr, nullptr,
        (int)M, 1024, 1024);

    // 5. LN1 -> out1 fp32 + out1b bf16
    ln_kernel<<<(int)M, 256, 0, stream>>>(out, ln1_g, ln1_b, out1, out1b);

    // 6. MLP up + GELU -> hbuf bf16
    mfma_gemm256_kernel<2><<<dim3(4096 / 256, M / 256), 512, 0, stream>>>(
        out1b, W1T, nullptr, hbuf, b1, nullptr, (int)M, 4096, 1024);

    // 7. MLP down + bias + residual(out1) -> d_out fp32
    gemm_n128_kernel<3><<<dim3(1024 / 128, M / 256), 512, 0, stream>>>(
        hbuf, W2T, out, b2, out1, nullptr, nullptr, nullptr,
        (int)M, 1024, 4096);

    // 8. LN2 in-place on d_out
    ln_kernel<<<(int)M, 256, 0, stream>>>(out, ln2_g, ln2_b, out, nullptr);
}

// Round 6
// 477.467 us; speedup vs baseline: 1.2263x; 1.0136x over previous
//
#include <hip/hip_runtime.h>
#include <math.h>

#define BB 4
#define SS 2048
#define DD 1024
#define HH 16
#define DHH 64
#define DFF 4096
static constexpr float LN_EPS = 1e-5f;

typedef __bf16 bf16x8 __attribute__((ext_vector_type(8)));
typedef float f32x4 __attribute__((ext_vector_type(4)));
typedef unsigned short u16x8 __attribute__((ext_vector_type(8)));
typedef unsigned int u32x4 __attribute__((ext_vector_type(4)));

// bf16 convert via HW RNE cvt (bit-identical to manual round-to-nearest-even).
__device__ __forceinline__ unsigned short f2bf(float f) {
    return __builtin_bit_cast(unsigned short, (__bf16)f);
}

// Fast 2^x via the gfx hardware exp2 (v_exp_f32).
__device__ __forceinline__ float fexp2(float x) {
    return __builtin_amdgcn_exp2f(x);
}

// Async global->LDS DMA, 16 B/lane; LDS dest = wave-uniform base + lane*16.
__device__ __forceinline__ void gl_lds16(const unsigned short* g,
                                         unsigned short* l) {
    __builtin_amdgcn_global_load_lds(
        (const __attribute__((address_space(1))) unsigned int*)g,
        (__attribute__((address_space(3))) unsigned int*)l, 16, 0, 0);
}

// Raw workgroup barrier with compiler memory fence (no vmcnt drain).
#define GBAR()                               \
    do {                                     \
        asm volatile("" ::: "memory");       \
        __builtin_amdgcn_s_barrier();        \
        asm volatile("" ::: "memory");       \
    } while (0)
#define VMCNT(n) asm volatile("s_waitcnt vmcnt(" #n ")" ::: "memory")

// ---------------------------------------------------------------------------
// fp32 [R][C] -> bf16 transposed [C][R]. 64x64 LDS tiles.
// ---------------------------------------------------------------------------
__global__ __launch_bounds__(256) void transpose_bf16_kernel(
    const float* __restrict__ in, unsigned short* __restrict__ outT,
    int R, int C) {
    __shared__ float t[64][65];
    const int r0 = blockIdx.y * 64, c0 = blockIdx.x * 64;
    const int cl = threadIdx.x & 63, rl = threadIdx.x >> 6;
#pragma unroll
    for (int rr = 0; rr < 16; ++rr)
        t[rl + rr * 4][cl] = in[(size_t)(r0 + rl + rr * 4) * C + c0 + cl];
    __syncthreads();
#pragma unroll
    for (int rr = 0; rr < 16; ++rr)
        outT[(size_t)(c0 + rl + rr * 4) * R + r0 + cl] = f2bf(t[cl][rl + rr * 4]);
}

// ---------------------------------------------------------------------------
// Wqkv [H][D][192] fp32 -> Wq2T bf16 [3072][1024] (row n=h*192+e, col k=d).
// ---------------------------------------------------------------------------
__global__ __launch_bounds__(256) void repack_wqkv_bf16_kernel(
    const float* __restrict__ Wqkv, unsigned short* __restrict__ Wq2T) {
    __shared__ float t[64][65];
    const int h = blockIdx.z;
    const int d0 = blockIdx.y * 64, e0 = blockIdx.x * 64;
    const int cl = threadIdx.x & 63, rl = threadIdx.x >> 6;
#pragma unroll
    for (int rr = 0; rr < 16; ++rr)
        t[rl + rr * 4][cl] =
            Wqkv[((size_t)h * DD + d0 + rl + rr * 4) * 192 + e0 + cl];
    __syncthreads();
#pragma unroll
    for (int rr = 0; rr < 16; ++rr)
        Wq2T[((size_t)h * 192 + e0 + rl + rr * 4) * DD + d0 + cl] =
            f2bf(t[cl][rl + rr * 4]);
}

__global__ __launch_bounds__(256) void f2bf_kernel(
    const float* __restrict__ in, unsigned short* __restrict__ out, int n) {
    int i = blockIdx.x * 256 + threadIdx.x;
    if (i < n) out[i] = f2bf(in[i]);
}

// ---------------------------------------------------------------------------
// Shared staging / fragment helpers (k-chunk XOR swizzle: chunk c of local
// row r holds global chunk c^(r&7); reads apply the same XOR).
// ---------------------------------------------------------------------------
// 128 local rows (2 gl_lds/thread at 512 thr). RS=6: 64-row stripes; RS=5: 32.
template <int RS>
__device__ __forceinline__ void stage_half(const unsigned short* __restrict__ G,
                                           int ldK, int growbase, int kbase,
                                           unsigned short* lbase, int tid) {
#pragma unroll
    for (int s = 0; s < 2; ++s) {
        const int c16 = s * 512 + tid;           // 16B chunk id in half-tile
        const int r = c16 >> 3, c = c16 & 7;     // local row, chunk-in-row
        const int grow =
            growbase + ((r >> RS) << (RS + 1)) + (r & ((1 << RS) - 1));
        const int gcol = kbase + ((c ^ (r & 7)) << 3);
        gl_lds16(&G[(size_t)grow * ldK + gcol], &lbase[c16 << 3]);
    }
}

// 64 local rows (1 gl_lds/thread at 512 thr), 32-row stripes.
__device__ __forceinline__ void stage_64(const unsigned short* __restrict__ G,
                                         int ldK, int growbase, int kbase,
                                         unsigned short* lbase, int tid) {
    const int r = tid >> 3, c = tid & 7;
    const int grow = growbase + ((r >> 5) << 6) + (r & 31);
    const int gcol = kbase + ((c ^ (r & 7)) << 3);
    gl_lds16(&G[(size_t)grow * ldK + gcol], &lbase[tid << 3]);
}

// 64x64 bf16 tile, arbitrary src row stride, natural row order
// (2 gl_lds/thread at 256 threads) — attention V^T tiles.
__device__ __forceinline__ void stage_kv(const unsigned short* __restrict__ src,
                                         size_t rstride, unsigned short* dst,
                                         int tid) {
#pragma unroll
    for (int s = 0; s < 2; ++s) {
        const int c16 = s * 256 + tid;
        const int r = c16 >> 3, c = c16 & 7;
        gl_lds16(&src[(size_t)r * rstride + ((c ^ (r & 7)) << 3)],
                 &dst[c16 << 3]);
    }
}

// K tile with pi row permutation (2 gl_lds/thread at 256 threads):
// LDS row rho holds global K row pi(rho) = 32*(j&1) + 8g + 4*(j>>1) + r2
// (rho = 16j + 4g + r2). This makes each lane's QK^T C-fragment hold exactly
// the kv values its own PV B-fragment needs -> zero cross-lane P exchange.
__device__ __forceinline__ void stage_k_pi(const unsigned short* __restrict__ src,
                                           unsigned short* dst, int tid) {
#pragma unroll
    for (int s = 0; s < 2; ++s) {
        const int c16 = s * 256 + tid;
        const int r = c16 >> 3, c = c16 & 7;
        const int gr = ((r >> 4) & 1) * 32 + (((r >> 2) & 3) << 3) +
                       ((r >> 5) & 1) * 4 + (r & 3);
        gl_lds16(&src[(size_t)gr * 64 + ((c ^ (r & 7)) << 3)],
                 &dst[c16 << 3]);
    }
}

// ---------------------------------------------------------------------------
// 256x256-tile, BK=64, 8-wave, 8-phase software-pipelined bf16 MFMA GEMM.
// (used for MLP-up, MODE 2). Per wave (wm=wave>>2, wn=wave&3): 128x64 output.
// vmcnt(6) at ph4/ph8 only. MODE 2: bf16 out = gelu_tanh(C+bias) LDS repack.
// ---------------------------------------------------------------------------
__device__ __forceinline__ void read_afrag(const unsigned short* s, int base,
                                           int wm, int l15, int g,
                                           bf16x8 af[4][2]) {
#pragma unroll
    for (int ii = 0; ii < 4; ++ii) {
        const int lr = wm * 64 + ii * 16 + l15;
#pragma unroll
        for (int ks = 0; ks < 2; ++ks) {
            const int p = ((ks << 2) + g) ^ (lr & 7);
            af[ii][ks] = __builtin_bit_cast(
                bf16x8, *(const u16x8*)&s[base + lr * 64 + p * 8]);
        }
    }
}

__device__ __forceinline__ void read_bfrag(const unsigned short* s, int base,
                                           int wn, int l15, int g,
                                           bf16x8 bf2[2][2]) {
#pragma unroll
    for (int jj = 0; jj < 2; ++jj) {
        const int lr = wn * 32 + jj * 16 + l15;
#pragma unroll
        for (int ks = 0; ks < 2; ++ks) {
            const int p = ((ks << 2) + g) ^ (lr & 7);
            bf2[jj][ks] = __builtin_bit_cast(
                bf16x8, *(const u16x8*)&s[base + lr * 64 + p * 8]);
        }
    }
}

template <int MH, int NH>
__device__ __forceinline__ void mfma_quad(f32x4 acc[8][4],
                                          const bf16x8 af[4][2],
                                          const bf16x8 bf2[2][2]) {
    __builtin_amdgcn_s_setprio(1);
#pragma unroll
    for (int ks = 0; ks < 2; ++ks)
#pragma unroll
        for (int ii = 0; ii < 4; ++ii)
#pragma unroll
            for (int jj = 0; jj < 2; ++jj)
                acc[MH * 4 + ii][NH * 2 + jj] =
                    __builtin_amdgcn_mfma_f32_16x16x32_bf16(
                        af[ii][ks], bf2[jj][ks],
                        acc[MH * 4 + ii][NH * 2 + jj], 0, 0, 0);
    __builtin_amdgcn_s_setprio(0);
}

template <int MODE>
__global__ __launch_bounds__(512) void mfma_gemm256_kernel(
    const unsigned short* __restrict__ A, const unsigned short* __restrict__ BT,
    float* __restrict__ Cf, unsigned short* __restrict__ Cb,
    const float* __restrict__ bias, const float* __restrict__ resid,
    int M, int N, int K) {
    __shared__ __align__(16) unsigned short smem[65536];  // 128 KiB
    const int tid = threadIdx.x;
    const int lane = tid & 63, wave = tid >> 6;
    const int wm = wave >> 2, wn = wave & 3;
    const int l15 = lane & 15, g = lane >> 4;

    const int gx = gridDim.x, nwg = gx * gridDim.y;
    const int lid = blockIdx.y * gx + blockIdx.x;
    const int swz = ((nwg & 7) == 0) ? ((lid & 7) * (nwg >> 3) + (lid >> 3))
                                     : lid;
    const int row0 = (swz / gx) * 256;
    const int col0 = (swz % gx) * 256;

    const int kt = K >> 6;

    f32x4 acc[8][4] = {};

    stage_half<6>(A, K, row0, 0, smem + 0, tid);           // T0 A h0
    stage_half<6>(A, K, row0 + 64, 0, smem + 8192, tid);   // T0 A h1
    stage_half<5>(BT, K, col0, 0, smem + 32768, tid);      // T0 B h0
    stage_half<5>(BT, K, col0 + 32, 0, smem + 40960, tid); // T0 B h1
    VMCNT(4);
    stage_half<6>(A, K, row0, 64, smem + 16384, tid);      // T1 A h0
    stage_half<6>(A, K, row0 + 64, 64, smem + 24576, tid); // T1 A h1
    stage_half<5>(BT, K, col0, 64, smem + 49152, tid);     // T1 B h0
    VMCNT(6);
    GBAR();

    bf16x8 af[4][2], bf0[2][2], bf1[2][2];
    for (int it = 0; it < (kt >> 1); ++it) {
        const int t1k = (2 * it + 1) << 6;
        int t2 = 2 * it + 2; if (t2 > kt - 1) t2 = kt - 1;
        int t3 = 2 * it + 3; if (t3 > kt - 1) t3 = kt - 1;
        const int t2k = t2 << 6, t3k = t3 << 6;

        read_afrag(smem, 0, wm, l15, g, af);
        read_bfrag(smem, 32768, wn, l15, g, bf0);
        stage_half<5>(BT, K, col0 + 32, t1k, smem + 57344, tid);
        GBAR();
        mfma_quad<0, 0>(acc, af, bf0);
        GBAR();

        read_bfrag(smem, 40960, wn, l15, g, bf1);
        stage_half<6>(A, K, row0, t2k, smem + 0, tid);
        GBAR();
        mfma_quad<0, 1>(acc, af, bf1);
        GBAR();

        read_afrag(smem, 8192, wm, l15, g, af);
        stage_half<5>(BT, K, col0, t2k, smem + 32768, tid);
        GBAR();
        mfma_quad<1, 1>(acc, af, bf1);
        GBAR();

        stage_half<6>(A, K, row0 + 64, t2k, smem + 8192, tid);
        GBAR();
        mfma_quad<1, 0>(acc, af, bf0);
        VMCNT(6);
        GBAR();

        read_afrag(smem, 16384, wm, l15, g, af);
        read_bfrag(smem, 49152, wn, l15, g, bf0);
        stage_half<5>(BT, K, col0 + 32, t2k, smem + 40960, tid);
        GBAR();
        mfma_quad<0, 0>(acc, af, bf0);
        GBAR();

        read_bfrag(smem, 57344, wn, l15, g, bf1);
        stage_half<6>(A, K, row0, t3k, smem + 16384, tid);
        GBAR();
        mfma_quad<0, 1>(acc, af, bf1);
        GBAR();

        read_afrag(smem, 24576, wm, l15, g, af);
        stage_half<5>(BT, K, col0, t3k, smem + 49152, tid);
        GBAR();
        mfma_quad<1, 1>(acc, af, bf1);
        GBAR();

        stage_half<6>(A, K, row0 + 64, t3k, smem + 24576, tid);
        GBAR();
        mfma_quad<1, 0>(acc, af, bf0);
        VMCNT(6);
        GBAR();
    }
    VMCNT(0);
    GBAR();

    if (MODE == 2) {
        constexpr int SLAB = 264;  // 32 x 256 bf16 slab, padded stride
#pragma unroll
        for (int i2 = 0; i2 < 8; ++i2) {
            __syncthreads();
#pragma unroll
            for (int j2 = 0; j2 < 4; ++j2) {
                const int col = wn * 64 + j2 * 16 + l15;
                const float bv = bias[col0 + col];
#pragma unroll
                for (int r = 0; r < 4; ++r) {
                    float v = acc[i2][j2][r] + bv;
                    // gelu_tanh: v * t/(t+1), t = 2^(v*(2.302118+0.102942 v^2))
                    float t = fexp2(v * (2.30211849f + 0.10294198f * v * v));
                    float gel = v * t * __builtin_amdgcn_rcpf(t + 1.f);
                    smem[(wm * 16 + g * 4 + r) * SLAB + col] = f2bf(gel);
                }
            }
            __syncthreads();
            const int sr = tid >> 4;           // 0..31 slab row
            const int cc = (tid & 15) * 16;    // col base
            const int grow = row0 + ((sr >> 4) << 7) + i2 * 16 + (sr & 15);
            *(u16x8*)&Cb[(size_t)grow * N + col0 + cc] =
                *(const u16x8*)&smem[sr * SLAB + cc];
            *(u16x8*)&Cb[(size_t)grow * N + col0 + cc + 8] =
                *(const u16x8*)&smem[sr * SLAB + cc + 8];
        }
        return;
    }

#pragma unroll
    for (int i2 = 0; i2 < 8; ++i2) {
#pragma unroll
        for (int j2 = 0; j2 < 4; ++j2) {
            const int col = col0 + wn * 64 + j2 * 16 + l15;
            const int rowb = row0 + wm * 128 + i2 * 16 + g * 4;
            const float bv = bias[col];
#pragma unroll
            for (int r = 0; r < 4; ++r) {
                const int row = rowb + r;
                float v = acc[i2][j2][r] + bv + resid[(size_t)row * N + col];
                Cf[(size_t)row * N + col] = v;
            }
        }
    }
}

// ---------------------------------------------------------------------------
// 256x128-tile, BK=64, 8-wave (4M x 2N), 8-phase GEMM — for N=1024/3072 cases
// where a 256x256 grid under-fills the 256 CUs. vmcnt(5) at ph4/ph8.
// MODE 3: fp32 C+bias+resid. MODE 4: QKV scatter.
// ---------------------------------------------------------------------------
__device__ __forceinline__ void read_af128(const unsigned short* s, int base,
                                           int wm, int l15, int g,
                                           bf16x8 af[2][2]) {
#pragma unroll
    for (int ii = 0; ii < 2; ++ii) {
        const int lr = wm * 32 + ii * 16 + l15;
#pragma unroll
        for (int ks = 0; ks < 2; ++ks) {
            const int p = ((ks << 2) + g) ^ (lr & 7);
            af[ii][ks] = __builtin_bit_cast(
                bf16x8, *(const u16x8*)&s[base + lr * 64 + p * 8]);
        }
    }
}

__device__ __forceinline__ void read_bf128(const unsigned short* s, int base,
                                           int wn, int l15, int g,
                                           bf16x8 bf2[2][2]) {
#pragma unroll
    for (int jj = 0; jj < 2; ++jj) {
        const int lr = wn * 32 + jj * 16 + l15;
#pragma unroll
        for (int ks = 0; ks < 2; ++ks) {
            const int p = ((ks << 2) + g) ^ (lr & 7);
            bf2[jj][ks] = __builtin_bit_cast(
                bf16x8, *(const u16x8*)&s[base + lr * 64 + p * 8]);
        }
    }
}

template <int MH, int NH>
__device__ __forceinline__ void mfma_quad128(f32x4 acc[4][4],
                                             const bf16x8 af[2][2],
                                             const bf16x8 bf2[2][2]) {
    __builtin_amdgcn_s_setprio(1);
#pragma unroll
    for (int ks = 0; ks < 2; ++ks)
#pragma unroll
        for (int ii = 0; ii < 2; ++ii)
#pragma unroll
            for (int jj = 0; jj < 2; ++jj)
                acc[MH * 2 + ii][NH * 2 + jj] =
                    __builtin_amdgcn_mfma_f32_16x16x32_bf16(
                        af[ii][ks], bf2[jj][ks],
                        acc[MH * 2 + ii][NH * 2 + jj], 0, 0, 0);
    __builtin_amdgcn_s_setprio(0);
}

template <int MODE>
__global__ __launch_bounds__(512) void gemm_n128_kernel(
    const unsigned short* __restrict__ A, const unsigned short* __restrict__ BT,
    float* __restrict__ Cf, const float* __restrict__ bias,
    const float* __restrict__ resid, unsigned short* __restrict__ Qb,
    unsigned short* __restrict__ Kb, unsigned short* __restrict__ VTb,
    int M, int N, int K) {
    __shared__ __align__(16) unsigned short smem[49152];  // 96 KiB
    const int tid = threadIdx.x;
    const int lane = tid & 63, wave = tid >> 6;
    const int wm = wave >> 1, wn = wave & 1;
    const int l15 = lane & 15, g = lane >> 4;

    const int gx = gridDim.x, nwg = gx * gridDim.y;
    const int lid = blockIdx.y * gx + blockIdx.x;
    const int swz = ((nwg & 7) == 0) ? ((lid & 7) * (nwg >> 3) + (lid >> 3))
                                     : lid;
    const int row0 = (swz / gx) * 256;
    const int col0 = (swz % gx) * 128;

    const int kt = K >> 6;

    f32x4 acc[4][4] = {};

    stage_half<5>(A, K, row0, 0, smem + 0, tid);            // T0 A h0 (2)
    stage_half<5>(A, K, row0 + 32, 0, smem + 8192, tid);    // T0 A h1 (2)
    stage_64(BT, K, col0, 0, smem + 32768, tid);            // T0 B h0 (1)
    stage_64(BT, K, col0 + 32, 0, smem + 36864, tid);       // T0 B h1 (1)
    VMCNT(4);
    stage_half<5>(A, K, row0, 64, smem + 16384, tid);       // T1 A h0 (2)
    stage_half<5>(A, K, row0 + 32, 64, smem + 24576, tid);  // T1 A h1 (2)
    stage_64(BT, K, col0, 64, smem + 40960, tid);           // T1 B h0 (1)
    VMCNT(5);   // T0's 6 loads done; T1's 5 in flight
    GBAR();

    bf16x8 af[2][2], bf0[2][2], bf1[2][2];
    for (int it = 0; it < (kt >> 1); ++it) {
        const int t1k = (2 * it + 1) << 6;
        int t2 = 2 * it + 2; if (t2 > kt - 1) t2 = kt - 1;   // clamped
        int t3 = 2 * it + 3; if (t3 > kt - 1) t3 = kt - 1;   // (junk re-stage,
        const int t2k = t2 << 6, t3k = t3 << 6;              //  dest dead)

        read_af128(smem, 0, wm, l15, g, af);
        read_bf128(smem, 32768, wn, l15, g, bf0);
        stage_64(BT, K, col0 + 32, t1k, smem + 45056, tid);
        GBAR();
        mfma_quad128<0, 0>(acc, af, bf0);
        GBAR();

        read_bf128(smem, 36864, wn, l15, g, bf1);
        stage_half<5>(A, K, row0, t2k, smem + 0, tid);
        GBAR();
        mfma_quad128<0, 1>(acc, af, bf1);
        GBAR();

        read_af128(smem, 8192, wm, l15, g, af);
        stage_64(BT, K, col0, t2k, smem + 32768, tid);
        GBAR();
        mfma_quad128<1, 1>(acc, af, bf1);
        GBAR();

        stage_half<5>(A, K, row0 + 32, t2k, smem + 8192, tid);
        GBAR();
        mfma_quad128<1, 0>(acc, af, bf0);
        VMCNT(5);
        GBAR();

        read_af128(smem, 16384, wm, l15, g, af);
        read_bf128(smem, 40960, wn, l15, g, bf0);
        stage_64(BT, K, col0 + 32, t2k, smem + 36864, tid);
        GBAR();
        mfma_quad128<0, 0>(acc, af, bf0);
        GBAR();

        read_bf128(smem, 45056, wn, l15, g, bf1);
        stage_half<5>(A, K, row0, t3k, smem + 16384, tid);
        GBAR();
        mfma_quad128<0, 1>(acc, af, bf1);
        GBAR();

        read_af128(smem, 24576, wm, l15, g, af);
        stage_64(BT, K, col0, t3k, smem + 40960, tid);
        GBAR();
        mfma_quad128<1, 1>(acc, af, bf1);
        GBAR();

        stage_half<5>(A, K, row0 + 32, t3k, smem + 24576, tid);
        GBAR();
        mfma_quad128<1, 0>(acc, af, bf0);
        VMCNT(5);
        GBAR();
    }
    VMCNT(0);  // drain junk prefetches before exit
    GBAR();

#pragma unroll
    for (int i2 = 0; i2 < 4; ++i2) {
#pragma unroll
        for (int j2 = 0; j2 < 4; ++j2) {
            const int col = col0 + wn * 64 + j2 * 16 + l15;
            const int rowb = row0 + wm * 64 + i2 * 16 + g * 4;
            if (MODE == 4) {
                const int h = col / 192, e = col % 192;
                const int bb = rowb >> 11, s = rowb & 2047;
                if (e < 64) {
                    unsigned short* q =
                        Qb + (((size_t)bb * HH + h) * SS + s) * 64 + e;
#pragma unroll
                    for (int r = 0; r < 4; ++r)
                        q[r * 64] = f2bf(acc[i2][j2][r] * 0.18033688f);
                } else if (e < 128) {
                    unsigned short* kp =
                        Kb + (((size_t)bb * HH + h) * SS + s) * 64 + (e - 64);
#pragma unroll
                    for (int r = 0; r < 4; ++r)
                        kp[r * 64] = f2bf(acc[i2][j2][r]);
                } else {
                    ushort4 pk;
                    pk.x = f2bf(acc[i2][j2][0]);
                    pk.y = f2bf(acc[i2][j2][1]);
                    pk.z = f2bf(acc[i2][j2][2]);
                    pk.w = f2bf(acc[i2][j2][3]);
                    *(ushort4*)(VTb + (((size_t)bb * HH + h) * 64 + (e - 128)) *
                                          SS + s) = pk;
                }
            } else {
                const float bv = bias[col];
#pragma unroll
                for (int r = 0; r < 4; ++r) {
                    const int row = rowb + r;
                    float v = acc[i2][j2][r] + bv + resid[(size_t)row * N + col];
                    Cf[(size_t)row * N + col] = v;
                }
            }
        }
    }
}

// ---------------------------------------------------------------------------
// Flash causal attention, transposed-score formulation, exp2 domain
// (Q pre-scaled by 0.125*log2e in the QKV epilogue).
// S^T = K Q^T; softmax per q-col (2 shuffles); O^T = V^T P^T.
// Block: 4 waves; each block processes TWO 128-q chunks {p, 15-p} of one
// (b,h) SEQUENTIALLY -> identical work per block (34 kv tiles), grid 64x8 =
// 512 blocks = exactly 2/CU, all co-resident. Wave owns 32 q (2x16 strips).
// K rows staged pi-PERMUTED (pi(16j+4g+r) = 32(j&1)+8g+4(j>>1)+r): each
// lane's QK^T C-frag then holds exactly its PV B-frag kv set -> the P
// exchange is LANE-LOCAL (pf = {Aw[ks],Bw[ks],Aw[2+ks],Bw[2+ks]}); zero
// ds_bpermute. Causal mask uses pi'd kv indices. LDS = K/V dbuf (32 KiB).
// vmcnt(4) counted prefetch; 2 barriers/tile.
// Defer-max (bit-exact, THR=0): skip O-rescale when __all(mx <= mst).
// ---------------------------------------------------------------------------
__global__ __launch_bounds__(256, 2) void fattn_kernel(
    const unsigned short* __restrict__ Qb, const unsigned short* __restrict__ Kb,
    const unsigned short* __restrict__ VTb, unsigned short* __restrict__ att) {
    __shared__ __align__(16) unsigned short Kls[2][64 * 64];
    __shared__ __align__(16) unsigned short VTls[2][64 * 64];

    const int bh = blockIdx.x;
    const int p = blockIdx.y;                    // 0..7 -> chunks {p, 15-p}
    const int tid = threadIdx.x;
    const int lane = tid & 63;
    const int wave = tid >> 6;                   // 0..3
    const int l15 = lane & 15;
    const int g = lane >> 4;
    const int b = bh >> 4, h = bh & 15;
    const int xh = l15 & 7;

    const unsigned short* Qh = Qb + (size_t)bh * SS * 64;
    const unsigned short* Kh = Kb + (size_t)bh * SS * 64;
    const unsigned short* Vh = VTb + (size_t)bh * 64 * SS;

#pragma unroll 1
    for (int half = 0; half < 2; ++half) {
        const int cidx = half ? (15 - p) : p;    // chunk index 0..15
        const int q0c = cidx << 7;
        const int qw = q0c + wave * 32;          // wave's first q row
        const int qlim = qw + 31;
        const int nt = (cidx << 1) + 2;          // kv tiles for this chunk

        // Q fragments straight from global (wave-private rows), 2 strips.
        bf16x8 qf[2][2];
#pragma unroll
        for (int i = 0; i < 2; ++i)
#pragma unroll
            for (int ks = 0; ks < 2; ++ks)
                qf[i][ks] = __builtin_bit_cast(
                    bf16x8, *(const u16x8*)&Qh[(size_t)(qw + i * 16 + l15) * 64 +
                                               ks * 32 + g * 8]);

        f32x4 oacc[4][2] = {};                   // O^T: [jo=dh][i=strip]
        float mst[2], lst[2];
#pragma unroll
        for (int i = 0; i < 2; ++i) { mst[i] = -1e30f; lst[i] = 0.f; }

        stage_k_pi(Kh, &Kls[0][0], tid);
        stage_kv(Vh, SS, &VTls[0][0], tid);

        for (int t = 0; t < nt; ++t) {
            const int t0 = t << 6;
            if (t + 1 < nt) {
                stage_k_pi(Kh + ((size_t)(t + 1) << 6) * 64,
                           &Kls[(t + 1) & 1][0], tid);
                stage_kv(Vh + ((t + 1) << 6), SS, &VTls[(t + 1) & 1][0], tid);
                VMCNT(4);   // tile t resident; t+1's 4 in flight
            } else {
                VMCNT(0);   // last tile: drain
            }
            GBAR();

            if (t0 <= qlim) {
                const unsigned short* Kt = &Kls[t & 1][0];
                const unsigned short* Vt = &VTls[t & 1][0];

                // ---- S^T = K Q^T (both strips share kb) ----
                f32x4 sacc[4][2] = {};
                __builtin_amdgcn_s_setprio(1);
#pragma unroll
                for (int ks = 0; ks < 2; ++ks) {
                    const int ko = ((((ks << 2) + g) ^ xh) << 3);
                    bf16x8 kb[4];
#pragma unroll
                    for (int j = 0; j < 4; ++j)
                        kb[j] = __builtin_bit_cast(
                            bf16x8,
                            *(const u16x8*)&Kt[(j * 16 + l15) * 64 + ko]);
#pragma unroll
                    for (int j = 0; j < 4; ++j)
#pragma unroll
                        for (int i = 0; i < 2; ++i)
                            sacc[j][i] =
                                __builtin_amdgcn_mfma_f32_16x16x32_bf16(
                                    kb[j], qf[i][ks], sacc[j][i], 0, 0, 0);
                }
                __builtin_amdgcn_s_setprio(0);

                // ---- causal mask (pi'd kv indices) ----
                if (t0 + 63 > qw) {
#pragma unroll
                    for (int j = 0; j < 4; ++j) {
                        const int kgb = t0 + ((j & 1) << 5) + (g << 3) +
                                        ((j >> 1) << 2);
#pragma unroll
                        for (int i = 0; i < 2; ++i) {
                            const int qgi = qw + i * 16 + l15;
#pragma unroll
                            for (int r = 0; r < 4; ++r)
                                if (kgb + r > qgi) sacc[j][i][r] = -1e30f;
                        }
                    }
                }

                // ---- online softmax (exp2 domain), P lane-local ----
                unsigned int Aw[2][4], Bw[2][4];
#pragma unroll
                for (int i = 0; i < 2; ++i) {
                    float mx = -1e30f;
#pragma unroll
                    for (int j = 0; j < 4; ++j)
                        mx = fmaxf(mx,
                                   fmaxf(fmaxf(sacc[j][i][0], sacc[j][i][1]),
                                         fmaxf(sacc[j][i][2], sacc[j][i][3])));
                    mx = fmaxf(mx, __shfl_xor(mx, 16));
                    mx = fmaxf(mx, __shfl_xor(mx, 32));
                    const bool grow = !__all(mx <= mst[i]);
                    float al = 1.f;
                    if (grow) {
                        const float mn = fmaxf(mst[i], mx);
                        al = fexp2(mst[i] - mn);
                        mst[i] = mn;
                    }
                    const float mm = mst[i];
                    float rsum = 0.f;
#pragma unroll
                    for (int j = 0; j < 4; ++j) {
                        float p0 = fexp2(sacc[j][i][0] - mm);
                        float p1 = fexp2(sacc[j][i][1] - mm);
                        float p2 = fexp2(sacc[j][i][2] - mm);
                        float p3 = fexp2(sacc[j][i][3] - mm);
                        rsum += (p0 + p1) + (p2 + p3);
                        Aw[i][j] = (unsigned int)f2bf(p0) |
                                   ((unsigned int)f2bf(p1) << 16);
                        Bw[i][j] = (unsigned int)f2bf(p2) |
                                   ((unsigned int)f2bf(p3) << 16);
                    }
                    rsum += __shfl_xor(rsum, 16);
                    rsum += __shfl_xor(rsum, 32);
                    if (grow) {
                        lst[i] = lst[i] * al + rsum;
#pragma unroll
                        for (int jo = 0; jo < 4; ++jo)
#pragma unroll
                            for (int r = 0; r < 4; ++r) oacc[jo][i][r] *= al;
                    } else {
                        lst[i] += rsum;
                    }
                }

                // ---- O^T += V^T P^T (pf fully lane-local via pi) ----
#pragma unroll
                for (int ks = 0; ks < 2; ++ks) {
                    const int ko = ((((ks << 2) + g) ^ xh) << 3);
                    bf16x8 vb[4];
#pragma unroll
                    for (int jo = 0; jo < 4; ++jo)
                        vb[jo] = __builtin_bit_cast(
                            bf16x8,
                            *(const u16x8*)&Vt[(jo * 16 + l15) * 64 + ko]);
                    __builtin_amdgcn_s_setprio(1);
#pragma unroll
                    for (int i = 0; i < 2; ++i) {
                        u32x4 pw;
                        pw[0] = Aw[i][ks];
                        pw[1] = Bw[i][ks];
                        pw[2] = Aw[i][2 + ks];
                        pw[3] = Bw[i][2 + ks];
                        const bf16x8 pf = __builtin_bit_cast(bf16x8, pw);
#pragma unroll
                        for (int jo = 0; jo < 4; ++jo)
                            oacc[jo][i] =
                                __builtin_amdgcn_mfma_f32_16x16x32_bf16(
                                    vb[jo], pf, oacc[jo][i], 0, 0, 0);
                    }
                    __builtin_amdgcn_s_setprio(0);
                }
            }
            GBAR();   // reads of buf[t&1] done before next overwrite
        }

        // ---- epilogue: O^T/l -> att[b, q, h*64+dh] ----
#pragma unroll
        for (int i = 0; i < 2; ++i) {
            const float inv = 1.f / lst[i];
            const int qg = qw + i * 16 + l15;
            unsigned short* dst =
                att + ((size_t)b * SS + qg) * DD + h * 64 + g * 4;
#pragma unroll
            for (int jo = 0; jo < 4; ++jo) {
                ushort4 pk;
                pk.x = f2bf(oacc[jo][i][0] * inv);
                pk.y = f2bf(oacc[jo][i][1] * inv);
                pk.z = f2bf(oacc[jo][i][2] * inv);
                pk.w = f2bf(oacc[jo][i][3] * inv);
                *(ushort4*)(dst + jo * 16) = pk;
            }
        }
        GBAR();   // epilogue is LDS-independent; sync before next chunk stage
    }
}

// ---------------------------------------------------------------------------
// LayerNorm over D=1024; optional bf16 copy. In-place safe.
// ---------------------------------------------------------------------------
__global__ __launch_bounds__(256) void ln_kernel(
    const float* __restrict__ X, const float* __restrict__ g,
    const float* __restrict__ bta, float* __restrict__ Y,
    unsigned short* __restrict__ Yb) {
    const int row = blockIdx.x;
    const float4 xv = ((const float4*)(X + (size_t)row * DD))[threadIdx.x];

    __shared__ float red1[4], red2[4];
    float s = xv.x + xv.y + xv.z + xv.w;
#pragma unroll
    for (int off = 32; off > 0; off >>= 1) s += __shfl_down(s, off);
    const int wave = threadIdx.x >> 6;
    if ((threadIdx.x & 63) == 0) red1[wave] = s;
    __syncthreads();
    const float mu = (red1[0] + red1[1] + red1[2] + red1[3]) * (1.f / DD);

    float dx = xv.x - mu, dy = xv.y - mu, dz = xv.z - mu, dw = xv.w - mu;
    float s2 = dx * dx + dy * dy + dz * dz + dw * dw;
#pragma unroll
    for (int off = 32; off > 0; off >>= 1) s2 += __shfl_down(s2, off);
    if ((threadIdx.x & 63) == 0) red2[wave] = s2;
    __syncthreads();
    const float var = (red2[0] + red2[1] + red2[2] + red2[3]) * (1.f / DD);
    const float rstd = rsqrtf(var + LN_EPS);

    const float4 gv = ((const float4*)g)[threadIdx.x];
    const float4 bv = ((const float4*)bta)[threadIdx.x];
    float4 yv;
    yv.x = dx * rstd * gv.x + bv.x;
    yv.y = dy * rstd * gv.y + bv.y;
    yv.z = dz * rstd * gv.z + bv.z;
    yv.w = dw * rstd * gv.w + bv.w;
    ((float4*)(Y + (size_t)row * DD))[threadIdx.x] = yv;
    if (Yb) {
        ushort4 q;
        q.x = f2bf(yv.x); q.y = f2bf(yv.y);
        q.z = f2bf(yv.z); q.w = f2bf(yv.w);
        ((ushort4*)(Yb + (size_t)row * DD))[threadIdx.x] = q;
    }
}

// ---------------------------------------------------------------------------
// Workspace (byte offsets, peak 144 MB):
//   [0,16M)    Qb bf16 (ph2-3) -> out1b bf16 (ph5+)
//   [16M,32M)  Kb; [32M,48M) VTb (ph2-3) -> hbuf bf16 [16M,80M) (ph6-7)
//   [96M,102M) Wq2T; [102M,118M) xb (ph1-2)
//   [96M,112M) att bf16 (ph3-4); [96M,128M) out1 fp32 (ph5-7)
//   [118M,120M) WprojT; [128M,136M) W1T; [136M,144M) W2T
// ---------------------------------------------------------------------------
extern "C" void kernel_launch(void* const* d_in, const int* in_sizes, int n_in,
                              void* d_out, int out_size, void* d_ws,
                              size_t ws_size, hipStream_t stream) {
    const float* x     = (const float*)d_in[0];
    const float* Wqkv  = (const float*)d_in[1];
    const float* Wproj = (const float*)d_in[2];
    const float* bproj = (const float*)d_in[3];
    const float* ln1_g = (const float*)d_in[4];
    const float* ln1_b = (const float*)d_in[5];
    const float* ln2_g = (const float*)d_in[6];
    const float* ln2_b = (const float*)d_in[7];
    const float* W1    = (const float*)d_in[8];
    const float* b1    = (const float*)d_in[9];
    const float* W2    = (const float*)d_in[10];
    const float* b2    = (const float*)d_in[11];
    float* out = (float*)d_out;

    const size_t M = (size_t)BB * SS;     // 8192
    const size_t MB = 1024 * 1024;
    char* w = (char*)d_ws;
    unsigned short* Qb     = (unsigned short*)(w + 0);
    unsigned short* out1b  = (unsigned short*)(w + 0);
    unsigned short* Kb     = (unsigned short*)(w + 16 * MB);
    unsigned short* VTb    = (unsigned short*)(w + 32 * MB);
    unsigned short* hbuf   = (unsigned short*)(w + 16 * MB);
    unsigned short* Wq2T   = (unsigned short*)(w + 96 * MB);
    unsigned short* xb     = (unsigned short*)(w + 102 * MB);
    unsigned short* att    = (unsigned short*)(w + 96 * MB);
    float*          out1   = (float*)(w + 96 * MB);
    unsigned short* WprojT = (unsigned short*)(w + 118 * MB);
    unsigned short* W1T    = (unsigned short*)(w + 128 * MB);
    unsigned short* W2T    = (unsigned short*)(w + 136 * MB);

    // 1. weight/input conversions
    repack_wqkv_bf16_kernel<<<dim3(3, 16, 16), 256, 0, stream>>>(Wqkv, Wq2T);
    transpose_bf16_kernel<<<dim3(16, 16), 256, 0, stream>>>(Wproj, WprojT, 1024, 1024);
    transpose_bf16_kernel<<<dim3(64, 16), 256, 0, stream>>>(W1, W1T, 1024, 4096);
    transpose_bf16_kernel<<<dim3(16, 64), 256, 0, stream>>>(W2, W2T, 4096, 1024);
    f2bf_kernel<<<(int)((M * DD + 255) / 256), 256, 0, stream>>>(x, xb, (int)(M * DD));

    // 2. QKV GEMM -> flash layouts Qb/Kb/VTb (bf16, Q in exp2 domain)
    gemm_n128_kernel<4><<<dim3(3072 / 128, M / 256), 512, 0, stream>>>(
        xb, Wq2T, nullptr, nullptr, nullptr, Qb, Kb, VTb, (int)M, 3072, 1024);

    // 3. flash causal attention -> att bf16 (4-wave equal-work chunk pairs)
    fattn_kernel<<<dim3(BB * HH, 8), 256, 0, stream>>>(Qb, Kb, VTb, att);

    // 4. proj GEMM + bias + residual(x) -> d_out fp32
    gemm_n128_kernel<3><<<dim3(1024 / 128, M / 256), 512, 0, stream>>>(
        att, WprojT, out, bproj, x, nullptr, nullptr, nullptr,
        (int)M, 1024, 1024);

    // 5. LN1 -> out1 fp32 + out1b bf16
    ln_kernel<<<(int)M, 256, 0, stream>>>(out, ln1_g, ln1_b, out1, out1b);

    // 6. MLP up + GELU -> hbuf bf16
    mfma_gemm256_kernel<2><<<dim3(4096 / 256, M / 256), 512, 0, stream>>>(
        out1b, W1T, nullptr, hbuf, b1, nullptr, (int)M, 4096, 1024);

    // 7. MLP down + bias + residual(out1) -> d_out fp32
    gemm_n128_kernel<3><<<dim3(1024 / 128, M / 256), 512, 0, stream>>>(
        hbuf, W2T, out, b2, out1, nullptr, nullptr, nullptr,
        (int)M, 1024, 4096);

    // 8. LN2 in-place on d_out
    ln_kernel<<<(int)M, 256, 0, stream>>>(out, ln2_g, ln2_b, out, nullptr);
}